// Round 9
// baseline (6207.458 us; speedup 1.0000x reference)
//
#include <hip/hip_runtime.h>
#include <math.h>

#define B_ 32
#define L_ 512
#define S_ 37
#define STATIC_ 8
#define D_ 768
#define DI_ 1536
#define N_ 16
#define DTR_ 48
#define NL_ 4
#define V_ 32
#define ROWS_ (B_*L_)      // 16384
#define CB_ 8              // batch chunk
#define CROWS_ (CB_*L_)    // 4096
#define NCH_ (B_/CB_)      // 4
#define NP2_ 1568          // dt_pre(1536) + B(16) + C(16)
#define NP2A_ 1664         // padded to 13*128
#define KE_ 96             // padded embed K (74 -> 96)
#define SEG_ 8             // time segments per sequence
#define TS_ 64             // L_/SEG_
#define UP_ 8              // scan prefetch depth

typedef __bf16 bf16;
typedef __bf16 bf16x8 __attribute__((ext_vector_type(8)));
typedef __bf16 bf16x2 __attribute__((ext_vector_type(2)));
typedef float f32x4 __attribute__((ext_vector_type(4)));

typedef __attribute__((address_space(3))) void lds_void;
typedef __attribute__((address_space(1))) const void gmem_void;

__device__ __forceinline__ void gld16(const void* g, void* l) {
    __builtin_amdgcn_global_load_lds((gmem_void*)g, (lds_void*)l, 16, 0, 0);
}

__device__ __forceinline__ float silu_(float x) { return x / (1.f + __expf(-x)); }
__device__ __forceinline__ float softplus_(float x) {
    return fmaxf(x, 0.f) + __logf(1.f + __expf(-fabsf(x)));
}
__device__ __forceinline__ unsigned pack_bf2_(float a, float b) {
    bf16x2 v{(bf16)a, (bf16)b};
    return __builtin_bit_cast(unsigned, v);
}
template<int CTRL>
__device__ __forceinline__ float dpp_add_(float p) {
    int vi = __builtin_amdgcn_update_dpp(0, __builtin_bit_cast(int, p),
                                         CTRL, 0xF, 0xF, true);
    return p + __builtin_bit_cast(float, vi);
}

// ================= bf16 MFMA GEMM: C[M,*] = A[M,K] @ W[Nalloc,K]^T =================
template<int MODE>
__global__ __launch_bounds__(256) void gemm_mfma(
    const bf16* __restrict__ A, const bf16* __restrict__ W,
    const float* __restrict__ addsrc, void* __restrict__ Cv,
    int Nstore, int K,
    const float* __restrict__ dt_bias, unsigned* __restrict__ scanw,
    float* __restrict__ bc)
{
    __shared__ bf16 As[128 * 32];
    __shared__ bf16 Bs[128 * 32];
    const int tid = threadIdx.x;
    const int m0 = blockIdx.y * 128, n0 = blockIdx.x * 128;

    f32x4 acc[4][4];
    #pragma unroll
    for (int i = 0; i < 4; i++)
        #pragma unroll
        for (int j = 0; j < 4; j++)
            acc[i][j] = f32x4{0.f, 0.f, 0.f, 0.f};

    const int srow = tid >> 2, spart = tid & 3;
    const bf16* ag = A + (size_t)(m0 + srow) * K + spart * 8;
    const bf16* wg = W + (size_t)(n0 + srow) * K + spart * 8;
    char* lA = (char*)As + tid * 16;
    char* lB = (char*)Bs + tid * 16;

    const int lane = tid & 63, wv = tid >> 6;
    const int wr = wv >> 1, wc = wv & 1;
    const int colL = lane & 15, quad = lane >> 4;
    const bf16* aRd = As + (wr * 64 + colL) * 32 + quad * 8;
    const bf16* bRd = Bs + (wc * 64 + colL) * 32 + quad * 8;

    for (int kt = 0; kt < K; kt += 32) {
        gld16(ag + kt, lA);
        gld16(ag + kt + (size_t)64 * K, lA + 4096);
        gld16(wg + kt, lB);
        gld16(wg + kt + (size_t)64 * K, lB + 4096);
        __syncthreads();
        bf16x8 fa[4], fb[4];
        #pragma unroll
        for (int i = 0; i < 4; i++) fa[i] = *(const bf16x8*)(aRd + i * 16 * 32);
        #pragma unroll
        for (int j = 0; j < 4; j++) fb[j] = *(const bf16x8*)(bRd + j * 16 * 32);
        #pragma unroll
        for (int i = 0; i < 4; i++)
            #pragma unroll
            for (int j = 0; j < 4; j++)
                acc[i][j] = __builtin_amdgcn_mfma_f32_16x16x32_bf16(fa[i], fb[j], acc[i][j], 0, 0, 0);
        __syncthreads();
    }

    float* Cf = (float*)Cv;
    bf16*  Cb = (bf16*)Cv;
    #pragma unroll
    for (int i = 0; i < 4; i++) {
        #pragma unroll
        for (int j = 0; j < 4; j++) {
            int n = n0 + wc * 64 + j * 16 + colL;
            #pragma unroll
            for (int r = 0; r < 4; r++) {
                int m = m0 + wr * 64 + i * 16 + quad * 4 + r;
                float v = acc[i][j][r];
                if (MODE == 2) {
                    if (n < DI_) {
                        float dtv = softplus_(v + dt_bias[n]);
                        float u = (float)A[(size_t)m * DI_ + n];
                        scanw[2 * ((size_t)m * DI_ + n)] = pack_bf2_(dtv * u, dtv);
                    } else if (n < NP2_) {
                        int jj = n - DI_;
                        int pos = (jj < 16) ? (2 * jj) : (2 * (jj - 16) + 1);
                        bc[(size_t)m * 32 + pos] = v;
                    }
                } else if (n < Nstore) {
                    if (addsrc) v += addsrc[(size_t)m * Nstore + n];
                    if (MODE == 1) Cb[(size_t)m * Nstore + n] = (bf16)v;
                    else           Cf[(size_t)m * Nstore + n] = v;
                }
            }
        }
    }
}

// ================= small prep kernels =================
__global__ __launch_bounds__(256) void cast_f2b_kernel(const float* __restrict__ s,
                                                       bf16* __restrict__ d) {
    size_t i = (size_t)blockIdx.x * 256 + threadIdx.x;
    d[i] = (bf16)s[i];
}

__global__ __launch_bounds__(256) void pad_lm_kernel(const float* __restrict__ s, bf16* __restrict__ d) {
    int i = blockIdx.x * 256 + threadIdx.x;     // 128*768
    int row = i / D_;
    d[i] = (row < V_) ? (bf16)s[i] : (bf16)0.f;
}

__global__ __launch_bounds__(256) void pad_embw_kernel(const float* __restrict__ s, bf16* __restrict__ d) {
    int i = blockIdx.x * 256 + threadIdx.x;     // 768*96
    int row = i / KE_, col = i % KE_;
    d[i] = (col < 2 * S_) ? (bf16)s[row * 2 * S_ + col] : (bf16)0.f;
}

__global__ __launch_bounds__(256) void feats_kernel(const float* __restrict__ x,
                                                    const int* __restrict__ mask,
                                                    bf16* __restrict__ d) {
    size_t i = (size_t)blockIdx.x * 256 + threadIdx.x;  // ROWS_*96
    size_t row = i / KE_;
    int col = (int)(i % KE_);
    float v = 0.f;
    if (col < S_) v = x[row * S_ + col];
    else if (col < 2 * S_) v = (float)mask[row * S_ + (col - S_)];
    d[i] = (bf16)v;
}

__global__ __launch_bounds__(256) void wcomb_kernel(const float* __restrict__ dtw,
                                                    const float* __restrict__ xpw,
                                                    bf16* __restrict__ wbig) {
    int l = blockIdx.y;
    size_t idx = (size_t)blockIdx.x * 256 + threadIdx.x;  // 1536*1536
    int i = (int)(idx / DI_), j = (int)(idx % DI_);
    const float* dr = dtw + ((size_t)l * DI_ + i) * DTR_;
    const float* xr = xpw + (size_t)l * (DTR_ + 2 * N_) * DI_ + j;
    float acc = 0.f;
    #pragma unroll
    for (int r = 0; r < DTR_; r++) acc += dr[r] * xr[(size_t)r * DI_];
    wbig[(size_t)l * NP2A_ * DI_ + idx] = (bf16)acc;
}

__global__ __launch_bounds__(256) void wbig_bc_kernel(const float* __restrict__ xpw,
                                                      bf16* __restrict__ wbig) {
    int l = blockIdx.y;
    int idx = blockIdx.x * 256 + threadIdx.x;   // 128*1536
    int row = DI_ + idx / DI_, col = idx % DI_;
    float v = 0.f;
    if (row < NP2_) v = xpw[(size_t)l * (DTR_ + 2 * N_) * DI_ + (size_t)(DTR_ + row - DI_) * DI_ + col];
    wbig[(size_t)l * NP2A_ * DI_ + (size_t)row * DI_ + col] = (bf16)v;
}

__global__ __launch_bounds__(256) void sstat_kernel(const float* __restrict__ stat,
                                                    const float* __restrict__ static_w,
                                                    const float* __restrict__ static_b,
                                                    const float* __restrict__ emb_b,
                                                    float* __restrict__ sstat) {
    int i = blockIdx.x * 256 + threadIdx.x;  // B_*D_
    int d = i % D_, b = i / D_;
    float acc = emb_b[d] + static_b[d];
    const float* sw = static_w + (size_t)d * STATIC_;
    const float* sv = stat + (size_t)b * STATIC_;
    #pragma unroll
    for (int s = 0; s < STATIC_; s++) acc += sv[s] * sw[s];
    sstat[i] = acc;
}

__device__ __forceinline__ void block_reduce2_(float& a, float& b, float* sbuf) {
    #pragma unroll
    for (int off = 32; off > 0; off >>= 1) {
        a += __shfl_down(a, off, 64);
        b += __shfl_down(b, off, 64);
    }
    int lane = threadIdx.x & 63, wid = threadIdx.x >> 6;
    if (lane == 0) { sbuf[wid] = a; sbuf[4 + wid] = b; }
    __syncthreads();
    a = sbuf[0] + sbuf[1] + sbuf[2] + sbuf[3];
    b = sbuf[4] + sbuf[5] + sbuf[6] + sbuf[7];
}

__global__ __launch_bounds__(256) void ln_embed_kernel(const float* __restrict__ h_pre,
                                                       const float* __restrict__ sstat,
                                                       const float* __restrict__ ln_w,
                                                       const float* __restrict__ ln_b,
                                                       float* __restrict__ h) {
    int row = blockIdx.x, b = row / L_, tid = threadIdx.x;
    __shared__ float sbuf[8];
    float v[3], sum = 0.f, sq = 0.f;
    #pragma unroll
    for (int j = 0; j < 3; j++) {
        int d = tid + 256 * j;
        v[j] = h_pre[(size_t)row * D_ + d] + sstat[b * D_ + d];
        sum += v[j]; sq += v[j] * v[j];
    }
    block_reduce2_(sum, sq, sbuf);
    float mu = sum * (1.f / D_);
    float rstd = rsqrtf(sq * (1.f / D_) - mu * mu + 1e-5f);
    #pragma unroll
    for (int j = 0; j < 3; j++) {
        int d = tid + 256 * j;
        h[(size_t)row * D_ + d] = (v[j] - mu) * rstd * ln_w[d] + ln_b[d];
    }
}

__global__ __launch_bounds__(256) void rmsnorm_bf_kernel(const float* __restrict__ h,
                                                         const float* __restrict__ w,
                                                         bf16* __restrict__ out) {
    int row = blockIdx.x, tid = threadIdx.x;
    __shared__ float sbuf[8];
    float v[3], ss = 0.f, dummy = 0.f;
    #pragma unroll
    for (int j = 0; j < 3; j++) {
        v[j] = h[(size_t)row * D_ + tid + 256 * j];
        ss += v[j] * v[j];
    }
    block_reduce2_(ss, dummy, sbuf);
    float rstd = rsqrtf(ss * (1.f / D_) + 1e-5f);
    #pragma unroll
    for (int j = 0; j < 3; j++) {
        int d = tid + 256 * j;
        out[(size_t)row * D_ + d] = (bf16)(v[j] * rstd * w[d]);
    }
}

// conv K=4 + silu -> xc ; gate pack -> scanw[2*idx+1] = pack(D*u*gz, gz)
__global__ __launch_bounds__(256) void conv_silu_kernel(const bf16* __restrict__ xzb,
                                                        const float* __restrict__ cw,
                                                        const float* __restrict__ cb,
                                                        const float* __restrict__ Dp,
                                                        bf16* __restrict__ xcb,
                                                        unsigned* __restrict__ scanw) {
    size_t idx = (size_t)blockIdx.x * 256 + threadIdx.x;   // CROWS_*DI_
    int d = (int)(idx % DI_);
    size_t row = idx / DI_;
    int t = (int)(row % L_);
    float acc = cb[d];
    const float* w = cw + d * 4;
    if (t >= 3) acc += w[0] * (float)xzb[(row - 3) * (2 * DI_) + d];
    if (t >= 2) acc += w[1] * (float)xzb[(row - 2) * (2 * DI_) + d];
    if (t >= 1) acc += w[2] * (float)xzb[(row - 1) * (2 * DI_) + d];
    acc += w[3] * (float)xzb[row * (2 * DI_) + d];
    float u = silu_(acc);
    xcb[idx] = (bf16)u;
    float z = (float)xzb[row * (2 * DI_) + DI_ + d];
    float gz = silu_(z);
    scanw[2 * idx + 1] = pack_bf2_(Dp[d] * u * gz, gz);
}

// ============== segmented scan: pass 1 — local scan (h0=0), emit P and h_end ==============
// grid: (DI_/16, CB_*SEG_); lane: n = tid&15, d = blockIdx.x*16 + tid>>4
__global__ __launch_bounds__(256) void scan_p1_kernel(const float* __restrict__ bc,
                                                      const unsigned* __restrict__ scanw,
                                                      const float* __restrict__ A_log,
                                                      float* __restrict__ Pseg,
                                                      float* __restrict__ Hseg) {
    int tid = threadIdx.x;
    int n = tid & 15;
    int d = blockIdx.x * 16 + (tid >> 4);
    int bs = blockIdx.y;               // b*SEG_ + seg
    int b = bs >> 3, seg = bs & 7;
    float AvL = -__expf(A_log[(size_t)d * N_ + n]) * 1.44269504f;
    size_t rbase = (size_t)b * L_ + seg * TS_;
    const unsigned* pduv = scanw + 2 * (rbase * DI_ + d);      // stride 2*DI_ per t
    const float*    pB   = bc + rbase * 32 + 2 * n;            // stride 32 per t

    unsigned dA0[UP_], dA1[UP_];
    float    B0[UP_],  B1[UP_];
    #pragma unroll
    for (int u = 0; u < UP_; u++) { dA0[u] = pduv[(size_t)u * 2 * DI_]; B0[u] = pB[(size_t)u * 32]; }

    float h = 0.f, dts = 0.f;
    for (int t0 = 0; t0 < TS_; t0 += 2 * UP_) {
        #pragma unroll
        for (int u = 0; u < UP_; u++) {
            int tt = t0 + UP_ + u; tt = tt < TS_ ? tt : TS_ - 1;
            dA1[u] = pduv[(size_t)tt * 2 * DI_]; B1[u] = pB[(size_t)tt * 32];
        }
        #pragma unroll
        for (int u = 0; u < UP_; u++) {
            bf16x2 dv = __builtin_bit_cast(bf16x2, dA0[u]);
            float du = (float)dv.x, dtv = (float)dv.y;
            float dA = __builtin_amdgcn_exp2f(dtv * AvL);
            h = dA * h + du * B0[u];
            dts += dtv;
        }
        #pragma unroll
        for (int u = 0; u < UP_; u++) {
            int tt = t0 + 2 * UP_ + u; tt = tt < TS_ ? tt : TS_ - 1;
            dA0[u] = pduv[(size_t)tt * 2 * DI_]; B0[u] = pB[(size_t)tt * 32];
        }
        #pragma unroll
        for (int u = 0; u < UP_; u++) {
            bf16x2 dv = __builtin_bit_cast(bf16x2, dA1[u]);
            float du = (float)dv.x, dtv = (float)dv.y;
            float dA = __builtin_amdgcn_exp2f(dtv * AvL);
            h = dA * h + du * B1[u];
            dts += dtv;
        }
    }
    size_t oidx = ((size_t)bs * DI_ + d) * N_ + n;
    Pseg[oidx] = __builtin_amdgcn_exp2f(AvL * dts);
    Hseg[oidx] = h;
}

// ============== pass 2 — combine segments: Hseg becomes h_start ==============
__global__ __launch_bounds__(256) void scan_p2_kernel(const float* __restrict__ Pseg,
                                                      float* __restrict__ Hseg) {
    int idx = blockIdx.x * 256 + threadIdx.x;   // CB_*DI_*N_
    int n = idx & 15;
    int rest = idx >> 4;
    int d = rest % DI_, b = rest / DI_;
    float hs = 0.f;
    #pragma unroll
    for (int s = 0; s < SEG_; s++) {
        size_t off = ((size_t)(b * SEG_ + s) * DI_ + d) * N_ + n;
        float Pv = Pseg[off];
        float he = Hseg[off];
        Hseg[off] = hs;
        hs = Pv * hs + he;
    }
}

// ============== pass 3 — re-scan segment from h_start, emit gated y ==============
__global__ __launch_bounds__(256) void scan_p3_kernel(const float* __restrict__ bc,
                                                      const uint2* __restrict__ scanin,
                                                      const float* __restrict__ A_log,
                                                      const float* __restrict__ Hseg,
                                                      bf16* __restrict__ yb) {
    int tid = threadIdx.x;
    int n = tid & 15;
    int d = blockIdx.x * 16 + (tid >> 4);
    int bs = blockIdx.y;
    int b = bs >> 3, seg = bs & 7;
    float AvL = -__expf(A_log[(size_t)d * N_ + n]) * 1.44269504f;
    size_t rbase = (size_t)b * L_ + seg * TS_;
    const uint2*  pin = scanin + rbase * DI_ + d;
    const float2* pBC = (const float2*)bc + rbase * 16 + n;
    bf16*         py  = yb + rbase * DI_ + d;
    float h = Hseg[((size_t)bs * DI_ + d) * N_ + n];

    uint2  iA[UP_], iB[UP_];
    float2 cA[UP_], cB[UP_];
    #pragma unroll
    for (int u = 0; u < UP_; u++) { iA[u] = pin[(size_t)u * DI_]; cA[u] = pBC[(size_t)u * 16]; }

    for (int t0 = 0; t0 < TS_; t0 += 2 * UP_) {
        #pragma unroll
        for (int u = 0; u < UP_; u++) {
            int tt = t0 + UP_ + u; tt = tt < TS_ ? tt : TS_ - 1;
            iB[u] = pin[(size_t)tt * DI_]; cB[u] = pBC[(size_t)tt * 16];
        }
        #pragma unroll
        for (int u = 0; u < UP_; u++) {
            uint2 iv = iA[u];
            bf16x2 dv = __builtin_bit_cast(bf16x2, iv.x);
            float du = (float)dv.x, dtv = (float)dv.y;
            float2 bcv = cA[u];
            float dA = __builtin_amdgcn_exp2f(dtv * AvL);
            h = dA * h + du * bcv.x;
            float p = h * bcv.y;
            p = dpp_add_<0xB1>(p);
            p = dpp_add_<0x4E>(p);
            p = dpp_add_<0x124>(p);
            p = dpp_add_<0x128>(p);
            if (n == 0) {
                bf16x2 og = __builtin_bit_cast(bf16x2, iv.y);
                py[(size_t)(t0 + u) * DI_] = (bf16)(p * (float)og.y + (float)og.x);
            }
        }
        #pragma unroll
        for (int u = 0; u < UP_; u++) {
            int tt = t0 + 2 * UP_ + u; tt = tt < TS_ ? tt : TS_ - 1;
            iA[u] = pin[(size_t)tt * DI_]; cA[u] = pBC[(size_t)tt * 16];
        }
        #pragma unroll
        for (int u = 0; u < UP_; u++) {
            uint2 iv = iB[u];
            bf16x2 dv = __builtin_bit_cast(bf16x2, iv.x);
            float du = (float)dv.x, dtv = (float)dv.y;
            float2 bcv = cB[u];
            float dA = __builtin_amdgcn_exp2f(dtv * AvL);
            h = dA * h + du * bcv.x;
            float p = h * bcv.y;
            p = dpp_add_<0xB1>(p);
            p = dpp_add_<0x4E>(p);
            p = dpp_add_<0x124>(p);
            p = dpp_add_<0x128>(p);
            if (n == 0) {
                bf16x2 og = __builtin_bit_cast(bf16x2, iv.y);
                py[(size_t)(t0 + UP_ + u) * DI_] = (bf16)(p * (float)og.y + (float)og.x);
            }
        }
    }
}

extern "C" void kernel_launch(void* const* d_in, const int* in_sizes, int n_in,
                              void* d_out, int out_size, void* d_ws, size_t ws_size,
                              hipStream_t stream) {
    const float* x        = (const float*)d_in[0];
    const float* stat     = (const float*)d_in[1];
    const int*   mask     = (const int*)d_in[3];
    const float* emb_w    = (const float*)d_in[5];
    const float* emb_b    = (const float*)d_in[6];
    const float* static_w = (const float*)d_in[7];
    const float* static_b = (const float*)d_in[8];
    const float* ln_w     = (const float*)d_in[9];
    const float* ln_b     = (const float*)d_in[10];
    const float* norm_w   = (const float*)d_in[11];
    const float* in_proj_w  = (const float*)d_in[12];
    const float* conv_w   = (const float*)d_in[13];
    const float* conv_b   = (const float*)d_in[14];
    const float* x_proj_w = (const float*)d_in[15];
    const float* dt_proj_w= (const float*)d_in[16];
    const float* dt_proj_b= (const float*)d_in[17];
    const float* A_log    = (const float*)d_in[18];
    const float* D_param  = (const float*)d_in[19];
    const float* out_proj_w = (const float*)d_in[20];
    const float* norm_f_w = (const float*)d_in[21];
    const float* lm_head_w= (const float*)d_in[22];
    float* out = (float*)d_out;

    // ---- workspace layout (bytes), total ~224 MB ----
    char* p = (char*)d_ws;
    float*    h      = (float*)p;         p += (size_t)ROWS_ * D_ * 4;          // 50.3 MB
    bf16*     hn_bf  = (bf16*)p;          p += (size_t)CROWS_ * D_ * 2;         // 6.3
    char*     xz_region = p;                                                    // h_pre alias start
    bf16*     xz_bf  = (bf16*)p;          p += (size_t)CROWS_ * 2 * DI_ * 2;    // 25.2
    bf16*     xc_bf  = (bf16*)p;          p += (size_t)CROWS_ * DI_ * 2;        // 12.6
    unsigned* scanw  = (unsigned*)p;      p += (size_t)CROWS_ * DI_ * 8;        // 50.3 (uint2)
    float*    bc     = (float*)p;         p += (size_t)CROWS_ * 32 * 4;         // 0.5
    float*    Pseg   = (float*)p;         p += (size_t)CB_ * SEG_ * DI_ * N_ * 4; // 6.3
    float*    Hseg   = (float*)p;         p += (size_t)CB_ * SEG_ * DI_ * N_ * 4; // 6.3
    bf16*     y_bf   = (bf16*)p;          p += (size_t)CROWS_ * DI_ * 2;        // 12.6
    bf16*     inw_bf = (bf16*)p;          p += (size_t)NL_ * 2 * DI_ * D_ * 2;  // 18.9
    bf16*     outw_bf= (bf16*)p;          p += (size_t)NL_ * D_ * DI_ * 2;      // 9.4
    bf16*     wbig   = (bf16*)p;          p += (size_t)NL_ * NP2A_ * DI_ * 2;   // 20.4
    bf16*     lmw_bf = (bf16*)p;          p += (size_t)128 * D_ * 2;
    bf16*     embw_bf= (bf16*)p;          p += (size_t)D_ * KE_ * 2;
    bf16*     feats  = (bf16*)p;          p += (size_t)ROWS_ * KE_ * 2;         // 3.1
    float*    sstat  = (float*)p;         p += (size_t)B_ * D_ * 4;
    float*    h_pre  = (float*)xz_region; // 50.3 MB alias over xz/xc/scanw (dead then)

    // ---- weight prep ----
    cast_f2b_kernel<<<(NL_ * 2 * DI_ * D_) / 256, 256, 0, stream>>>(in_proj_w, inw_bf);
    cast_f2b_kernel<<<(NL_ * D_ * DI_) / 256, 256, 0, stream>>>(out_proj_w, outw_bf);
    pad_lm_kernel<<<(128 * D_) / 256, 256, 0, stream>>>(lm_head_w, lmw_bf);
    pad_embw_kernel<<<(D_ * KE_) / 256, 256, 0, stream>>>(emb_w, embw_bf);
    feats_kernel<<<(ROWS_ * KE_) / 256, 256, 0, stream>>>(x, mask, feats);
    dim3 gwc((DI_ * DI_) / 256, NL_);
    wcomb_kernel<<<gwc, 256, 0, stream>>>(dt_proj_w, x_proj_w, wbig);
    dim3 gbc((128 * DI_) / 256, NL_);
    wbig_bc_kernel<<<gbc, 256, 0, stream>>>(x_proj_w, wbig);
    sstat_kernel<<<(B_ * D_) / 256, 256, 0, stream>>>(stat, static_w, static_b, emb_b, sstat);

    // ---- embed + LN ----
    dim3 ge(D_ / 128, ROWS_ / 128);
    gemm_mfma<0><<<ge, 256, 0, stream>>>(feats, embw_bf, nullptr, h_pre, D_, KE_,
                                         nullptr, nullptr, nullptr);
    ln_embed_kernel<<<ROWS_, 256, 0, stream>>>(h_pre, sstat, ln_w, ln_b, h);

    // ---- layers ----
    for (int l = 0; l < NL_; l++) {
        for (int c = 0; c < NCH_; c++) {
            float* hc = h + (size_t)c * CROWS_ * D_;

            rmsnorm_bf_kernel<<<CROWS_, 256, 0, stream>>>(hc, norm_w + (size_t)l * D_, hn_bf);

            dim3 g1((2 * DI_) / 128, CROWS_ / 128);
            gemm_mfma<1><<<g1, 256, 0, stream>>>(hn_bf, inw_bf + (size_t)l * 2 * DI_ * D_,
                                                 nullptr, xz_bf, 2 * DI_, D_,
                                                 nullptr, nullptr, nullptr);

            conv_silu_kernel<<<(CROWS_ * DI_) / 256, 256, 0, stream>>>(
                xz_bf, conv_w + (size_t)l * DI_ * 4, conv_b + (size_t)l * DI_,
                D_param + (size_t)l * DI_, xc_bf, scanw);

            dim3 g2(NP2A_ / 128, CROWS_ / 128);
            gemm_mfma<2><<<g2, 256, 0, stream>>>(xc_bf, wbig + (size_t)l * NP2A_ * DI_,
                                                 nullptr, nullptr, NP2_, DI_,
                                                 dt_proj_b + (size_t)l * DI_, scanw, bc);

            dim3 gs(DI_ / 16, CB_ * SEG_);
            scan_p1_kernel<<<gs, 256, 0, stream>>>(bc, scanw,
                                                   A_log + (size_t)l * DI_ * N_, Pseg, Hseg);
            scan_p2_kernel<<<(CB_ * DI_ * N_) / 256, 256, 0, stream>>>(Pseg, Hseg);
            scan_p3_kernel<<<gs, 256, 0, stream>>>(bc, (const uint2*)scanw,
                                                   A_log + (size_t)l * DI_ * N_, Hseg, y_bf);

            dim3 g3(D_ / 128, CROWS_ / 128);
            gemm_mfma<0><<<g3, 256, 0, stream>>>(y_bf, outw_bf + (size_t)l * D_ * DI_,
                                                 hc, hc, D_, DI_,
                                                 nullptr, nullptr, nullptr);
        }
    }

    // ---- final rmsnorm + lm_head ----
    for (int c = 0; c < NCH_; c++) {
        float* hc = h + (size_t)c * CROWS_ * D_;
        rmsnorm_bf_kernel<<<CROWS_, 256, 0, stream>>>(hc, norm_f_w, hn_bf);
        dim3 glm(1, CROWS_ / 128);
        gemm_mfma<0><<<glm, 256, 0, stream>>>(hn_bf, lmw_bf, nullptr,
                                              out + (size_t)c * CROWS_ * V_, V_, D_,
                                              nullptr, nullptr, nullptr);
    }
}

// Round 10
// 4610.345 us; speedup vs baseline: 1.3464x; 1.3464x over previous
//
#include <hip/hip_runtime.h>
#include <math.h>

#define B_ 32
#define L_ 512
#define S_ 37
#define STATIC_ 8
#define D_ 768
#define DI_ 1536
#define N_ 16
#define DTR_ 48
#define NL_ 4
#define V_ 32
#define ROWS_ (B_*L_)      // 16384
#define CB_ 8              // batch chunk
#define CROWS_ (CB_*L_)    // 4096
#define NCH_ (B_/CB_)      // 4
#define NP2_ 1568          // dt_pre(1536) + B(16) + C(16)
#define NP2A_ 1664         // padded to 13*128
#define KE_ 96             // padded embed K (74 -> 96)
#define TCH_ 64            // scan LDS chunk (timesteps)
#define NCHT_ (L_/TCH_)    // 8 chunks

typedef __bf16 bf16;
typedef __bf16 bf16x8 __attribute__((ext_vector_type(8)));
typedef __bf16 bf16x2 __attribute__((ext_vector_type(2)));
typedef float f32x4 __attribute__((ext_vector_type(4)));

typedef __attribute__((address_space(3))) void lds_void;
typedef __attribute__((address_space(1))) const void gmem_void;

__device__ __forceinline__ void gld16(const void* g, void* l) {
    __builtin_amdgcn_global_load_lds((gmem_void*)g, (lds_void*)l, 16, 0, 0);
}

__device__ __forceinline__ float silu_(float x) { return x / (1.f + __expf(-x)); }
__device__ __forceinline__ float softplus_(float x) {
    return fmaxf(x, 0.f) + __logf(1.f + __expf(-fabsf(x)));
}
__device__ __forceinline__ unsigned pack_bf2_(float a, float b) {
    bf16x2 v{(bf16)a, (bf16)b};
    return __builtin_bit_cast(unsigned, v);
}
template<int CTRL>
__device__ __forceinline__ float dpp_add_(float p) {
    int vi = __builtin_amdgcn_update_dpp(0, __builtin_bit_cast(int, p),
                                         CTRL, 0xF, 0xF, true);
    return p + __builtin_bit_cast(float, vi);
}

// ================= bf16 MFMA GEMM: C[M,*] = A[M,K] @ W[Nalloc,K]^T =================
// MODE 0: f32 out (+addsrc); MODE 1: bf16 out;
// MODE 2: scan-prep: n<DI_ -> scanw[2*(m*DI_+n)] = pack(du,dtv); DI_<=n<NP2_ -> interleaved bc
template<int MODE>
__global__ __launch_bounds__(256) void gemm_mfma(
    const bf16* __restrict__ A, const bf16* __restrict__ W,
    const float* __restrict__ addsrc, void* __restrict__ Cv,
    int Nstore, int K,
    const float* __restrict__ dt_bias, unsigned* __restrict__ scanw,
    float* __restrict__ bc)
{
    __shared__ bf16 As[128 * 32];
    __shared__ bf16 Bs[128 * 32];
    const int tid = threadIdx.x;
    const int m0 = blockIdx.y * 128, n0 = blockIdx.x * 128;

    f32x4 acc[4][4];
    #pragma unroll
    for (int i = 0; i < 4; i++)
        #pragma unroll
        for (int j = 0; j < 4; j++)
            acc[i][j] = f32x4{0.f, 0.f, 0.f, 0.f};

    const int srow = tid >> 2, spart = tid & 3;
    const bf16* ag = A + (size_t)(m0 + srow) * K + spart * 8;
    const bf16* wg = W + (size_t)(n0 + srow) * K + spart * 8;
    char* lA = (char*)As + tid * 16;
    char* lB = (char*)Bs + tid * 16;

    const int lane = tid & 63, wv = tid >> 6;
    const int wr = wv >> 1, wc = wv & 1;
    const int colL = lane & 15, quad = lane >> 4;
    const bf16* aRd = As + (wr * 64 + colL) * 32 + quad * 8;
    const bf16* bRd = Bs + (wc * 64 + colL) * 32 + quad * 8;

    for (int kt = 0; kt < K; kt += 32) {
        gld16(ag + kt, lA);
        gld16(ag + kt + (size_t)64 * K, lA + 4096);
        gld16(wg + kt, lB);
        gld16(wg + kt + (size_t)64 * K, lB + 4096);
        __syncthreads();
        bf16x8 fa[4], fb[4];
        #pragma unroll
        for (int i = 0; i < 4; i++) fa[i] = *(const bf16x8*)(aRd + i * 16 * 32);
        #pragma unroll
        for (int j = 0; j < 4; j++) fb[j] = *(const bf16x8*)(bRd + j * 16 * 32);
        #pragma unroll
        for (int i = 0; i < 4; i++)
            #pragma unroll
            for (int j = 0; j < 4; j++)
                acc[i][j] = __builtin_amdgcn_mfma_f32_16x16x32_bf16(fa[i], fb[j], acc[i][j], 0, 0, 0);
        __syncthreads();
    }

    float* Cf = (float*)Cv;
    bf16*  Cb = (bf16*)Cv;
    #pragma unroll
    for (int i = 0; i < 4; i++) {
        #pragma unroll
        for (int j = 0; j < 4; j++) {
            int n = n0 + wc * 64 + j * 16 + colL;
            #pragma unroll
            for (int r = 0; r < 4; r++) {
                int m = m0 + wr * 64 + i * 16 + quad * 4 + r;
                float v = acc[i][j][r];
                if (MODE == 2) {
                    if (n < DI_) {
                        float dtv = softplus_(v + dt_bias[n]);
                        float u = (float)A[(size_t)m * DI_ + n];
                        scanw[2 * ((size_t)m * DI_ + n)] = pack_bf2_(dtv * u, dtv);
                    } else if (n < NP2_) {
                        int jj = n - DI_;
                        int pos = (jj < 16) ? (2 * jj) : (2 * (jj - 16) + 1);
                        bc[(size_t)m * 32 + pos] = v;
                    }
                } else if (n < Nstore) {
                    if (addsrc) v += addsrc[(size_t)m * Nstore + n];
                    if (MODE == 1) Cb[(size_t)m * Nstore + n] = (bf16)v;
                    else           Cf[(size_t)m * Nstore + n] = v;
                }
            }
        }
    }
}

// ================= small prep kernels =================
__global__ __launch_bounds__(256) void cast_f2b_kernel(const float* __restrict__ s,
                                                       bf16* __restrict__ d) {
    size_t i = (size_t)blockIdx.x * 256 + threadIdx.x;
    d[i] = (bf16)s[i];
}

__global__ __launch_bounds__(256) void pad_lm_kernel(const float* __restrict__ s, bf16* __restrict__ d) {
    int i = blockIdx.x * 256 + threadIdx.x;     // 128*768
    int row = i / D_;
    d[i] = (row < V_) ? (bf16)s[i] : (bf16)0.f;
}

__global__ __launch_bounds__(256) void pad_embw_kernel(const float* __restrict__ s, bf16* __restrict__ d) {
    int i = blockIdx.x * 256 + threadIdx.x;     // 768*96
    int row = i / KE_, col = i % KE_;
    d[i] = (col < 2 * S_) ? (bf16)s[row * 2 * S_ + col] : (bf16)0.f;
}

__global__ __launch_bounds__(256) void feats_kernel(const float* __restrict__ x,
                                                    const int* __restrict__ mask,
                                                    bf16* __restrict__ d) {
    size_t i = (size_t)blockIdx.x * 256 + threadIdx.x;  // ROWS_*96
    size_t row = i / KE_;
    int col = (int)(i % KE_);
    float v = 0.f;
    if (col < S_) v = x[row * S_ + col];
    else if (col < 2 * S_) v = (float)mask[row * S_ + (col - S_)];
    d[i] = (bf16)v;
}

__global__ __launch_bounds__(256) void wcomb_kernel(const float* __restrict__ dtw,
                                                    const float* __restrict__ xpw,
                                                    bf16* __restrict__ wbig) {
    int l = blockIdx.y;
    size_t idx = (size_t)blockIdx.x * 256 + threadIdx.x;  // 1536*1536
    int i = (int)(idx / DI_), j = (int)(idx % DI_);
    const float* dr = dtw + ((size_t)l * DI_ + i) * DTR_;
    const float* xr = xpw + (size_t)l * (DTR_ + 2 * N_) * DI_ + j;
    float acc = 0.f;
    #pragma unroll
    for (int r = 0; r < DTR_; r++) acc += dr[r] * xr[(size_t)r * DI_];
    wbig[(size_t)l * NP2A_ * DI_ + idx] = (bf16)acc;
}

__global__ __launch_bounds__(256) void wbig_bc_kernel(const float* __restrict__ xpw,
                                                      bf16* __restrict__ wbig) {
    int l = blockIdx.y;
    int idx = blockIdx.x * 256 + threadIdx.x;   // 128*1536
    int row = DI_ + idx / DI_, col = idx % DI_;
    float v = 0.f;
    if (row < NP2_) v = xpw[(size_t)l * (DTR_ + 2 * N_) * DI_ + (size_t)(DTR_ + row - DI_) * DI_ + col];
    wbig[(size_t)l * NP2A_ * DI_ + (size_t)row * DI_ + col] = (bf16)v;
}

__global__ __launch_bounds__(256) void sstat_kernel(const float* __restrict__ stat,
                                                    const float* __restrict__ static_w,
                                                    const float* __restrict__ static_b,
                                                    const float* __restrict__ emb_b,
                                                    float* __restrict__ sstat) {
    int i = blockIdx.x * 256 + threadIdx.x;  // B_*D_
    int d = i % D_, b = i / D_;
    float acc = emb_b[d] + static_b[d];
    const float* sw = static_w + (size_t)d * STATIC_;
    const float* sv = stat + (size_t)b * STATIC_;
    #pragma unroll
    for (int s = 0; s < STATIC_; s++) acc += sv[s] * sw[s];
    sstat[i] = acc;
}

__device__ __forceinline__ void block_reduce2_(float& a, float& b, float* sbuf) {
    #pragma unroll
    for (int off = 32; off > 0; off >>= 1) {
        a += __shfl_down(a, off, 64);
        b += __shfl_down(b, off, 64);
    }
    int lane = threadIdx.x & 63, wid = threadIdx.x >> 6;
    if (lane == 0) { sbuf[wid] = a; sbuf[4 + wid] = b; }
    __syncthreads();
    a = sbuf[0] + sbuf[1] + sbuf[2] + sbuf[3];
    b = sbuf[4] + sbuf[5] + sbuf[6] + sbuf[7];
}

__global__ __launch_bounds__(256) void ln_embed_kernel(const float* __restrict__ h_pre,
                                                       const float* __restrict__ sstat,
                                                       const float* __restrict__ ln_w,
                                                       const float* __restrict__ ln_b,
                                                       float* __restrict__ h) {
    int row = blockIdx.x, b = row / L_, tid = threadIdx.x;
    __shared__ float sbuf[8];
    float v[3], sum = 0.f, sq = 0.f;
    #pragma unroll
    for (int j = 0; j < 3; j++) {
        int d = tid + 256 * j;
        v[j] = h_pre[(size_t)row * D_ + d] + sstat[b * D_ + d];
        sum += v[j]; sq += v[j] * v[j];
    }
    block_reduce2_(sum, sq, sbuf);
    float mu = sum * (1.f / D_);
    float rstd = rsqrtf(sq * (1.f / D_) - mu * mu + 1e-5f);
    #pragma unroll
    for (int j = 0; j < 3; j++) {
        int d = tid + 256 * j;
        h[(size_t)row * D_ + d] = (v[j] - mu) * rstd * ln_w[d] + ln_b[d];
    }
}

__global__ __launch_bounds__(256) void rmsnorm_bf_kernel(const float* __restrict__ h,
                                                         const float* __restrict__ w,
                                                         bf16* __restrict__ out) {
    int row = blockIdx.x, tid = threadIdx.x;
    __shared__ float sbuf[8];
    float v[3], ss = 0.f, dummy = 0.f;
    #pragma unroll
    for (int j = 0; j < 3; j++) {
        v[j] = h[(size_t)row * D_ + tid + 256 * j];
        ss += v[j] * v[j];
    }
    block_reduce2_(ss, dummy, sbuf);
    float rstd = rsqrtf(ss * (1.f / D_) + 1e-5f);
    #pragma unroll
    for (int j = 0; j < 3; j++) {
        int d = tid + 256 * j;
        out[(size_t)row * D_ + d] = (bf16)(v[j] * rstd * w[d]);
    }
}

// conv K=4 + silu -> xc ; gate pack -> scanw[2*idx+1] = pack(D*u*gz, gz)
__global__ __launch_bounds__(256) void conv_silu_kernel(const bf16* __restrict__ xzb,
                                                        const float* __restrict__ cw,
                                                        const float* __restrict__ cb,
                                                        const float* __restrict__ Dp,
                                                        bf16* __restrict__ xcb,
                                                        unsigned* __restrict__ scanw) {
    size_t idx = (size_t)blockIdx.x * 256 + threadIdx.x;   // CROWS_*DI_
    int d = (int)(idx % DI_);
    size_t row = idx / DI_;
    int t = (int)(row % L_);
    float acc = cb[d];
    const float* w = cw + d * 4;
    if (t >= 3) acc += w[0] * (float)xzb[(row - 3) * (2 * DI_) + d];
    if (t >= 2) acc += w[1] * (float)xzb[(row - 2) * (2 * DI_) + d];
    if (t >= 1) acc += w[2] * (float)xzb[(row - 1) * (2 * DI_) + d];
    acc += w[3] * (float)xzb[row * (2 * DI_) + d];
    float u = silu_(acc);
    xcb[idx] = (bf16)u;
    float z = (float)xzb[row * (2 * DI_) + DI_ + d];
    float gz = silu_(z);
    scanw[2 * idx + 1] = pack_bf2_(Dp[d] * u * gz, gz);
}

// ============== single-pass scan with LDS double-buffered staging ==============
// block: 16 d_local x 16 n; grid: (DI_/16, CB_). Chunks of TCH_=64 timesteps.
// LDS: lsw[buf][t][d] = uint2{pack(du,dtv), pack(off,gz)}; lbc[buf][t][n] = float2{B_n, C_n}
__global__ __launch_bounds__(256) void scan_lds_kernel(const float2* __restrict__ bcp,
                                                       const uint2* __restrict__ scanin,
                                                       const float* __restrict__ A_log,
                                                       bf16* __restrict__ yb) {
    __shared__ uint2  lsw[2][TCH_][16];
    __shared__ float2 lbc[2][TCH_][16];
    const int tid = threadIdx.x;
    const int n = tid & 15, dl = tid >> 4;
    const int d = blockIdx.x * 16 + dl;
    const int b = blockIdx.y;
    const float AvL = -__expf(A_log[(size_t)d * N_ + n]) * 1.44269504f;
    const size_t seqbase = (size_t)b * L_;
    const int d0 = blockIdx.x * 16;

    // staging role: this thread covers (t = i*16 + dl, elem = n) for i=0..3
    uint2  swr[4];
    float2 bcr[4];

    #define GLOAD(c)                                                        \
        {                                                                   \
            size_t rb = seqbase + (size_t)(c) * TCH_;                       \
            _Pragma("unroll")                                               \
            for (int i = 0; i < 4; i++) {                                   \
                int t = i * 16 + dl;                                        \
                swr[i] = scanin[(rb + t) * DI_ + d0 + n];                   \
                bcr[i] = bcp[(rb + t) * 16 + n];                            \
            }                                                               \
        }
    #define DSWRITE(p)                                                      \
        {                                                                   \
            _Pragma("unroll")                                               \
            for (int i = 0; i < 4; i++) {                                   \
                int t = i * 16 + dl;                                        \
                lsw[p][t][n] = swr[i];                                      \
                lbc[p][t][n] = bcr[i];                                      \
            }                                                               \
        }

    GLOAD(0);
    DSWRITE(0);
    __syncthreads();
    GLOAD(1);

    float h = 0.f;
    for (int c = 0; c < NCHT_; c++) {
        int p = c & 1;
        bf16* py = yb + (seqbase + (size_t)c * TCH_) * DI_ + d;
        #pragma unroll 8
        for (int t = 0; t < TCH_; t++) {
            uint2 iv = lsw[p][t][dl];
            float2 bcv = lbc[p][t][n];
            bf16x2 dv = __builtin_bit_cast(bf16x2, iv.x);
            float du = (float)dv.x, dtv = (float)dv.y;
            float dA = __builtin_amdgcn_exp2f(dtv * AvL);
            h = dA * h + du * bcv.x;
            float pq = h * bcv.y;
            pq = dpp_add_<0xB1>(pq);    // quad_perm(1,0,3,2)
            pq = dpp_add_<0x4E>(pq);    // quad_perm(2,3,0,1)
            pq = dpp_add_<0x124>(pq);   // row_ror:4
            pq = dpp_add_<0x128>(pq);   // row_ror:8
            if (n == 0) {
                bf16x2 og = __builtin_bit_cast(bf16x2, iv.y);
                py[(size_t)t * DI_] = (bf16)(pq * (float)og.y + (float)og.x);
            }
        }
        if (c + 1 < NCHT_) {
            DSWRITE(p ^ 1);
            __syncthreads();
            if (c + 2 < NCHT_) GLOAD(c + 2);
        }
    }
    #undef GLOAD
    #undef DSWRITE
}

extern "C" void kernel_launch(void* const* d_in, const int* in_sizes, int n_in,
                              void* d_out, int out_size, void* d_ws, size_t ws_size,
                              hipStream_t stream) {
    const float* x        = (const float*)d_in[0];
    const float* stat     = (const float*)d_in[1];
    const int*   mask     = (const int*)d_in[3];
    const float* emb_w    = (const float*)d_in[5];
    const float* emb_b    = (const float*)d_in[6];
    const float* static_w = (const float*)d_in[7];
    const float* static_b = (const float*)d_in[8];
    const float* ln_w     = (const float*)d_in[9];
    const float* ln_b     = (const float*)d_in[10];
    const float* norm_w   = (const float*)d_in[11];
    const float* in_proj_w  = (const float*)d_in[12];
    const float* conv_w   = (const float*)d_in[13];
    const float* conv_b   = (const float*)d_in[14];
    const float* x_proj_w = (const float*)d_in[15];
    const float* dt_proj_w= (const float*)d_in[16];
    const float* dt_proj_b= (const float*)d_in[17];
    const float* A_log    = (const float*)d_in[18];
    const float* D_param  = (const float*)d_in[19];
    const float* out_proj_w = (const float*)d_in[20];
    const float* norm_f_w = (const float*)d_in[21];
    const float* lm_head_w= (const float*)d_in[22];
    float* out = (float*)d_out;

    // ---- workspace layout (bytes), total ~211 MB ----
    char* p = (char*)d_ws;
    float*    h      = (float*)p;         p += (size_t)ROWS_ * D_ * 4;          // 50.3 MB
    bf16*     hn_bf  = (bf16*)p;          p += (size_t)CROWS_ * D_ * 2;         // 6.3
    char*     xz_region = p;                                                    // h_pre alias start
    bf16*     xz_bf  = (bf16*)p;          p += (size_t)CROWS_ * 2 * DI_ * 2;    // 25.2
    bf16*     xc_bf  = (bf16*)p;          p += (size_t)CROWS_ * DI_ * 2;        // 12.6
    unsigned* scanw  = (unsigned*)p;      p += (size_t)CROWS_ * DI_ * 8;        // 50.3 (uint2)
    float*    bc     = (float*)p;         p += (size_t)CROWS_ * 32 * 4;         // 0.5
    bf16*     y_bf   = (bf16*)p;          p += (size_t)CROWS_ * DI_ * 2;        // 12.6
    bf16*     inw_bf = (bf16*)p;          p += (size_t)NL_ * 2 * DI_ * D_ * 2;  // 18.9
    bf16*     outw_bf= (bf16*)p;          p += (size_t)NL_ * D_ * DI_ * 2;      // 9.4
    bf16*     wbig   = (bf16*)p;          p += (size_t)NL_ * NP2A_ * DI_ * 2;   // 20.4
    bf16*     lmw_bf = (bf16*)p;          p += (size_t)128 * D_ * 2;
    bf16*     embw_bf= (bf16*)p;          p += (size_t)D_ * KE_ * 2;
    bf16*     feats  = (bf16*)p;          p += (size_t)ROWS_ * KE_ * 2;         // 3.1
    float*    sstat  = (float*)p;         p += (size_t)B_ * D_ * 4;
    float*    h_pre  = (float*)xz_region; // 50.3 MB alias over xz/xc/scanw (dead then)

    // ---- weight prep ----
    cast_f2b_kernel<<<(NL_ * 2 * DI_ * D_) / 256, 256, 0, stream>>>(in_proj_w, inw_bf);
    cast_f2b_kernel<<<(NL_ * D_ * DI_) / 256, 256, 0, stream>>>(out_proj_w, outw_bf);
    pad_lm_kernel<<<(128 * D_) / 256, 256, 0, stream>>>(lm_head_w, lmw_bf);
    pad_embw_kernel<<<(D_ * KE_) / 256, 256, 0, stream>>>(emb_w, embw_bf);
    feats_kernel<<<(ROWS_ * KE_) / 256, 256, 0, stream>>>(x, mask, feats);
    dim3 gwc((DI_ * DI_) / 256, NL_);
    wcomb_kernel<<<gwc, 256, 0, stream>>>(dt_proj_w, x_proj_w, wbig);
    dim3 gbc((128 * DI_) / 256, NL_);
    wbig_bc_kernel<<<gbc, 256, 0, stream>>>(x_proj_w, wbig);
    sstat_kernel<<<(B_ * D_) / 256, 256, 0, stream>>>(stat, static_w, static_b, emb_b, sstat);

    // ---- embed + LN ----
    dim3 ge(D_ / 128, ROWS_ / 128);
    gemm_mfma<0><<<ge, 256, 0, stream>>>(feats, embw_bf, nullptr, h_pre, D_, KE_,
                                         nullptr, nullptr, nullptr);
    ln_embed_kernel<<<ROWS_, 256, 0, stream>>>(h_pre, sstat, ln_w, ln_b, h);

    // ---- layers ----
    for (int l = 0; l < NL_; l++) {
        for (int c = 0; c < NCH_; c++) {
            float* hc = h + (size_t)c * CROWS_ * D_;

            rmsnorm_bf_kernel<<<CROWS_, 256, 0, stream>>>(hc, norm_w + (size_t)l * D_, hn_bf);

            dim3 g1((2 * DI_) / 128, CROWS_ / 128);
            gemm_mfma<1><<<g1, 256, 0, stream>>>(hn_bf, inw_bf + (size_t)l * 2 * DI_ * D_,
                                                 nullptr, xz_bf, 2 * DI_, D_,
                                                 nullptr, nullptr, nullptr);

            conv_silu_kernel<<<(CROWS_ * DI_) / 256, 256, 0, stream>>>(
                xz_bf, conv_w + (size_t)l * DI_ * 4, conv_b + (size_t)l * DI_,
                D_param + (size_t)l * DI_, xc_bf, scanw);

            dim3 g2(NP2A_ / 128, CROWS_ / 128);
            gemm_mfma<2><<<g2, 256, 0, stream>>>(xc_bf, wbig + (size_t)l * NP2A_ * DI_,
                                                 nullptr, nullptr, NP2_, DI_,
                                                 dt_proj_b + (size_t)l * DI_, scanw, bc);

            dim3 gs(DI_ / 16, CB_);
            scan_lds_kernel<<<gs, 256, 0, stream>>>((const float2*)bc, (const uint2*)scanw,
                                                    A_log + (size_t)l * DI_ * N_, y_bf);

            dim3 g3(D_ / 128, CROWS_ / 128);
            gemm_mfma<0><<<g3, 256, 0, stream>>>(y_bf, outw_bf + (size_t)l * D_ * DI_,
                                                 hc, hc, D_, DI_,
                                                 nullptr, nullptr, nullptr);
        }
    }

    // ---- final rmsnorm + lm_head ----
    for (int c = 0; c < NCH_; c++) {
        float* hc = h + (size_t)c * CROWS_ * D_;
        rmsnorm_bf_kernel<<<CROWS_, 256, 0, stream>>>(hc, norm_f_w, hn_bf);
        dim3 glm(1, CROWS_ / 128);
        gemm_mfma<0><<<glm, 256, 0, stream>>>(hn_bf, lmw_bf, nullptr,
                                              out + (size_t)c * CROWS_ * V_, V_, D_,
                                              nullptr, nullptr, nullptr);
    }
}

// Round 11
// 4358.533 us; speedup vs baseline: 1.4242x; 1.0578x over previous
//
#include <hip/hip_runtime.h>
#include <math.h>

#define B_ 32
#define L_ 512
#define S_ 37
#define STATIC_ 8
#define D_ 768
#define DI_ 1536
#define N_ 16
#define DTR_ 48
#define NL_ 4
#define V_ 32
#define ROWS_ (B_*L_)      // 16384
#define CB_ 8              // batch chunk
#define CROWS_ (CB_*L_)    // 4096
#define NCH_ (B_/CB_)      // 4
#define KE_ 96             // padded embed K (74 -> 96)
#define TCH_ 64            // scan LDS chunk (timesteps)
#define NCHT_ (L_/TCH_)    // 8 chunks

typedef __bf16 bf16;
typedef __bf16 bf16x8 __attribute__((ext_vector_type(8)));
typedef __bf16 bf16x2 __attribute__((ext_vector_type(2)));
typedef float f32x4 __attribute__((ext_vector_type(4)));

typedef __attribute__((address_space(3))) void lds_void;
typedef __attribute__((address_space(1))) const void gmem_void;

__device__ __forceinline__ void gld16(const void* g, void* l) {
    __builtin_amdgcn_global_load_lds((gmem_void*)g, (lds_void*)l, 16, 0, 0);
}

__device__ __forceinline__ float silu_(float x) { return x / (1.f + __expf(-x)); }
__device__ __forceinline__ float softplus_(float x) {
    return fmaxf(x, 0.f) + __logf(1.f + __expf(-fabsf(x)));
}
__device__ __forceinline__ unsigned pack_bf2_(float a, float b) {
    bf16x2 v{(bf16)a, (bf16)b};
    return __builtin_bit_cast(unsigned, v);
}
template<int CTRL>
__device__ __forceinline__ float dpp_add_(float p) {
    int vi = __builtin_amdgcn_update_dpp(0, __builtin_bit_cast(int, p),
                                         CTRL, 0xF, 0xF, true);
    return p + __builtin_bit_cast(float, vi);
}

// ================= bf16 MFMA GEMM: C[M,*] = A[M,K] @ W[Nalloc,K]^T =================
// MODE 0: f32 out (+addsrc), stride Nstore
// MODE 1: bf16 out, stride Nstore
// MODE 2: dt epilogue: dtv=softplus(v+dt_bias[n]); u=uref[m*DI_+n]; scanw[2*(m*DI_+n)]=pack(du,dtv)
// MODE 3: xproj epilogue: n<64 -> dtr[m*64+n]=v (bf16); 64<=n<96 -> bc interleaved
template<int MODE>
__global__ __launch_bounds__(256) void gemm_mfma(
    const bf16* __restrict__ A, const bf16* __restrict__ W,
    const float* __restrict__ addsrc, void* __restrict__ Cv,
    int Nstore, int K,
    const float* __restrict__ dt_bias, unsigned* __restrict__ scanw,
    float* __restrict__ bc, const bf16* __restrict__ uref,
    bf16* __restrict__ dtr)
{
    __shared__ bf16 As[128 * 32];
    __shared__ bf16 Bs[128 * 32];
    const int tid = threadIdx.x;
    const int m0 = blockIdx.y * 128, n0 = blockIdx.x * 128;

    f32x4 acc[4][4];
    #pragma unroll
    for (int i = 0; i < 4; i++)
        #pragma unroll
        for (int j = 0; j < 4; j++)
            acc[i][j] = f32x4{0.f, 0.f, 0.f, 0.f};

    const int srow = tid >> 2, spart = tid & 3;
    const bf16* ag = A + (size_t)(m0 + srow) * K + spart * 8;
    const bf16* wg = W + (size_t)(n0 + srow) * K + spart * 8;
    char* lA = (char*)As + tid * 16;
    char* lB = (char*)Bs + tid * 16;

    const int lane = tid & 63, wv = tid >> 6;
    const int wr = wv >> 1, wc = wv & 1;
    const int colL = lane & 15, quad = lane >> 4;
    const bf16* aRd = As + (wr * 64 + colL) * 32 + quad * 8;
    const bf16* bRd = Bs + (wc * 64 + colL) * 32 + quad * 8;

    for (int kt = 0; kt < K; kt += 32) {
        gld16(ag + kt, lA);
        gld16(ag + kt + (size_t)64 * K, lA + 4096);
        gld16(wg + kt, lB);
        gld16(wg + kt + (size_t)64 * K, lB + 4096);
        __syncthreads();
        bf16x8 fa[4], fb[4];
        #pragma unroll
        for (int i = 0; i < 4; i++) fa[i] = *(const bf16x8*)(aRd + i * 16 * 32);
        #pragma unroll
        for (int j = 0; j < 4; j++) fb[j] = *(const bf16x8*)(bRd + j * 16 * 32);
        #pragma unroll
        for (int i = 0; i < 4; i++)
            #pragma unroll
            for (int j = 0; j < 4; j++)
                acc[i][j] = __builtin_amdgcn_mfma_f32_16x16x32_bf16(fa[i], fb[j], acc[i][j], 0, 0, 0);
        __syncthreads();
    }

    float* Cf = (float*)Cv;
    bf16*  Cb = (bf16*)Cv;
    #pragma unroll
    for (int i = 0; i < 4; i++) {
        #pragma unroll
        for (int j = 0; j < 4; j++) {
            int n = n0 + wc * 64 + j * 16 + colL;
            #pragma unroll
            for (int r = 0; r < 4; r++) {
                int m = m0 + wr * 64 + i * 16 + quad * 4 + r;
                float v = acc[i][j][r];
                if (MODE == 2) {
                    float dtv = softplus_(v + dt_bias[n]);
                    float u = (float)uref[(size_t)m * DI_ + n];
                    scanw[2 * ((size_t)m * DI_ + n)] = pack_bf2_(dtv * u, dtv);
                } else if (MODE == 3) {
                    if (n < 64) {
                        dtr[(size_t)m * 64 + n] = (bf16)v;
                    } else if (n < 96) {
                        int jj = n - 64;
                        int pos = (jj < 16) ? (2 * jj) : (2 * (jj - 16) + 1);
                        bc[(size_t)m * 32 + pos] = v;
                    }
                } else if (n < Nstore) {
                    if (addsrc) v += addsrc[(size_t)m * Nstore + n];
                    if (MODE == 1) Cb[(size_t)m * Nstore + n] = (bf16)v;
                    else           Cf[(size_t)m * Nstore + n] = v;
                }
            }
        }
    }
}

// ================= small prep kernels =================
__global__ __launch_bounds__(256) void cast_f2b_kernel(const float* __restrict__ s,
                                                       bf16* __restrict__ d) {
    size_t i = (size_t)blockIdx.x * 256 + threadIdx.x;
    d[i] = (bf16)s[i];
}

__global__ __launch_bounds__(256) void pad_lm_kernel(const float* __restrict__ s, bf16* __restrict__ d) {
    int i = blockIdx.x * 256 + threadIdx.x;     // 128*768
    int row = i / D_;
    d[i] = (row < V_) ? (bf16)s[i] : (bf16)0.f;
}

__global__ __launch_bounds__(256) void pad_embw_kernel(const float* __restrict__ s, bf16* __restrict__ d) {
    int i = blockIdx.x * 256 + threadIdx.x;     // 768*96
    int row = i / KE_, col = i % KE_;
    d[i] = (col < 2 * S_) ? (bf16)s[row * 2 * S_ + col] : (bf16)0.f;
}

__global__ __launch_bounds__(256) void feats_kernel(const float* __restrict__ x,
                                                    const int* __restrict__ mask,
                                                    bf16* __restrict__ d) {
    size_t i = (size_t)blockIdx.x * 256 + threadIdx.x;  // ROWS_*96
    size_t row = i / KE_;
    int col = (int)(i % KE_);
    float v = 0.f;
    if (col < S_) v = x[row * S_ + col];
    else if (col < 2 * S_) v = (float)mask[row * S_ + (col - S_)];
    d[i] = (bf16)v;
}

// x_proj padded+remapped: (NL,128,1536) rows: 0..47=dt_r, 48..63=0, 64..95=B|C, 96..127=0
__global__ __launch_bounds__(256) void xpw_pad_kernel(const float* __restrict__ xpw,
                                                      bf16* __restrict__ d) {
    int l = blockIdx.y;
    int idx = blockIdx.x * 256 + threadIdx.x;   // 128*1536
    int row = idx / DI_, col = idx % DI_;
    float v = 0.f;
    if (row < DTR_) v = xpw[((size_t)l * (DTR_ + 2 * N_) + row) * DI_ + col];
    else if (row >= 64 && row < 96) v = xpw[((size_t)l * (DTR_ + 2 * N_) + row - 16) * DI_ + col];
    d[(size_t)l * 128 * DI_ + idx] = (bf16)v;
}

// dt_proj_w padded: (NL,1536,64), cols 48..63 = 0
__global__ __launch_bounds__(256) void dtw_pad_kernel(const float* __restrict__ dtw,
                                                      bf16* __restrict__ d) {
    int l = blockIdx.y;
    int idx = blockIdx.x * 256 + threadIdx.x;   // 1536*64
    int row = idx / 64, c = idx % 64;
    float v = (c < DTR_) ? dtw[((size_t)l * DI_ + row) * DTR_ + c] : 0.f;
    d[(size_t)l * DI_ * 64 + idx] = (bf16)v;
}

__global__ __launch_bounds__(256) void sstat_kernel(const float* __restrict__ stat,
                                                    const float* __restrict__ static_w,
                                                    const float* __restrict__ static_b,
                                                    const float* __restrict__ emb_b,
                                                    float* __restrict__ sstat) {
    int i = blockIdx.x * 256 + threadIdx.x;  // B_*D_
    int d = i % D_, b = i / D_;
    float acc = emb_b[d] + static_b[d];
    const float* sw = static_w + (size_t)d * STATIC_;
    const float* sv = stat + (size_t)b * STATIC_;
    #pragma unroll
    for (int s = 0; s < STATIC_; s++) acc += sv[s] * sw[s];
    sstat[i] = acc;
}

__device__ __forceinline__ void block_reduce2_(float& a, float& b, float* sbuf) {
    #pragma unroll
    for (int off = 32; off > 0; off >>= 1) {
        a += __shfl_down(a, off, 64);
        b += __shfl_down(b, off, 64);
    }
    int lane = threadIdx.x & 63, wid = threadIdx.x >> 6;
    if (lane == 0) { sbuf[wid] = a; sbuf[4 + wid] = b; }
    __syncthreads();
    a = sbuf[0] + sbuf[1] + sbuf[2] + sbuf[3];
    b = sbuf[4] + sbuf[5] + sbuf[6] + sbuf[7];
}

__global__ __launch_bounds__(256) void ln_embed_kernel(const float* __restrict__ h_pre,
                                                       const float* __restrict__ sstat,
                                                       const float* __restrict__ ln_w,
                                                       const float* __restrict__ ln_b,
                                                       float* __restrict__ h) {
    int row = blockIdx.x, b = row / L_, tid = threadIdx.x;
    __shared__ float sbuf[8];
    float v[3], sum = 0.f, sq = 0.f;
    #pragma unroll
    for (int j = 0; j < 3; j++) {
        int d = tid + 256 * j;
        v[j] = h_pre[(size_t)row * D_ + d] + sstat[b * D_ + d];
        sum += v[j]; sq += v[j] * v[j];
    }
    block_reduce2_(sum, sq, sbuf);
    float mu = sum * (1.f / D_);
    float rstd = rsqrtf(sq * (1.f / D_) - mu * mu + 1e-5f);
    #pragma unroll
    for (int j = 0; j < 3; j++) {
        int d = tid + 256 * j;
        h[(size_t)row * D_ + d] = (v[j] - mu) * rstd * ln_w[d] + ln_b[d];
    }
}

__global__ __launch_bounds__(256) void rmsnorm_bf_kernel(const float* __restrict__ h,
                                                         const float* __restrict__ w,
                                                         bf16* __restrict__ out) {
    int row = blockIdx.x, tid = threadIdx.x;
    __shared__ float sbuf[8];
    float v[3], ss = 0.f, dummy = 0.f;
    #pragma unroll
    for (int j = 0; j < 3; j++) {
        v[j] = h[(size_t)row * D_ + tid + 256 * j];
        ss += v[j] * v[j];
    }
    block_reduce2_(ss, dummy, sbuf);
    float rstd = rsqrtf(ss * (1.f / D_) + 1e-5f);
    #pragma unroll
    for (int j = 0; j < 3; j++) {
        int d = tid + 256 * j;
        out[(size_t)row * D_ + d] = (bf16)(v[j] * rstd * w[d]);
    }
}

// conv K=4 + silu -> xc ; gate pack -> scanw[2*idx+1] = pack(D*u*gz, gz)
__global__ __launch_bounds__(256) void conv_silu_kernel(const bf16* __restrict__ xzb,
                                                        const float* __restrict__ cw,
                                                        const float* __restrict__ cb,
                                                        const float* __restrict__ Dp,
                                                        bf16* __restrict__ xcb,
                                                        unsigned* __restrict__ scanw) {
    size_t idx = (size_t)blockIdx.x * 256 + threadIdx.x;   // CROWS_*DI_
    int d = (int)(idx % DI_);
    size_t row = idx / DI_;
    int t = (int)(row % L_);
    float acc = cb[d];
    const float* w = cw + d * 4;
    if (t >= 3) acc += w[0] * (float)xzb[(row - 3) * (2 * DI_) + d];
    if (t >= 2) acc += w[1] * (float)xzb[(row - 2) * (2 * DI_) + d];
    if (t >= 1) acc += w[2] * (float)xzb[(row - 1) * (2 * DI_) + d];
    acc += w[3] * (float)xzb[row * (2 * DI_) + d];
    float u = silu_(acc);
    xcb[idx] = (bf16)u;
    float z = (float)xzb[row * (2 * DI_) + DI_ + d];
    float gz = silu_(z);
    scanw[2 * idx + 1] = pack_bf2_(Dp[d] * u * gz, gz);
}

// ============== single-pass scan with LDS double-buffered staging ==============
__global__ __launch_bounds__(256) void scan_lds_kernel(const float2* __restrict__ bcp,
                                                       const uint2* __restrict__ scanin,
                                                       const float* __restrict__ A_log,
                                                       bf16* __restrict__ yb) {
    __shared__ uint2  lsw[2][TCH_][16];
    __shared__ float2 lbc[2][TCH_][16];
    const int tid = threadIdx.x;
    const int n = tid & 15, dl = tid >> 4;
    const int d = blockIdx.x * 16 + dl;
    const int b = blockIdx.y;
    const float AvL = -__expf(A_log[(size_t)d * N_ + n]) * 1.44269504f;
    const size_t seqbase = (size_t)b * L_;
    const int d0 = blockIdx.x * 16;

    uint2  swr[4];
    float2 bcr[4];

    #define GLOAD(c)                                                        \
        {                                                                   \
            size_t rb = seqbase + (size_t)(c) * TCH_;                       \
            _Pragma("unroll")                                               \
            for (int i = 0; i < 4; i++) {                                   \
                int t = i * 16 + dl;                                        \
                swr[i] = scanin[(rb + t) * DI_ + d0 + n];                   \
                bcr[i] = bcp[(rb + t) * 16 + n];                            \
            }                                                               \
        }
    #define DSWRITE(p)                                                      \
        {                                                                   \
            _Pragma("unroll")                                               \
            for (int i = 0; i < 4; i++) {                                   \
                int t = i * 16 + dl;                                        \
                lsw[p][t][n] = swr[i];                                      \
                lbc[p][t][n] = bcr[i];                                      \
            }                                                               \
        }

    GLOAD(0);
    DSWRITE(0);
    __syncthreads();
    GLOAD(1);

    float h = 0.f;
    for (int c = 0; c < NCHT_; c++) {
        int p = c & 1;
        bf16* py = yb + (seqbase + (size_t)c * TCH_) * DI_ + d;
        #pragma unroll 8
        for (int t = 0; t < TCH_; t++) {
            uint2 iv = lsw[p][t][dl];
            float2 bcv = lbc[p][t][n];
            bf16x2 dv = __builtin_bit_cast(bf16x2, iv.x);
            float du = (float)dv.x, dtv = (float)dv.y;
            float dA = __builtin_amdgcn_exp2f(dtv * AvL);
            h = dA * h + du * bcv.x;
            float pq = h * bcv.y;
            pq = dpp_add_<0xB1>(pq);
            pq = dpp_add_<0x4E>(pq);
            pq = dpp_add_<0x124>(pq);
            pq = dpp_add_<0x128>(pq);
            if (n == 0) {
                bf16x2 og = __builtin_bit_cast(bf16x2, iv.y);
                py[(size_t)t * DI_] = (bf16)(pq * (float)og.y + (float)og.x);
            }
        }
        if (c + 1 < NCHT_) {
            DSWRITE(p ^ 1);
            __syncthreads();
            if (c + 2 < NCHT_) GLOAD(c + 2);
        }
    }
    #undef GLOAD
    #undef DSWRITE
}

extern "C" void kernel_launch(void* const* d_in, const int* in_sizes, int n_in,
                              void* d_out, int out_size, void* d_ws, size_t ws_size,
                              hipStream_t stream) {
    const float* x        = (const float*)d_in[0];
    const float* stat     = (const float*)d_in[1];
    const int*   mask     = (const int*)d_in[3];
    const float* emb_w    = (const float*)d_in[5];
    const float* emb_b    = (const float*)d_in[6];
    const float* static_w = (const float*)d_in[7];
    const float* static_b = (const float*)d_in[8];
    const float* ln_w     = (const float*)d_in[9];
    const float* ln_b     = (const float*)d_in[10];
    const float* norm_w   = (const float*)d_in[11];
    const float* in_proj_w  = (const float*)d_in[12];
    const float* conv_w   = (const float*)d_in[13];
    const float* conv_b   = (const float*)d_in[14];
    const float* x_proj_w = (const float*)d_in[15];
    const float* dt_proj_w= (const float*)d_in[16];
    const float* dt_proj_b= (const float*)d_in[17];
    const float* A_log    = (const float*)d_in[18];
    const float* D_param  = (const float*)d_in[19];
    const float* out_proj_w = (const float*)d_in[20];
    const float* norm_f_w = (const float*)d_in[21];
    const float* lm_head_w= (const float*)d_in[22];
    float* out = (float*)d_out;

    // ---- workspace layout (bytes), total ~194 MB ----
    char* p = (char*)d_ws;
    float*    h      = (float*)p;         p += (size_t)ROWS_ * D_ * 4;          // 50.3 MB
    bf16*     hn_bf  = (bf16*)p;          p += (size_t)CROWS_ * D_ * 2;         // 6.3
    char*     xz_region = p;                                                    // h_pre alias start
    bf16*     xz_bf  = (bf16*)p;          p += (size_t)CROWS_ * 2 * DI_ * 2;    // 25.2
    bf16*     xc_bf  = (bf16*)p;          p += (size_t)CROWS_ * DI_ * 2;        // 12.6
    unsigned* scanw  = (unsigned*)p;      p += (size_t)CROWS_ * DI_ * 8;        // 50.3 (uint2)
    float*    bc     = (float*)p;         p += (size_t)CROWS_ * 32 * 4;         // 0.5
    bf16*     dtr_bf = (bf16*)p;          p += (size_t)CROWS_ * 64 * 2;         // 0.5
    bf16*     y_bf   = (bf16*)p;          p += (size_t)CROWS_ * DI_ * 2;        // 12.6
    bf16*     inw_bf = (bf16*)p;          p += (size_t)NL_ * 2 * DI_ * D_ * 2;  // 18.9
    bf16*     outw_bf= (bf16*)p;          p += (size_t)NL_ * D_ * DI_ * 2;      // 9.4
    bf16*     xpwp_bf= (bf16*)p;          p += (size_t)NL_ * 128 * DI_ * 2;     // 1.6
    bf16*     dtwp_bf= (bf16*)p;          p += (size_t)NL_ * DI_ * 64 * 2;      // 0.8
    bf16*     lmw_bf = (bf16*)p;          p += (size_t)128 * D_ * 2;
    bf16*     embw_bf= (bf16*)p;          p += (size_t)D_ * KE_ * 2;
    bf16*     feats  = (bf16*)p;          p += (size_t)ROWS_ * KE_ * 2;         // 3.1
    float*    sstat  = (float*)p;         p += (size_t)B_ * D_ * 4;
    float*    h_pre  = (float*)xz_region; // 50.3 MB alias over xz/xc/scanw (dead then)

    // ---- weight prep ----
    cast_f2b_kernel<<<(NL_ * 2 * DI_ * D_) / 256, 256, 0, stream>>>(in_proj_w, inw_bf);
    cast_f2b_kernel<<<(NL_ * D_ * DI_) / 256, 256, 0, stream>>>(out_proj_w, outw_bf);
    pad_lm_kernel<<<(128 * D_) / 256, 256, 0, stream>>>(lm_head_w, lmw_bf);
    pad_embw_kernel<<<(D_ * KE_) / 256, 256, 0, stream>>>(emb_w, embw_bf);
    feats_kernel<<<(ROWS_ * KE_) / 256, 256, 0, stream>>>(x, mask, feats);
    dim3 gxp((128 * DI_) / 256, NL_);
    xpw_pad_kernel<<<gxp, 256, 0, stream>>>(x_proj_w, xpwp_bf);
    dim3 gdt((DI_ * 64) / 256, NL_);
    dtw_pad_kernel<<<gdt, 256, 0, stream>>>(dt_proj_w, dtwp_bf);
    sstat_kernel<<<(B_ * D_) / 256, 256, 0, stream>>>(stat, static_w, static_b, emb_b, sstat);

    // ---- embed + LN ----
    dim3 ge(D_ / 128, ROWS_ / 128);
    gemm_mfma<0><<<ge, 256, 0, stream>>>(feats, embw_bf, nullptr, h_pre, D_, KE_,
                                         nullptr, nullptr, nullptr, nullptr, nullptr);
    ln_embed_kernel<<<ROWS_, 256, 0, stream>>>(h_pre, sstat, ln_w, ln_b, h);

    // ---- layers ----
    for (int l = 0; l < NL_; l++) {
        for (int c = 0; c < NCH_; c++) {
            float* hc = h + (size_t)c * CROWS_ * D_;

            rmsnorm_bf_kernel<<<CROWS_, 256, 0, stream>>>(hc, norm_w + (size_t)l * D_, hn_bf);

            dim3 g1((2 * DI_) / 128, CROWS_ / 128);
            gemm_mfma<1><<<g1, 256, 0, stream>>>(hn_bf, inw_bf + (size_t)l * 2 * DI_ * D_,
                                                 nullptr, xz_bf, 2 * DI_, D_,
                                                 nullptr, nullptr, nullptr, nullptr, nullptr);

            conv_silu_kernel<<<(CROWS_ * DI_) / 256, 256, 0, stream>>>(
                xz_bf, conv_w + (size_t)l * DI_ * 4, conv_b + (size_t)l * DI_,
                D_param + (size_t)l * DI_, xc_bf, scanw);

            // x_proj: dtr (cols 0..63) + bc (interleaved) via MODE 3
            dim3 g2a(1, CROWS_ / 128);
            gemm_mfma<3><<<g2a, 256, 0, stream>>>(xc_bf, xpwp_bf + (size_t)l * 128 * DI_,
                                                  nullptr, nullptr, 0, DI_,
                                                  nullptr, nullptr, bc, nullptr, dtr_bf);

            // dt: softplus + du pack into scanw via MODE 2
            dim3 g2b(DI_ / 128, CROWS_ / 128);
            gemm_mfma<2><<<g2b, 256, 0, stream>>>(dtr_bf, dtwp_bf + (size_t)l * DI_ * 64,
                                                  nullptr, nullptr, 0, 64,
                                                  dt_proj_b + (size_t)l * DI_, scanw,
                                                  nullptr, xc_bf, nullptr);

            dim3 gs(DI_ / 16, CB_);
            scan_lds_kernel<<<gs, 256, 0, stream>>>((const float2*)bc, (const uint2*)scanw,
                                                    A_log + (size_t)l * DI_ * N_, y_bf);

            dim3 g3(D_ / 128, CROWS_ / 128);
            gemm_mfma<0><<<g3, 256, 0, stream>>>(y_bf, outw_bf + (size_t)l * D_ * DI_,
                                                 hc, hc, D_, DI_,
                                                 nullptr, nullptr, nullptr, nullptr, nullptr);
        }
    }

    // ---- final rmsnorm + lm_head ----
    for (int c = 0; c < NCH_; c++) {
        float* hc = h + (size_t)c * CROWS_ * D_;
        rmsnorm_bf_kernel<<<CROWS_, 256, 0, stream>>>(hc, norm_f_w, hn_bf);
        dim3 glm(1, CROWS_ / 128);
        gemm_mfma<0><<<glm, 256, 0, stream>>>(hn_bf, lmw_bf, nullptr,
                                              out + (size_t)c * CROWS_ * V_, V_, D_,
                                              nullptr, nullptr, nullptr, nullptr, nullptr);
    }
}

// Round 12
// 3868.126 us; speedup vs baseline: 1.6048x; 1.1268x over previous
//
#include <hip/hip_runtime.h>
#include <math.h>

#define B_ 32
#define L_ 512
#define S_ 37
#define STATIC_ 8
#define D_ 768
#define DI_ 1536
#define N_ 16
#define DTR_ 48
#define NL_ 4
#define V_ 32
#define ROWS_ (B_*L_)      // 16384
#define CB_ 8              // batch chunk
#define CROWS_ (CB_*L_)    // 4096
#define NCH_ (B_/CB_)      // 4
#define KE_ 96             // padded embed K (74 -> 96)
#define TCH_ 64            // scan LDS chunk (timesteps)
#define NCHT_ (L_/TCH_)    // 8 chunks

typedef __bf16 bf16;
typedef __bf16 bf16x8 __attribute__((ext_vector_type(8)));
typedef __bf16 bf16x2 __attribute__((ext_vector_type(2)));
typedef float f32x4 __attribute__((ext_vector_type(4)));

typedef __attribute__((address_space(3))) void lds_void;
typedef __attribute__((address_space(1))) const void gmem_void;

__device__ __forceinline__ void gld16(const void* g, void* l) {
    __builtin_amdgcn_global_load_lds((gmem_void*)g, (lds_void*)l, 16, 0, 0);
}

__device__ __forceinline__ float silu_(float x) { return x / (1.f + __expf(-x)); }
__device__ __forceinline__ float softplus_(float x) {
    return fmaxf(x, 0.f) + __logf(1.f + __expf(-fabsf(x)));
}
__device__ __forceinline__ unsigned pack_bf2_(float a, float b) {
    bf16x2 v{(bf16)a, (bf16)b};
    return __builtin_bit_cast(unsigned, v);
}
template<int CTRL>
__device__ __forceinline__ float dpp_add_(float p) {
    int vi = __builtin_amdgcn_update_dpp(0, __builtin_bit_cast(int, p),
                                         CTRL, 0xF, 0xF, true);
    return p + __builtin_bit_cast(float, vi);
}

// ================= bf16 MFMA GEMM: C[M,*] = A[M,K] @ W[Nalloc,K]^T =================
// MODE 0: f32 out (+addsrc), stride Nstore
// MODE 1: bf16 out, stride Nstore
// MODE 2: dt epilogue: dtv=softplus(v+dt_bias[n]); u=uref[m*DI_+n]; scanw[2*(m*DI_+n)]=pack(du,dtv)
// MODE 3: xproj epilogue: n<64 -> dtr[m*64+n]=v (bf16); 64<=n<96 -> bc interleaved
template<int MODE>
__global__ __launch_bounds__(256) void gemm_mfma(
    const bf16* __restrict__ A, const bf16* __restrict__ W,
    const float* __restrict__ addsrc, void* __restrict__ Cv,
    int Nstore, int K,
    const float* __restrict__ dt_bias, unsigned* __restrict__ scanw,
    float* __restrict__ bc, const bf16* __restrict__ uref,
    bf16* __restrict__ dtr)
{
    __shared__ bf16 As[128 * 32];
    __shared__ bf16 Bs[128 * 32];
    const int tid = threadIdx.x;
    const int m0 = blockIdx.y * 128, n0 = blockIdx.x * 128;

    f32x4 acc[4][4];
    #pragma unroll
    for (int i = 0; i < 4; i++)
        #pragma unroll
        for (int j = 0; j < 4; j++)
            acc[i][j] = f32x4{0.f, 0.f, 0.f, 0.f};

    const int srow = tid >> 2, spart = tid & 3;
    const bf16* ag = A + (size_t)(m0 + srow) * K + spart * 8;
    const bf16* wg = W + (size_t)(n0 + srow) * K + spart * 8;
    char* lA = (char*)As + tid * 16;
    char* lB = (char*)Bs + tid * 16;

    const int lane = tid & 63, wv = tid >> 6;
    const int wr = wv >> 1, wc = wv & 1;
    const int colL = lane & 15, quad = lane >> 4;
    const bf16* aRd = As + (wr * 64 + colL) * 32 + quad * 8;
    const bf16* bRd = Bs + (wc * 64 + colL) * 32 + quad * 8;

    for (int kt = 0; kt < K; kt += 32) {
        gld16(ag + kt, lA);
        gld16(ag + kt + (size_t)64 * K, lA + 4096);
        gld16(wg + kt, lB);
        gld16(wg + kt + (size_t)64 * K, lB + 4096);
        __syncthreads();
        bf16x8 fa[4], fb[4];
        #pragma unroll
        for (int i = 0; i < 4; i++) fa[i] = *(const bf16x8*)(aRd + i * 16 * 32);
        #pragma unroll
        for (int j = 0; j < 4; j++) fb[j] = *(const bf16x8*)(bRd + j * 16 * 32);
        #pragma unroll
        for (int i = 0; i < 4; i++)
            #pragma unroll
            for (int j = 0; j < 4; j++)
                acc[i][j] = __builtin_amdgcn_mfma_f32_16x16x32_bf16(fa[i], fb[j], acc[i][j], 0, 0, 0);
        __syncthreads();
    }

    float* Cf = (float*)Cv;
    bf16*  Cb = (bf16*)Cv;
    #pragma unroll
    for (int i = 0; i < 4; i++) {
        #pragma unroll
        for (int j = 0; j < 4; j++) {
            int n = n0 + wc * 64 + j * 16 + colL;
            #pragma unroll
            for (int r = 0; r < 4; r++) {
                int m = m0 + wr * 64 + i * 16 + quad * 4 + r;
                float v = acc[i][j][r];
                if (MODE == 2) {
                    float dtv = softplus_(v + dt_bias[n]);
                    float u = (float)uref[(size_t)m * DI_ + n];
                    scanw[2 * ((size_t)m * DI_ + n)] = pack_bf2_(dtv * u, dtv);
                } else if (MODE == 3) {
                    if (n < 64) {
                        dtr[(size_t)m * 64 + n] = (bf16)v;
                    } else if (n < 96) {
                        int jj = n - 64;
                        int pos = (jj < 16) ? (2 * jj) : (2 * (jj - 16) + 1);
                        bc[(size_t)m * 32 + pos] = v;
                    }
                } else if (n < Nstore) {
                    if (addsrc) v += addsrc[(size_t)m * Nstore + n];
                    if (MODE == 1) Cb[(size_t)m * Nstore + n] = (bf16)v;
                    else           Cf[(size_t)m * Nstore + n] = v;
                }
            }
        }
    }
}

// ================= small prep kernels =================
__global__ __launch_bounds__(256) void cast_f2b_kernel(const float* __restrict__ s,
                                                       bf16* __restrict__ d) {
    size_t i = (size_t)blockIdx.x * 256 + threadIdx.x;
    d[i] = (bf16)s[i];
}

__global__ __launch_bounds__(256) void pad_lm_kernel(const float* __restrict__ s, bf16* __restrict__ d) {
    int i = blockIdx.x * 256 + threadIdx.x;     // 128*768
    int row = i / D_;
    d[i] = (row < V_) ? (bf16)s[i] : (bf16)0.f;
}

__global__ __launch_bounds__(256) void pad_embw_kernel(const float* __restrict__ s, bf16* __restrict__ d) {
    int i = blockIdx.x * 256 + threadIdx.x;     // 768*96
    int row = i / KE_, col = i % KE_;
    d[i] = (col < 2 * S_) ? (bf16)s[row * 2 * S_ + col] : (bf16)0.f;
}

__global__ __launch_bounds__(256) void feats_kernel(const float* __restrict__ x,
                                                    const int* __restrict__ mask,
                                                    bf16* __restrict__ d) {
    size_t i = (size_t)blockIdx.x * 256 + threadIdx.x;  // ROWS_*96
    size_t row = i / KE_;
    int col = (int)(i % KE_);
    float v = 0.f;
    if (col < S_) v = x[row * S_ + col];
    else if (col < 2 * S_) v = (float)mask[row * S_ + (col - S_)];
    d[i] = (bf16)v;
}

// x_proj padded+remapped: (NL,128,1536) rows: 0..47=dt_r, 48..63=0, 64..95=B|C, 96..127=0
__global__ __launch_bounds__(256) void xpw_pad_kernel(const float* __restrict__ xpw,
                                                      bf16* __restrict__ d) {
    int l = blockIdx.y;
    int idx = blockIdx.x * 256 + threadIdx.x;   // 128*1536
    int row = idx / DI_, col = idx % DI_;
    float v = 0.f;
    if (row < DTR_) v = xpw[((size_t)l * (DTR_ + 2 * N_) + row) * DI_ + col];
    else if (row >= 64 && row < 96) v = xpw[((size_t)l * (DTR_ + 2 * N_) + row - 16) * DI_ + col];
    d[(size_t)l * 128 * DI_ + idx] = (bf16)v;
}

// dt_proj_w padded: (NL,1536,64), cols 48..63 = 0
__global__ __launch_bounds__(256) void dtw_pad_kernel(const float* __restrict__ dtw,
                                                      bf16* __restrict__ d) {
    int l = blockIdx.y;
    int idx = blockIdx.x * 256 + threadIdx.x;   // 1536*64
    int row = idx / 64, c = idx % 64;
    float v = (c < DTR_) ? dtw[((size_t)l * DI_ + row) * DTR_ + c] : 0.f;
    d[(size_t)l * DI_ * 64 + idx] = (bf16)v;
}

__global__ __launch_bounds__(256) void sstat_kernel(const float* __restrict__ stat,
                                                    const float* __restrict__ static_w,
                                                    const float* __restrict__ static_b,
                                                    const float* __restrict__ emb_b,
                                                    float* __restrict__ sstat) {
    int i = blockIdx.x * 256 + threadIdx.x;  // B_*D_
    int d = i % D_, b = i / D_;
    float acc = emb_b[d] + static_b[d];
    const float* sw = static_w + (size_t)d * STATIC_;
    const float* sv = stat + (size_t)b * STATIC_;
    #pragma unroll
    for (int s = 0; s < STATIC_; s++) acc += sv[s] * sw[s];
    sstat[i] = acc;
}

__device__ __forceinline__ void block_reduce2_(float& a, float& b, float* sbuf) {
    #pragma unroll
    for (int off = 32; off > 0; off >>= 1) {
        a += __shfl_down(a, off, 64);
        b += __shfl_down(b, off, 64);
    }
    int lane = threadIdx.x & 63, wid = threadIdx.x >> 6;
    if (lane == 0) { sbuf[wid] = a; sbuf[4 + wid] = b; }
    __syncthreads();
    a = sbuf[0] + sbuf[1] + sbuf[2] + sbuf[3];
    b = sbuf[4] + sbuf[5] + sbuf[6] + sbuf[7];
}

__global__ __launch_bounds__(256) void ln_embed_kernel(const float* __restrict__ h_pre,
                                                       const float* __restrict__ sstat,
                                                       const float* __restrict__ ln_w,
                                                       const float* __restrict__ ln_b,
                                                       float* __restrict__ h) {
    int row = blockIdx.x, b = row / L_, tid = threadIdx.x;
    __shared__ float sbuf[8];
    float v[3], sum = 0.f, sq = 0.f;
    #pragma unroll
    for (int j = 0; j < 3; j++) {
        int d = tid + 256 * j;
        v[j] = h_pre[(size_t)row * D_ + d] + sstat[b * D_ + d];
        sum += v[j]; sq += v[j] * v[j];
    }
    block_reduce2_(sum, sq, sbuf);
    float mu = sum * (1.f / D_);
    float rstd = rsqrtf(sq * (1.f / D_) - mu * mu + 1e-5f);
    #pragma unroll
    for (int j = 0; j < 3; j++) {
        int d = tid + 256 * j;
        h[(size_t)row * D_ + d] = (v[j] - mu) * rstd * ln_w[d] + ln_b[d];
    }
}

__global__ __launch_bounds__(256) void rmsnorm_bf_kernel(const float* __restrict__ h,
                                                         const float* __restrict__ w,
                                                         bf16* __restrict__ out) {
    int row = blockIdx.x, tid = threadIdx.x;
    __shared__ float sbuf[8];
    float v[3], ss = 0.f, dummy = 0.f;
    #pragma unroll
    for (int j = 0; j < 3; j++) {
        v[j] = h[(size_t)row * D_ + tid + 256 * j];
        ss += v[j] * v[j];
    }
    block_reduce2_(ss, dummy, sbuf);
    float rstd = rsqrtf(ss * (1.f / D_) + 1e-5f);
    #pragma unroll
    for (int j = 0; j < 3; j++) {
        int d = tid + 256 * j;
        out[(size_t)row * D_ + d] = (bf16)(v[j] * rstd * w[d]);
    }
}

// conv K=4 + silu -> xc (2 channels/thread) ; gate packs -> scanw[.y]
__global__ __launch_bounds__(256) void conv_silu_kernel(const bf16* __restrict__ xzb,
                                                        const float* __restrict__ cw,
                                                        const float* __restrict__ cb,
                                                        const float* __restrict__ Dp,
                                                        bf16* __restrict__ xcb,
                                                        unsigned* __restrict__ scanw) {
    size_t idx = (size_t)blockIdx.x * 256 + threadIdx.x;   // CROWS_*DI_/2
    int d2 = (int)(idx % (DI_ / 2));
    size_t row = idx / (DI_ / 2);
    int t = (int)(row % L_);
    int d = d2 * 2;
    const unsigned* xz32 = (const unsigned*)xzb;           // uint = bf16 pair; row stride DI_
    size_t base = row * DI_ + d2;
    unsigned p0  = xz32[base];
    unsigned pm1 = (t >= 1) ? xz32[base - DI_]     : 0u;
    unsigned pm2 = (t >= 2) ? xz32[base - 2 * DI_] : 0u;
    unsigned pm3 = (t >= 3) ? xz32[base - 3 * DI_] : 0u;
    unsigned pz  = xz32[row * DI_ + DI_ / 2 + d2];

    bf16x2 v0  = __builtin_bit_cast(bf16x2, p0);
    bf16x2 v1  = __builtin_bit_cast(bf16x2, pm1);
    bf16x2 v2  = __builtin_bit_cast(bf16x2, pm2);
    bf16x2 v3  = __builtin_bit_cast(bf16x2, pm3);
    bf16x2 vz  = __builtin_bit_cast(bf16x2, pz);

    float4 wa = ((const float4*)cw)[d];
    float4 wb = ((const float4*)cw)[d + 1];
    float2 cbv = ((const float2*)cb)[d2];
    float2 Dv  = ((const float2*)Dp)[d2];

    float acca = cbv.x + wa.x * (float)v3.x + wa.y * (float)v2.x + wa.z * (float)v1.x + wa.w * (float)v0.x;
    float accb = cbv.y + wb.x * (float)v3.y + wb.y * (float)v2.y + wb.z * (float)v1.y + wb.w * (float)v0.y;
    float ua = silu_(acca), ub = silu_(accb);
    ((unsigned*)xcb)[row * (DI_ / 2) + d2] = pack_bf2_(ua, ub);
    float gza = silu_((float)vz.x), gzb = silu_((float)vz.y);
    size_t sbase = 2 * (row * DI_ + d);
    scanw[sbase + 1] = pack_bf2_(Dv.x * ua * gza, gza);
    scanw[sbase + 3] = pack_bf2_(Dv.y * ub * gzb, gzb);
}

// ============== single-pass scan: LDS staging for scanw, register dbuf for bc ==============
__global__ __launch_bounds__(256) void scan_lds_kernel(const float2* __restrict__ bcp,
                                                       const uint2* __restrict__ scanin,
                                                       const float* __restrict__ A_log,
                                                       bf16* __restrict__ yb) {
    __shared__ uint2 lsw[2][TCH_][16];
    const int tid = threadIdx.x;
    const int n = tid & 15, dl = tid >> 4;
    const int d = blockIdx.x * 16 + dl;
    const int b = blockIdx.y;
    const float AvL = -__expf(A_log[(size_t)d * N_ + n]) * 1.44269504f;
    const size_t seqbase = (size_t)b * L_;
    const int d0 = blockIdx.x * 16;
    const float2* pBC = bcp + seqbase * 16 + n;

    uint2 swr[4];
    #define GLOAD(c)                                                        \
        {                                                                   \
            size_t rb = seqbase + (size_t)(c) * TCH_;                       \
            _Pragma("unroll")                                               \
            for (int i = 0; i < 4; i++) {                                   \
                int t = i * 16 + dl;                                        \
                swr[i] = scanin[(rb + t) * DI_ + d0 + n];                   \
            }                                                               \
        }
    #define DSWRITE(p)                                                      \
        {                                                                   \
            _Pragma("unroll")                                               \
            for (int i = 0; i < 4; i++) {                                   \
                int t = i * 16 + dl;                                        \
                lsw[p][t][n] = swr[i];                                      \
            }                                                               \
        }

    float2 bcb[2][8];
    #pragma unroll
    for (int u = 0; u < 8; u++) bcb[0][u] = pBC[(size_t)u * 16];

    GLOAD(0);
    DSWRITE(0);
    __syncthreads();
    GLOAD(1);

    float h = 0.f;
    for (int c = 0; c < NCHT_; c++) {
        int p = c & 1;
        bf16* py = yb + (seqbase + (size_t)c * TCH_) * DI_ + d;
        #pragma unroll
        for (int g = 0; g < 8; g++) {
            int G = c * 8 + g;
            if (G + 1 < 64) {
                #pragma unroll
                for (int u = 0; u < 8; u++)
                    bcb[(G + 1) & 1][u] = pBC[((size_t)(G + 1) * 8 + u) * 16];
            }
            #pragma unroll
            for (int u = 0; u < 8; u++) {
                int t = g * 8 + u;
                uint2 iv = lsw[p][t][dl];
                float2 bcv = bcb[G & 1][u];
                bf16x2 dv = __builtin_bit_cast(bf16x2, iv.x);
                float du = (float)dv.x, dtv = (float)dv.y;
                float dA = __builtin_amdgcn_exp2f(dtv * AvL);
                h = dA * h + du * bcv.x;
                float pq = h * bcv.y;
                pq = dpp_add_<0xB1>(pq);
                pq = dpp_add_<0x4E>(pq);
                pq = dpp_add_<0x124>(pq);
                pq = dpp_add_<0x128>(pq);
                if (n == 0) {
                    bf16x2 og = __builtin_bit_cast(bf16x2, iv.y);
                    py[(size_t)t * DI_] = (bf16)(pq * (float)og.y + (float)og.x);
                }
            }
        }
        if (c + 1 < NCHT_) {
            DSWRITE(p ^ 1);
            __syncthreads();
            if (c + 2 < NCHT_) GLOAD(c + 2);
        }
    }
    #undef GLOAD
    #undef DSWRITE
}

extern "C" void kernel_launch(void* const* d_in, const int* in_sizes, int n_in,
                              void* d_out, int out_size, void* d_ws, size_t ws_size,
                              hipStream_t stream) {
    const float* x        = (const float*)d_in[0];
    const float* stat     = (const float*)d_in[1];
    const int*   mask     = (const int*)d_in[3];
    const float* emb_w    = (const float*)d_in[5];
    const float* emb_b    = (const float*)d_in[6];
    const float* static_w = (const float*)d_in[7];
    const float* static_b = (const float*)d_in[8];
    const float* ln_w     = (const float*)d_in[9];
    const float* ln_b     = (const float*)d_in[10];
    const float* norm_w   = (const float*)d_in[11];
    const float* in_proj_w  = (const float*)d_in[12];
    const float* conv_w   = (const float*)d_in[13];
    const float* conv_b   = (const float*)d_in[14];
    const float* x_proj_w = (const float*)d_in[15];
    const float* dt_proj_w= (const float*)d_in[16];
    const float* dt_proj_b= (const float*)d_in[17];
    const float* A_log    = (const float*)d_in[18];
    const float* D_param  = (const float*)d_in[19];
    const float* out_proj_w = (const float*)d_in[20];
    const float* norm_f_w = (const float*)d_in[21];
    const float* lm_head_w= (const float*)d_in[22];
    float* out = (float*)d_out;

    // ---- workspace layout (bytes), total ~209 MB ----
    char* p = (char*)d_ws;
    float*    h      = (float*)p;         p += (size_t)ROWS_ * D_ * 4;          // 50.3 MB
    bf16*     hn_bf  = (bf16*)p;          p += (size_t)CROWS_ * D_ * 2;         // 6.3
    char*     xz_region = p;                                                    // h_pre alias start
    bf16*     xz_bf  = (bf16*)p;          p += (size_t)CROWS_ * 2 * DI_ * 2;    // 25.2
    bf16*     xc_bf  = (bf16*)p;          p += (size_t)CROWS_ * DI_ * 2;        // 12.6
    unsigned* scanw  = (unsigned*)p;      p += (size_t)CROWS_ * DI_ * 8;        // 50.3 (uint2)
    float*    bc     = (float*)p;         p += (size_t)CROWS_ * 32 * 4;         // 0.5
    bf16*     dtr_bf = (bf16*)p;          p += (size_t)CROWS_ * 64 * 2;         // 0.5
    bf16*     y_bf   = (bf16*)p;          p += (size_t)ROWS_ * DI_ * 2;         // 50.3 (FULL batch)
    bf16*     inw_l  = (bf16*)p;          p += (size_t)2 * DI_ * D_ * 2;        // 4.7 (per-layer)
    bf16*     outw_l = (bf16*)p;          p += (size_t)D_ * DI_ * 2;            // 2.4 (per-layer)
    bf16*     xpwp_bf= (bf16*)p;          p += (size_t)NL_ * 128 * DI_ * 2;     // 1.6
    bf16*     dtwp_bf= (bf16*)p;          p += (size_t)NL_ * DI_ * 64 * 2;      // 0.8
    bf16*     lmw_bf = (bf16*)p;          p += (size_t)128 * D_ * 2;
    bf16*     embw_bf= (bf16*)p;          p += (size_t)D_ * KE_ * 2;
    bf16*     feats  = (bf16*)p;          p += (size_t)ROWS_ * KE_ * 2;         // 3.1
    float*    sstat  = (float*)p;         p += (size_t)B_ * D_ * 4;
    float*    h_pre  = (float*)xz_region; // 50.3 MB alias over xz/xc/scanw (dead then)

    // ---- weight prep ----
    pad_lm_kernel<<<(128 * D_) / 256, 256, 0, stream>>>(lm_head_w, lmw_bf);
    pad_embw_kernel<<<(D_ * KE_) / 256, 256, 0, stream>>>(emb_w, embw_bf);
    feats_kernel<<<(ROWS_ * KE_) / 256, 256, 0, stream>>>(x, mask, feats);
    dim3 gxp((128 * DI_) / 256, NL_);
    xpw_pad_kernel<<<gxp, 256, 0, stream>>>(x_proj_w, xpwp_bf);
    dim3 gdt((DI_ * 64) / 256, NL_);
    dtw_pad_kernel<<<gdt, 256, 0, stream>>>(dt_proj_w, dtwp_bf);
    sstat_kernel<<<(B_ * D_) / 256, 256, 0, stream>>>(stat, static_w, static_b, emb_b, sstat);

    // ---- embed + LN ----
    dim3 ge(D_ / 128, ROWS_ / 128);
    gemm_mfma<0><<<ge, 256, 0, stream>>>(feats, embw_bf, nullptr, h_pre, D_, KE_,
                                         nullptr, nullptr, nullptr, nullptr, nullptr);
    ln_embed_kernel<<<ROWS_, 256, 0, stream>>>(h_pre, sstat, ln_w, ln_b, h);

    // ---- layers ----
    for (int l = 0; l < NL_; l++) {
        // per-layer weight casts (saves workspace vs all-layer buffers)
        cast_f2b_kernel<<<(2 * DI_ * D_) / 256, 256, 0, stream>>>(
            in_proj_w + (size_t)l * 2 * DI_ * D_, inw_l);
        cast_f2b_kernel<<<(D_ * DI_) / 256, 256, 0, stream>>>(
            out_proj_w + (size_t)l * D_ * DI_, outw_l);

        for (int c = 0; c < NCH_; c++) {
            float* hc = h + (size_t)c * CROWS_ * D_;

            rmsnorm_bf_kernel<<<CROWS_, 256, 0, stream>>>(hc, norm_w + (size_t)l * D_, hn_bf);

            dim3 g1((2 * DI_) / 128, CROWS_ / 128);
            gemm_mfma<1><<<g1, 256, 0, stream>>>(hn_bf, inw_l,
                                                 nullptr, xz_bf, 2 * DI_, D_,
                                                 nullptr, nullptr, nullptr, nullptr, nullptr);

            conv_silu_kernel<<<(CROWS_ * DI_ / 2) / 256, 256, 0, stream>>>(
                xz_bf, conv_w + (size_t)l * DI_ * 4, conv_b + (size_t)l * DI_,
                D_param + (size_t)l * DI_, xc_bf, scanw);

            dim3 g2a(1, CROWS_ / 128);
            gemm_mfma<3><<<g2a, 256, 0, stream>>>(xc_bf, xpwp_bf + (size_t)l * 128 * DI_,
                                                  nullptr, nullptr, 0, DI_,
                                                  nullptr, nullptr, bc, nullptr, dtr_bf);

            dim3 g2b(DI_ / 128, CROWS_ / 128);
            gemm_mfma<2><<<g2b, 256, 0, stream>>>(dtr_bf, dtwp_bf + (size_t)l * DI_ * 64,
                                                  nullptr, nullptr, 0, 64,
                                                  dt_proj_b + (size_t)l * DI_, scanw,
                                                  nullptr, xc_bf, nullptr);

            dim3 gs(DI_ / 16, CB_);
            scan_lds_kernel<<<gs, 256, 0, stream>>>((const float2*)bc, (const uint2*)scanw,
                                                    A_log + (size_t)l * DI_ * N_,
                                                    y_bf + (size_t)c * CROWS_ * DI_);
        }

        // full-batch out_proj: h += y @ outw^T  (768 blocks)
        dim3 g3(D_ / 128, ROWS_ / 128);
        gemm_mfma<0><<<g3, 256, 0, stream>>>(y_bf, outw_l,
                                             h, h, D_, DI_,
                                             nullptr, nullptr, nullptr, nullptr, nullptr);
    }

    // ---- final rmsnorm + lm_head ----
    for (int c = 0; c < NCH_; c++) {
        float* hc = h + (size_t)c * CROWS_ * D_;
        rmsnorm_bf_kernel<<<CROWS_, 256, 0, stream>>>(hc, norm_f_w, hn_bf);
        dim3 glm(1, CROWS_ / 128);
        gemm_mfma<0><<<glm, 256, 0, stream>>>(hn_bf, lmw_bf, nullptr,
                                              out + (size_t)c * CROWS_ * V_, V_, D_,
                                              nullptr, nullptr, nullptr, nullptr, nullptr);
    }
}

// Round 13
// 3288.041 us; speedup vs baseline: 1.8879x; 1.1764x over previous
//
#include <hip/hip_runtime.h>
#include <math.h>

#define B_ 32
#define L_ 512
#define S_ 37
#define STATIC_ 8
#define D_ 768
#define DI_ 1536
#define N_ 16
#define DTR_ 48
#define NL_ 4
#define V_ 32
#define ROWS_ (B_*L_)      // 16384
#define CB_ 8              // batch chunk
#define CROWS_ (CB_*L_)    // 4096
#define NCH_ (B_/CB_)      // 4
#define KE_ 96             // padded embed K (74 -> 96)
#define TCH_ 64            // scan LDS chunk (timesteps)
#define NCHT_ (L_/TCH_)    // 8 chunks
#define KS_ 4              // xproj split-K slices
#define KSL_ (DI_/KS_)     // 384

typedef __bf16 bf16;
typedef __bf16 bf16x8 __attribute__((ext_vector_type(8)));
typedef __bf16 bf16x2 __attribute__((ext_vector_type(2)));
typedef float f32x4 __attribute__((ext_vector_type(4)));

typedef __attribute__((address_space(3))) void lds_void;
typedef __attribute__((address_space(1))) const void gmem_void;

__device__ __forceinline__ void gld16(const void* g, void* l) {
    __builtin_amdgcn_global_load_lds((gmem_void*)g, (lds_void*)l, 16, 0, 0);
}

__device__ __forceinline__ float silu_(float x) { return x / (1.f + __expf(-x)); }
__device__ __forceinline__ float softplus_(float x) {
    return fmaxf(x, 0.f) + __logf(1.f + __expf(-fabsf(x)));
}
__device__ __forceinline__ unsigned pack_bf2_(float a, float b) {
    bf16x2 v{(bf16)a, (bf16)b};
    return __builtin_bit_cast(unsigned, v);
}
template<int CTRL>
__device__ __forceinline__ float dpp_add_(float p) {
    int vi = __builtin_amdgcn_update_dpp(0, __builtin_bit_cast(int, p),
                                         CTRL, 0xF, 0xF, true);
    return p + __builtin_bit_cast(float, vi);
}

// ================= bf16 MFMA GEMM: C[M,*] = A[M,K] @ W[Nalloc,K]^T =================
// MODE 0: f32 out (+addsrc), stride Nstore
// MODE 1: bf16 out, stride Nstore
// MODE 2: dt epilogue: dtv=softplus(v+dt_bias[n]); u=uref[m*DI_+n]; scanw[2*(m*DI_+n)]=pack(du,dtv)
// MODE 4: split-K partial: blockIdx.x = K-slice; n0=0; n<96 -> pbuf[ks][m][n] = v (f32)
template<int MODE>
__global__ __launch_bounds__(256) void gemm_mfma(
    const bf16* __restrict__ A, const bf16* __restrict__ W,
    const float* __restrict__ addsrc, void* __restrict__ Cv,
    int Nstore, int K,
    const float* __restrict__ dt_bias, unsigned* __restrict__ scanw,
    float* __restrict__ pbuf, const bf16* __restrict__ uref)
{
    __shared__ bf16 As[128 * 32];
    __shared__ bf16 Bs[128 * 32];
    const int tid = threadIdx.x;
    const int m0 = blockIdx.y * 128;
    const int n0 = (MODE == 4) ? 0 : blockIdx.x * 128;
    const int kbeg = (MODE == 4) ? blockIdx.x * KSL_ : 0;
    const int kend = (MODE == 4) ? kbeg + KSL_ : K;

    f32x4 acc[4][4];
    #pragma unroll
    for (int i = 0; i < 4; i++)
        #pragma unroll
        for (int j = 0; j < 4; j++)
            acc[i][j] = f32x4{0.f, 0.f, 0.f, 0.f};

    const int srow = tid >> 2, spart = tid & 3;
    const bf16* ag = A + (size_t)(m0 + srow) * K + spart * 8;
    const bf16* wg = W + (size_t)(n0 + srow) * K + spart * 8;
    char* lA = (char*)As + tid * 16;
    char* lB = (char*)Bs + tid * 16;

    const int lane = tid & 63, wv = tid >> 6;
    const int wr = wv >> 1, wc = wv & 1;
    const int colL = lane & 15, quad = lane >> 4;
    const bf16* aRd = As + (wr * 64 + colL) * 32 + quad * 8;
    const bf16* bRd = Bs + (wc * 64 + colL) * 32 + quad * 8;

    for (int kt = kbeg; kt < kend; kt += 32) {
        gld16(ag + kt, lA);
        gld16(ag + kt + (size_t)64 * K, lA + 4096);
        gld16(wg + kt, lB);
        gld16(wg + kt + (size_t)64 * K, lB + 4096);
        __syncthreads();
        bf16x8 fa[4], fb[4];
        #pragma unroll
        for (int i = 0; i < 4; i++) fa[i] = *(const bf16x8*)(aRd + i * 16 * 32);
        #pragma unroll
        for (int j = 0; j < 4; j++) fb[j] = *(const bf16x8*)(bRd + j * 16 * 32);
        #pragma unroll
        for (int i = 0; i < 4; i++)
            #pragma unroll
            for (int j = 0; j < 4; j++)
                acc[i][j] = __builtin_amdgcn_mfma_f32_16x16x32_bf16(fa[i], fb[j], acc[i][j], 0, 0, 0);
        __syncthreads();
    }

    float* Cf = (float*)Cv;
    bf16*  Cb = (bf16*)Cv;
    #pragma unroll
    for (int i = 0; i < 4; i++) {
        #pragma unroll
        for (int j = 0; j < 4; j++) {
            int n = n0 + wc * 64 + j * 16 + colL;
            #pragma unroll
            for (int r = 0; r < 4; r++) {
                int m = m0 + wr * 64 + i * 16 + quad * 4 + r;
                float v = acc[i][j][r];
                if (MODE == 2) {
                    float dtv = softplus_(v + dt_bias[n]);
                    float u = (float)uref[(size_t)m * DI_ + n];
                    scanw[2 * ((size_t)m * DI_ + n)] = pack_bf2_(dtv * u, dtv);
                } else if (MODE == 4) {
                    if (n < 96)
                        pbuf[((size_t)blockIdx.x * CROWS_ + m) * 96 + n] = v;
                } else if (n < Nstore) {
                    if (addsrc) v += addsrc[(size_t)m * Nstore + n];
                    if (MODE == 1) Cb[(size_t)m * Nstore + n] = (bf16)v;
                    else           Cf[(size_t)m * Nstore + n] = v;
                }
            }
        }
    }
}

// reduce split-K partials -> dtr (bf16) + bc (interleaved f32)
__global__ __launch_bounds__(256) void xpost_kernel(const float* __restrict__ pbuf,
                                                    bf16* __restrict__ dtr,
                                                    float* __restrict__ bc) {
    int idx = blockIdx.x * 256 + threadIdx.x;   // CROWS_*96
    int m = idx / 96, j = idx % 96;
    float s = pbuf[idx];
    #pragma unroll
    for (int k = 1; k < KS_; k++) s += pbuf[(size_t)k * CROWS_ * 96 + idx];
    if (j < 64) {
        dtr[(size_t)m * 64 + j] = (bf16)s;
    } else {
        int jj = j - 64;
        int pos = (jj < 16) ? (2 * jj) : (2 * (jj - 16) + 1);
        bc[(size_t)m * 32 + pos] = s;
    }
}

// ================= small prep kernels =================
__global__ __launch_bounds__(256) void cast_f2b_kernel(const float* __restrict__ s,
                                                       bf16* __restrict__ d) {
    size_t i = (size_t)blockIdx.x * 256 + threadIdx.x;
    d[i] = (bf16)s[i];
}

__global__ __launch_bounds__(256) void pad_lm_kernel(const float* __restrict__ s, bf16* __restrict__ d) {
    int i = blockIdx.x * 256 + threadIdx.x;     // 128*768
    int row = i / D_;
    d[i] = (row < V_) ? (bf16)s[i] : (bf16)0.f;
}

__global__ __launch_bounds__(256) void pad_embw_kernel(const float* __restrict__ s, bf16* __restrict__ d) {
    int i = blockIdx.x * 256 + threadIdx.x;     // 768*96
    int row = i / KE_, col = i % KE_;
    d[i] = (col < 2 * S_) ? (bf16)s[row * 2 * S_ + col] : (bf16)0.f;
}

__global__ __launch_bounds__(256) void feats_kernel(const float* __restrict__ x,
                                                    const int* __restrict__ mask,
                                                    bf16* __restrict__ d) {
    size_t i = (size_t)blockIdx.x * 256 + threadIdx.x;  // ROWS_*96
    size_t row = i / KE_;
    int col = (int)(i % KE_);
    float v = 0.f;
    if (col < S_) v = x[row * S_ + col];
    else if (col < 2 * S_) v = (float)mask[row * S_ + (col - S_)];
    d[i] = (bf16)v;
}

// x_proj padded+remapped: (NL,128,1536) rows: 0..47=dt_r, 48..63=0, 64..95=B|C, 96..127=0
__global__ __launch_bounds__(256) void xpw_pad_kernel(const float* __restrict__ xpw,
                                                      bf16* __restrict__ d) {
    int l = blockIdx.y;
    int idx = blockIdx.x * 256 + threadIdx.x;   // 128*1536
    int row = idx / DI_, col = idx % DI_;
    float v = 0.f;
    if (row < DTR_) v = xpw[((size_t)l * (DTR_ + 2 * N_) + row) * DI_ + col];
    else if (row >= 64 && row < 96) v = xpw[((size_t)l * (DTR_ + 2 * N_) + row - 16) * DI_ + col];
    d[(size_t)l * 128 * DI_ + idx] = (bf16)v;
}

// dt_proj_w padded: (NL,1536,64), cols 48..63 = 0
__global__ __launch_bounds__(256) void dtw_pad_kernel(const float* __restrict__ dtw,
                                                      bf16* __restrict__ d) {
    int l = blockIdx.y;
    int idx = blockIdx.x * 256 + threadIdx.x;   // 1536*64
    int row = idx / 64, c = idx % 64;
    float v = (c < DTR_) ? dtw[((size_t)l * DI_ + row) * DTR_ + c] : 0.f;
    d[(size_t)l * DI_ * 64 + idx] = (bf16)v;
}

__global__ __launch_bounds__(256) void sstat_kernel(const float* __restrict__ stat,
                                                    const float* __restrict__ static_w,
                                                    const float* __restrict__ static_b,
                                                    const float* __restrict__ emb_b,
                                                    float* __restrict__ sstat) {
    int i = blockIdx.x * 256 + threadIdx.x;  // B_*D_
    int d = i % D_, b = i / D_;
    float acc = emb_b[d] + static_b[d];
    const float* sw = static_w + (size_t)d * STATIC_;
    const float* sv = stat + (size_t)b * STATIC_;
    #pragma unroll
    for (int s = 0; s < STATIC_; s++) acc += sv[s] * sw[s];
    sstat[i] = acc;
}

__device__ __forceinline__ void block_reduce2_(float& a, float& b, float* sbuf) {
    #pragma unroll
    for (int off = 32; off > 0; off >>= 1) {
        a += __shfl_down(a, off, 64);
        b += __shfl_down(b, off, 64);
    }
    int lane = threadIdx.x & 63, wid = threadIdx.x >> 6;
    if (lane == 0) { sbuf[wid] = a; sbuf[4 + wid] = b; }
    __syncthreads();
    a = sbuf[0] + sbuf[1] + sbuf[2] + sbuf[3];
    b = sbuf[4] + sbuf[5] + sbuf[6] + sbuf[7];
}

__global__ __launch_bounds__(256) void ln_embed_kernel(const float* __restrict__ h_pre,
                                                       const float* __restrict__ sstat,
                                                       const float* __restrict__ ln_w,
                                                       const float* __restrict__ ln_b,
                                                       float* __restrict__ h) {
    int row = blockIdx.x, b = row / L_, tid = threadIdx.x;
    __shared__ float sbuf[8];
    float v[3], sum = 0.f, sq = 0.f;
    #pragma unroll
    for (int j = 0; j < 3; j++) {
        int d = tid + 256 * j;
        v[j] = h_pre[(size_t)row * D_ + d] + sstat[b * D_ + d];
        sum += v[j]; sq += v[j] * v[j];
    }
    block_reduce2_(sum, sq, sbuf);
    float mu = sum * (1.f / D_);
    float rstd = rsqrtf(sq * (1.f / D_) - mu * mu + 1e-5f);
    #pragma unroll
    for (int j = 0; j < 3; j++) {
        int d = tid + 256 * j;
        h[(size_t)row * D_ + d] = (v[j] - mu) * rstd * ln_w[d] + ln_b[d];
    }
}

__global__ __launch_bounds__(256) void rmsnorm_bf_kernel(const float* __restrict__ h,
                                                         const float* __restrict__ w,
                                                         bf16* __restrict__ out) {
    int row = blockIdx.x, tid = threadIdx.x;
    __shared__ float sbuf[8];
    float v[3], ss = 0.f, dummy = 0.f;
    #pragma unroll
    for (int j = 0; j < 3; j++) {
        v[j] = h[(size_t)row * D_ + tid + 256 * j];
        ss += v[j] * v[j];
    }
    block_reduce2_(ss, dummy, sbuf);
    float rstd = rsqrtf(ss * (1.f / D_) + 1e-5f);
    #pragma unroll
    for (int j = 0; j < 3; j++) {
        int d = tid + 256 * j;
        out[(size_t)row * D_ + d] = (bf16)(v[j] * rstd * w[d]);
    }
}

// conv K=4 + silu -> xc (2 channels/thread) ; gate packs -> scanw[.y]
__global__ __launch_bounds__(256) void conv_silu_kernel(const bf16* __restrict__ xzb,
                                                        const float* __restrict__ cw,
                                                        const float* __restrict__ cb,
                                                        const float* __restrict__ Dp,
                                                        bf16* __restrict__ xcb,
                                                        unsigned* __restrict__ scanw) {
    size_t idx = (size_t)blockIdx.x * 256 + threadIdx.x;   // CROWS_*DI_/2
    int d2 = (int)(idx % (DI_ / 2));
    size_t row = idx / (DI_ / 2);
    int t = (int)(row % L_);
    int d = d2 * 2;
    const unsigned* xz32 = (const unsigned*)xzb;           // uint = bf16 pair; row stride DI_
    size_t base = row * DI_ + d2;
    unsigned p0  = xz32[base];
    unsigned pm1 = (t >= 1) ? xz32[base - DI_]     : 0u;
    unsigned pm2 = (t >= 2) ? xz32[base - 2 * DI_] : 0u;
    unsigned pm3 = (t >= 3) ? xz32[base - 3 * DI_] : 0u;
    unsigned pz  = xz32[row * DI_ + DI_ / 2 + d2];

    bf16x2 v0  = __builtin_bit_cast(bf16x2, p0);
    bf16x2 v1  = __builtin_bit_cast(bf16x2, pm1);
    bf16x2 v2  = __builtin_bit_cast(bf16x2, pm2);
    bf16x2 v3  = __builtin_bit_cast(bf16x2, pm3);
    bf16x2 vz  = __builtin_bit_cast(bf16x2, pz);

    float4 wa = ((const float4*)cw)[d];
    float4 wb = ((const float4*)cw)[d + 1];
    float2 cbv = ((const float2*)cb)[d2];
    float2 Dv  = ((const float2*)Dp)[d2];

    float acca = cbv.x + wa.x * (float)v3.x + wa.y * (float)v2.x + wa.z * (float)v1.x + wa.w * (float)v0.x;
    float accb = cbv.y + wb.x * (float)v3.y + wb.y * (float)v2.y + wb.z * (float)v1.y + wb.w * (float)v0.y;
    float ua = silu_(acca), ub = silu_(accb);
    ((unsigned*)xcb)[row * (DI_ / 2) + d2] = pack_bf2_(ua, ub);
    float gza = silu_((float)vz.x), gzb = silu_((float)vz.y);
    size_t sbase = 2 * (row * DI_ + d);
    scanw[sbase + 1] = pack_bf2_(Dv.x * ua * gza, gza);
    scanw[sbase + 3] = pack_bf2_(Dv.y * ub * gzb, gzb);
}

// ============== single-pass scan with LDS double-buffered staging (r11 version) ==============
__global__ __launch_bounds__(256) void scan_lds_kernel(const float2* __restrict__ bcp,
                                                       const uint2* __restrict__ scanin,
                                                       const float* __restrict__ A_log,
                                                       bf16* __restrict__ yb) {
    __shared__ uint2  lsw[2][TCH_][16];
    __shared__ float2 lbc[2][TCH_][16];
    const int tid = threadIdx.x;
    const int n = tid & 15, dl = tid >> 4;
    const int d = blockIdx.x * 16 + dl;
    const int b = blockIdx.y;
    const float AvL = -__expf(A_log[(size_t)d * N_ + n]) * 1.44269504f;
    const size_t seqbase = (size_t)b * L_;
    const int d0 = blockIdx.x * 16;

    uint2  swr[4];
    float2 bcr[4];

    #define GLOAD(c)                                                        \
        {                                                                   \
            size_t rb = seqbase + (size_t)(c) * TCH_;                       \
            _Pragma("unroll")                                               \
            for (int i = 0; i < 4; i++) {                                   \
                int t = i * 16 + dl;                                        \
                swr[i] = scanin[(rb + t) * DI_ + d0 + n];                   \
                bcr[i] = bcp[(rb + t) * 16 + n];                            \
            }                                                               \
        }
    #define DSWRITE(p)                                                      \
        {                                                                   \
            _Pragma("unroll")                                               \
            for (int i = 0; i < 4; i++) {                                   \
                int t = i * 16 + dl;                                        \
                lsw[p][t][n] = swr[i];                                      \
                lbc[p][t][n] = bcr[i];                                      \
            }                                                               \
        }

    GLOAD(0);
    DSWRITE(0);
    __syncthreads();
    GLOAD(1);

    float h = 0.f;
    for (int c = 0; c < NCHT_; c++) {
        int p = c & 1;
        bf16* py = yb + (seqbase + (size_t)c * TCH_) * DI_ + d;
        #pragma unroll 8
        for (int t = 0; t < TCH_; t++) {
            uint2 iv = lsw[p][t][dl];
            float2 bcv = lbc[p][t][n];
            bf16x2 dv = __builtin_bit_cast(bf16x2, iv.x);
            float du = (float)dv.x, dtv = (float)dv.y;
            float dA = __builtin_amdgcn_exp2f(dtv * AvL);
            h = dA * h + du * bcv.x;
            float pq = h * bcv.y;
            pq = dpp_add_<0xB1>(pq);
            pq = dpp_add_<0x4E>(pq);
            pq = dpp_add_<0x124>(pq);
            pq = dpp_add_<0x128>(pq);
            if (n == 0) {
                bf16x2 og = __builtin_bit_cast(bf16x2, iv.y);
                py[(size_t)t * DI_] = (bf16)(pq * (float)og.y + (float)og.x);
            }
        }
        if (c + 1 < NCHT_) {
            DSWRITE(p ^ 1);
            __syncthreads();
            if (c + 2 < NCHT_) GLOAD(c + 2);
        }
    }
    #undef GLOAD
    #undef DSWRITE
}

extern "C" void kernel_launch(void* const* d_in, const int* in_sizes, int n_in,
                              void* d_out, int out_size, void* d_ws, size_t ws_size,
                              hipStream_t stream) {
    const float* x        = (const float*)d_in[0];
    const float* stat     = (const float*)d_in[1];
    const int*   mask     = (const int*)d_in[3];
    const float* emb_w    = (const float*)d_in[5];
    const float* emb_b    = (const float*)d_in[6];
    const float* static_w = (const float*)d_in[7];
    const float* static_b = (const float*)d_in[8];
    const float* ln_w     = (const float*)d_in[9];
    const float* ln_b     = (const float*)d_in[10];
    const float* norm_w   = (const float*)d_in[11];
    const float* in_proj_w  = (const float*)d_in[12];
    const float* conv_w   = (const float*)d_in[13];
    const float* conv_b   = (const float*)d_in[14];
    const float* x_proj_w = (const float*)d_in[15];
    const float* dt_proj_w= (const float*)d_in[16];
    const float* dt_proj_b= (const float*)d_in[17];
    const float* A_log    = (const float*)d_in[18];
    const float* D_param  = (const float*)d_in[19];
    const float* out_proj_w = (const float*)d_in[20];
    const float* norm_f_w = (const float*)d_in[21];
    const float* lm_head_w= (const float*)d_in[22];
    float* out = (float*)d_out;

    // ---- workspace layout (bytes), total ~215 MB ----
    char* p = (char*)d_ws;
    float*    h      = (float*)p;         p += (size_t)ROWS_ * D_ * 4;          // 50.3 MB
    bf16*     hn_bf  = (bf16*)p;          p += (size_t)CROWS_ * D_ * 2;         // 6.3
    char*     xz_region = p;                                                    // h_pre alias start
    bf16*     xz_bf  = (bf16*)p;          p += (size_t)CROWS_ * 2 * DI_ * 2;    // 25.2
    bf16*     xc_bf  = (bf16*)p;          p += (size_t)CROWS_ * DI_ * 2;        // 12.6
    unsigned* scanw  = (unsigned*)p;      p += (size_t)CROWS_ * DI_ * 8;        // 50.3 (uint2)
    float*    bc     = (float*)p;         p += (size_t)CROWS_ * 32 * 4;         // 0.5
    bf16*     dtr_bf = (bf16*)p;          p += (size_t)CROWS_ * 64 * 2;         // 0.5
    float*    pbuf   = (float*)p;         p += (size_t)KS_ * CROWS_ * 96 * 4;   // 6.3
    bf16*     y_bf   = (bf16*)p;          p += (size_t)ROWS_ * DI_ * 2;         // 50.3 (FULL batch)
    bf16*     inw_l  = (bf16*)p;          p += (size_t)2 * DI_ * D_ * 2;        // 4.7 (per-layer)
    bf16*     outw_l = (bf16*)p;          p += (size_t)D_ * DI_ * 2;            // 2.4 (per-layer)
    bf16*     xpwp_bf= (bf16*)p;          p += (size_t)NL_ * 128 * DI_ * 2;     // 1.6
    bf16*     dtwp_bf= (bf16*)p;          p += (size_t)NL_ * DI_ * 64 * 2;      // 0.8
    bf16*     lmw_bf = (bf16*)p;          p += (size_t)128 * D_ * 2;
    bf16*     embw_bf= (bf16*)p;          p += (size_t)D_ * KE_ * 2;
    bf16*     feats  = (bf16*)p;          p += (size_t)ROWS_ * KE_ * 2;         // 3.1
    float*    sstat  = (float*)p;         p += (size_t)B_ * D_ * 4;
    float*    h_pre  = (float*)xz_region; // 50.3 MB alias over xz/xc/scanw (dead then)

    // ---- weight prep ----
    pad_lm_kernel<<<(128 * D_) / 256, 256, 0, stream>>>(lm_head_w, lmw_bf);
    pad_embw_kernel<<<(D_ * KE_) / 256, 256, 0, stream>>>(emb_w, embw_bf);
    feats_kernel<<<(ROWS_ * KE_) / 256, 256, 0, stream>>>(x, mask, feats);
    dim3 gxp((128 * DI_) / 256, NL_);
    xpw_pad_kernel<<<gxp, 256, 0, stream>>>(x_proj_w, xpwp_bf);
    dim3 gdt((DI_ * 64) / 256, NL_);
    dtw_pad_kernel<<<gdt, 256, 0, stream>>>(dt_proj_w, dtwp_bf);
    sstat_kernel<<<(B_ * D_) / 256, 256, 0, stream>>>(stat, static_w, static_b, emb_b, sstat);

    // ---- embed + LN ----
    dim3 ge(D_ / 128, ROWS_ / 128);
    gemm_mfma<0><<<ge, 256, 0, stream>>>(feats, embw_bf, nullptr, h_pre, D_, KE_,
                                         nullptr, nullptr, nullptr, nullptr);
    ln_embed_kernel<<<ROWS_, 256, 0, stream>>>(h_pre, sstat, ln_w, ln_b, h);

    // ---- layers ----
    for (int l = 0; l < NL_; l++) {
        cast_f2b_kernel<<<(2 * DI_ * D_) / 256, 256, 0, stream>>>(
            in_proj_w + (size_t)l * 2 * DI_ * D_, inw_l);
        cast_f2b_kernel<<<(D_ * DI_) / 256, 256, 0, stream>>>(
            out_proj_w + (size_t)l * D_ * DI_, outw_l);

        for (int c = 0; c < NCH_; c++) {
            float* hc = h + (size_t)c * CROWS_ * D_;

            rmsnorm_bf_kernel<<<CROWS_, 256, 0, stream>>>(hc, norm_w + (size_t)l * D_, hn_bf);

            dim3 g1((2 * DI_) / 128, CROWS_ / 128);
            gemm_mfma<1><<<g1, 256, 0, stream>>>(hn_bf, inw_l,
                                                 nullptr, xz_bf, 2 * DI_, D_,
                                                 nullptr, nullptr, nullptr, nullptr);

            conv_silu_kernel<<<(CROWS_ * DI_ / 2) / 256, 256, 0, stream>>>(
                xz_bf, conv_w + (size_t)l * DI_ * 4, conv_b + (size_t)l * DI_,
                D_param + (size_t)l * DI_, xc_bf, scanw);

            // x_proj split-K: partial f32 tiles, then reduce
            dim3 g2a(KS_, CROWS_ / 128);
            gemm_mfma<4><<<g2a, 256, 0, stream>>>(xc_bf, xpwp_bf + (size_t)l * 128 * DI_,
                                                  nullptr, nullptr, 0, DI_,
                                                  nullptr, nullptr, pbuf, nullptr);
            xpost_kernel<<<(CROWS_ * 96) / 256, 256, 0, stream>>>(pbuf, dtr_bf, bc);

            dim3 g2b(DI_ / 128, CROWS_ / 128);
            gemm_mfma<2><<<g2b, 256, 0, stream>>>(dtr_bf, dtwp_bf + (size_t)l * DI_ * 64,
                                                  nullptr, nullptr, 0, 64,
                                                  dt_proj_b + (size_t)l * DI_, scanw,
                                                  nullptr, xc_bf);

            dim3 gs(DI_ / 16, CB_);
            scan_lds_kernel<<<gs, 256, 0, stream>>>((const float2*)bc, (const uint2*)scanw,
                                                    A_log + (size_t)l * DI_ * N_,
                                                    y_bf + (size_t)c * CROWS_ * DI_);
        }

        // full-batch out_proj: h += y @ outw^T  (768 blocks)
        dim3 g3(D_ / 128, ROWS_ / 128);
        gemm_mfma<0><<<g3, 256, 0, stream>>>(y_bf, outw_l,
                                             h, h, D_, DI_,
                                             nullptr, nullptr, nullptr, nullptr);
    }

    // ---- final rmsnorm + lm_head ----
    for (int c = 0; c < NCH_; c++) {
        float* hc = h + (size_t)c * CROWS_ * D_;
        rmsnorm_bf_kernel<<<CROWS_, 256, 0, stream>>>(hc, norm_f_w, hn_bf);
        dim3 glm(1, CROWS_ / 128);
        gemm_mfma<0><<<glm, 256, 0, stream>>>(hn_bf, lmw_bf, nullptr,
                                              out + (size_t)c * CROWS_ * V_, V_, D_,
                                              nullptr, nullptr, nullptr, nullptr);
    }
}

// Round 14
// 3260.654 us; speedup vs baseline: 1.9037x; 1.0084x over previous
//
#include <hip/hip_runtime.h>
#include <math.h>

#define B_ 32
#define L_ 512
#define S_ 37
#define STATIC_ 8
#define D_ 768
#define DI_ 1536
#define N_ 16
#define DTR_ 48
#define NL_ 4
#define V_ 32
#define ROWS_ (B_*L_)      // 16384
#define CB_ 8              // batch chunk
#define CROWS_ (CB_*L_)    // 4096
#define NCH_ (B_/CB_)      // 4
#define KE_ 96             // padded embed K (74 -> 96)
#define TCH_ 64            // scan LDS chunk (timesteps)
#define NCHT_ (L_/TCH_)    // 8 chunks
#define KS_ 4              // xproj split-K slices
#define KSL_ (DI_/KS_)     // 384

typedef __bf16 bf16;
typedef __bf16 bf16x8 __attribute__((ext_vector_type(8)));
typedef __bf16 bf16x2 __attribute__((ext_vector_type(2)));
typedef float f32x4 __attribute__((ext_vector_type(4)));

typedef __attribute__((address_space(3))) void lds_void;
typedef __attribute__((address_space(1))) const void gmem_void;

__device__ __forceinline__ void gld16(const void* g, void* l) {
    __builtin_amdgcn_global_load_lds((gmem_void*)g, (lds_void*)l, 16, 0, 0);
}

__device__ __forceinline__ float silu_(float x) { return x / (1.f + __expf(-x)); }
__device__ __forceinline__ float softplus_(float x) {
    return fmaxf(x, 0.f) + __logf(1.f + __expf(-fabsf(x)));
}
__device__ __forceinline__ unsigned pack_bf2_(float a, float b) {
    bf16x2 v{(bf16)a, (bf16)b};
    return __builtin_bit_cast(unsigned, v);
}
template<int CTRL>
__device__ __forceinline__ float dpp_add_(float p) {
    int vi = __builtin_amdgcn_update_dpp(0, __builtin_bit_cast(int, p),
                                         CTRL, 0xF, 0xF, true);
    return p + __builtin_bit_cast(float, vi);
}

// ================= bf16 MFMA GEMM: C[M,*] = A[M,K] @ W[Nalloc,K]^T =================
// MODE 0: f32 out (+addsrc), stride Nstore   [1-D grid, XCD swizzle; ntn = n-tiles]
// MODE 1: bf16 out, stride Nstore            [1-D grid, XCD swizzle]
// MODE 2: dt epilogue (softplus+pack)        [1-D grid, XCD swizzle]
// MODE 4: split-K partial: blockIdx.x = K-slice, blockIdx.y = m-tile (2-D grid)
template<int MODE>
__global__ __launch_bounds__(256) void gemm_mfma(
    const bf16* __restrict__ A, const bf16* __restrict__ W,
    const float* __restrict__ addsrc, void* __restrict__ Cv,
    int Nstore, int K, int ntn,
    const float* __restrict__ dt_bias, unsigned* __restrict__ scanw,
    float* __restrict__ pbuf, const bf16* __restrict__ uref)
{
    __shared__ bf16 As[128 * 32];
    __shared__ bf16 Bs[128 * 32];
    const int tid = threadIdx.x;

    int m0, n0, kbeg, kend;
    if (MODE == 4) {
        m0 = blockIdx.y * 128; n0 = 0;
        kbeg = blockIdx.x * KSL_; kend = kbeg + KSL_;
    } else {
        // XCD-aware swizzle: same-A-tile blocks (same m_tile) -> same XCD, adjacent slots
        int bid = blockIdx.x;
        int xcd = bid & 7, slot = bid >> 3;
        int Mtiles = gridDim.x / ntn;
        int mband = Mtiles >> 3;                 // m-tiles per XCD
        int m_tile = xcd * mband + slot / ntn;
        int n_tile = slot % ntn;
        m0 = m_tile * 128; n0 = n_tile * 128;
        kbeg = 0; kend = K;
    }

    f32x4 acc[4][4];
    #pragma unroll
    for (int i = 0; i < 4; i++)
        #pragma unroll
        for (int j = 0; j < 4; j++)
            acc[i][j] = f32x4{0.f, 0.f, 0.f, 0.f};

    const int srow = tid >> 2, spart = tid & 3;
    const bf16* ag = A + (size_t)(m0 + srow) * K + spart * 8;
    const bf16* wg = W + (size_t)(n0 + srow) * K + spart * 8;
    char* lA = (char*)As + tid * 16;
    char* lB = (char*)Bs + tid * 16;

    const int lane = tid & 63, wv = tid >> 6;
    const int wr = wv >> 1, wc = wv & 1;
    const int colL = lane & 15, quad = lane >> 4;
    const bf16* aRd = As + (wr * 64 + colL) * 32 + quad * 8;
    const bf16* bRd = Bs + (wc * 64 + colL) * 32 + quad * 8;

    for (int kt = kbeg; kt < kend; kt += 32) {
        gld16(ag + kt, lA);
        gld16(ag + kt + (size_t)64 * K, lA + 4096);
        gld16(wg + kt, lB);
        gld16(wg + kt + (size_t)64 * K, lB + 4096);
        __syncthreads();
        bf16x8 fa[4], fb[4];
        #pragma unroll
        for (int i = 0; i < 4; i++) fa[i] = *(const bf16x8*)(aRd + i * 16 * 32);
        #pragma unroll
        for (int j = 0; j < 4; j++) fb[j] = *(const bf16x8*)(bRd + j * 16 * 32);
        #pragma unroll
        for (int i = 0; i < 4; i++)
            #pragma unroll
            for (int j = 0; j < 4; j++)
                acc[i][j] = __builtin_amdgcn_mfma_f32_16x16x32_bf16(fa[i], fb[j], acc[i][j], 0, 0, 0);
        __syncthreads();
    }

    float* Cf = (float*)Cv;
    bf16*  Cb = (bf16*)Cv;
    #pragma unroll
    for (int i = 0; i < 4; i++) {
        #pragma unroll
        for (int j = 0; j < 4; j++) {
            int n = n0 + wc * 64 + j * 16 + colL;
            #pragma unroll
            for (int r = 0; r < 4; r++) {
                int m = m0 + wr * 64 + i * 16 + quad * 4 + r;
                float v = acc[i][j][r];
                if (MODE == 2) {
                    float dtv = softplus_(v + dt_bias[n]);
                    float u = (float)uref[(size_t)m * DI_ + n];
                    scanw[2 * ((size_t)m * DI_ + n)] = pack_bf2_(dtv * u, dtv);
                } else if (MODE == 4) {
                    if (n < 96)
                        pbuf[((size_t)blockIdx.x * CROWS_ + m) * 96 + n] = v;
                } else if (n < Nstore) {
                    if (addsrc) v += addsrc[(size_t)m * Nstore + n];
                    if (MODE == 1) Cb[(size_t)m * Nstore + n] = (bf16)v;
                    else           Cf[(size_t)m * Nstore + n] = v;
                }
            }
        }
    }
}

// reduce split-K partials -> dtr (bf16) + bc (interleaved f32)
__global__ __launch_bounds__(256) void xpost_kernel(const float* __restrict__ pbuf,
                                                    bf16* __restrict__ dtr,
                                                    float* __restrict__ bc) {
    int idx = blockIdx.x * 256 + threadIdx.x;   // CROWS_*96
    int m = idx / 96, j = idx % 96;
    float s = pbuf[idx];
    #pragma unroll
    for (int k = 1; k < KS_; k++) s += pbuf[(size_t)k * CROWS_ * 96 + idx];
    if (j < 64) {
        dtr[(size_t)m * 64 + j] = (bf16)s;
    } else {
        int jj = j - 64;
        int pos = (jj < 16) ? (2 * jj) : (2 * (jj - 16) + 1);
        bc[(size_t)m * 32 + pos] = s;
    }
}

// ================= small prep kernels =================
__global__ __launch_bounds__(256) void cast_f2b_kernel(const float* __restrict__ s,
                                                       bf16* __restrict__ d) {
    size_t i = (size_t)blockIdx.x * 256 + threadIdx.x;
    d[i] = (bf16)s[i];
}

__global__ __launch_bounds__(256) void pad_lm_kernel(const float* __restrict__ s, bf16* __restrict__ d) {
    int i = blockIdx.x * 256 + threadIdx.x;     // 128*768
    int row = i / D_;
    d[i] = (row < V_) ? (bf16)s[i] : (bf16)0.f;
}

__global__ __launch_bounds__(256) void pad_embw_kernel(const float* __restrict__ s, bf16* __restrict__ d) {
    int i = blockIdx.x * 256 + threadIdx.x;     // 768*96
    int row = i / KE_, col = i % KE_;
    d[i] = (col < 2 * S_) ? (bf16)s[row * 2 * S_ + col] : (bf16)0.f;
}

__global__ __launch_bounds__(256) void feats_kernel(const float* __restrict__ x,
                                                    const int* __restrict__ mask,
                                                    bf16* __restrict__ d) {
    size_t i = (size_t)blockIdx.x * 256 + threadIdx.x;  // ROWS_*96
    size_t row = i / KE_;
    int col = (int)(i % KE_);
    float v = 0.f;
    if (col < S_) v = x[row * S_ + col];
    else if (col < 2 * S_) v = (float)mask[row * S_ + (col - S_)];
    d[i] = (bf16)v;
}

// x_proj padded+remapped: (NL,128,1536) rows: 0..47=dt_r, 48..63=0, 64..95=B|C, 96..127=0
__global__ __launch_bounds__(256) void xpw_pad_kernel(const float* __restrict__ xpw,
                                                      bf16* __restrict__ d) {
    int l = blockIdx.y;
    int idx = blockIdx.x * 256 + threadIdx.x;   // 128*1536
    int row = idx / DI_, col = idx % DI_;
    float v = 0.f;
    if (row < DTR_) v = xpw[((size_t)l * (DTR_ + 2 * N_) + row) * DI_ + col];
    else if (row >= 64 && row < 96) v = xpw[((size_t)l * (DTR_ + 2 * N_) + row - 16) * DI_ + col];
    d[(size_t)l * 128 * DI_ + idx] = (bf16)v;
}

// dt_proj_w padded: (NL,1536,64), cols 48..63 = 0
__global__ __launch_bounds__(256) void dtw_pad_kernel(const float* __restrict__ dtw,
                                                      bf16* __restrict__ d) {
    int l = blockIdx.y;
    int idx = blockIdx.x * 256 + threadIdx.x;   // 1536*64
    int row = idx / 64, c = idx % 64;
    float v = (c < DTR_) ? dtw[((size_t)l * DI_ + row) * DTR_ + c] : 0.f;
    d[(size_t)l * DI_ * 64 + idx] = (bf16)v;
}

__global__ __launch_bounds__(256) void sstat_kernel(const float* __restrict__ stat,
                                                    const float* __restrict__ static_w,
                                                    const float* __restrict__ static_b,
                                                    const float* __restrict__ emb_b,
                                                    float* __restrict__ sstat) {
    int i = blockIdx.x * 256 + threadIdx.x;  // B_*D_
    int d = i % D_, b = i / D_;
    float acc = emb_b[d] + static_b[d];
    const float* sw = static_w + (size_t)d * STATIC_;
    const float* sv = stat + (size_t)b * STATIC_;
    #pragma unroll
    for (int s = 0; s < STATIC_; s++) acc += sv[s] * sw[s];
    sstat[i] = acc;
}

__device__ __forceinline__ void block_reduce2_(float& a, float& b, float* sbuf) {
    #pragma unroll
    for (int off = 32; off > 0; off >>= 1) {
        a += __shfl_down(a, off, 64);
        b += __shfl_down(b, off, 64);
    }
    int lane = threadIdx.x & 63, wid = threadIdx.x >> 6;
    if (lane == 0) { sbuf[wid] = a; sbuf[4 + wid] = b; }
    __syncthreads();
    a = sbuf[0] + sbuf[1] + sbuf[2] + sbuf[3];
    b = sbuf[4] + sbuf[5] + sbuf[6] + sbuf[7];
}

__global__ __launch_bounds__(256) void ln_embed_kernel(const float* __restrict__ h_pre,
                                                       const float* __restrict__ sstat,
                                                       const float* __restrict__ ln_w,
                                                       const float* __restrict__ ln_b,
                                                       float* __restrict__ h) {
    int row = blockIdx.x, b = row / L_, tid = threadIdx.x;
    __shared__ float sbuf[8];
    float v[3], sum = 0.f, sq = 0.f;
    #pragma unroll
    for (int j = 0; j < 3; j++) {
        int d = tid + 256 * j;
        v[j] = h_pre[(size_t)row * D_ + d] + sstat[b * D_ + d];
        sum += v[j]; sq += v[j] * v[j];
    }
    block_reduce2_(sum, sq, sbuf);
    float mu = sum * (1.f / D_);
    float rstd = rsqrtf(sq * (1.f / D_) - mu * mu + 1e-5f);
    #pragma unroll
    for (int j = 0; j < 3; j++) {
        int d = tid + 256 * j;
        h[(size_t)row * D_ + d] = (v[j] - mu) * rstd * ln_w[d] + ln_b[d];
    }
}

__global__ __launch_bounds__(256) void rmsnorm_bf_kernel(const float* __restrict__ h,
                                                         const float* __restrict__ w,
                                                         bf16* __restrict__ out) {
    int row = blockIdx.x, tid = threadIdx.x;
    __shared__ float sbuf[8];
    float v[3], ss = 0.f, dummy = 0.f;
    #pragma unroll
    for (int j = 0; j < 3; j++) {
        v[j] = h[(size_t)row * D_ + tid + 256 * j];
        ss += v[j] * v[j];
    }
    block_reduce2_(ss, dummy, sbuf);
    float rstd = rsqrtf(ss * (1.f / D_) + 1e-5f);
    #pragma unroll
    for (int j = 0; j < 3; j++) {
        int d = tid + 256 * j;
        out[(size_t)row * D_ + d] = (bf16)(v[j] * rstd * w[d]);
    }
}

// conv K=4 + silu -> xc (2 channels/thread) ; gate packs -> scanw[.y]
__global__ __launch_bounds__(256) void conv_silu_kernel(const bf16* __restrict__ xzb,
                                                        const float* __restrict__ cw,
                                                        const float* __restrict__ cb,
                                                        const float* __restrict__ Dp,
                                                        bf16* __restrict__ xcb,
                                                        unsigned* __restrict__ scanw) {
    size_t idx = (size_t)blockIdx.x * 256 + threadIdx.x;   // CROWS_*DI_/2
    int d2 = (int)(idx % (DI_ / 2));
    size_t row = idx / (DI_ / 2);
    int t = (int)(row % L_);
    int d = d2 * 2;
    const unsigned* xz32 = (const unsigned*)xzb;           // uint = bf16 pair; row stride DI_
    size_t base = row * DI_ + d2;
    unsigned p0  = xz32[base];
    unsigned pm1 = (t >= 1) ? xz32[base - DI_]     : 0u;
    unsigned pm2 = (t >= 2) ? xz32[base - 2 * DI_] : 0u;
    unsigned pm3 = (t >= 3) ? xz32[base - 3 * DI_] : 0u;
    unsigned pz  = xz32[row * DI_ + DI_ / 2 + d2];

    bf16x2 v0  = __builtin_bit_cast(bf16x2, p0);
    bf16x2 v1  = __builtin_bit_cast(bf16x2, pm1);
    bf16x2 v2  = __builtin_bit_cast(bf16x2, pm2);
    bf16x2 v3  = __builtin_bit_cast(bf16x2, pm3);
    bf16x2 vz  = __builtin_bit_cast(bf16x2, pz);

    float4 wa = ((const float4*)cw)[d];
    float4 wb = ((const float4*)cw)[d + 1];
    float2 cbv = ((const float2*)cb)[d2];
    float2 Dv  = ((const float2*)Dp)[d2];

    float acca = cbv.x + wa.x * (float)v3.x + wa.y * (float)v2.x + wa.z * (float)v1.x + wa.w * (float)v0.x;
    float accb = cbv.y + wb.x * (float)v3.y + wb.y * (float)v2.y + wb.z * (float)v1.y + wb.w * (float)v0.y;
    float ua = silu_(acca), ub = silu_(accb);
    ((unsigned*)xcb)[row * (DI_ / 2) + d2] = pack_bf2_(ua, ub);
    float gza = silu_((float)vz.x), gzb = silu_((float)vz.y);
    size_t sbase = 2 * (row * DI_ + d);
    scanw[sbase + 1] = pack_bf2_(Dv.x * ua * gza, gza);
    scanw[sbase + 3] = pack_bf2_(Dv.y * ub * gzb, gzb);
}

// ============== single-pass scan with LDS double-buffered staging ==============
__global__ __launch_bounds__(256) void scan_lds_kernel(const float2* __restrict__ bcp,
                                                       const uint2* __restrict__ scanin,
                                                       const float* __restrict__ A_log,
                                                       bf16* __restrict__ yb) {
    __shared__ uint2  lsw[2][TCH_][16];
    __shared__ float2 lbc[2][TCH_][16];
    const int tid = threadIdx.x;
    const int n = tid & 15, dl = tid >> 4;
    const int d = blockIdx.x * 16 + dl;
    const int b = blockIdx.y;
    const float AvL = -__expf(A_log[(size_t)d * N_ + n]) * 1.44269504f;
    const size_t seqbase = (size_t)b * L_;
    const int d0 = blockIdx.x * 16;

    uint2  swr[4];
    float2 bcr[4];

    #define GLOAD(c)                                                        \
        {                                                                   \
            size_t rb = seqbase + (size_t)(c) * TCH_;                       \
            _Pragma("unroll")                                               \
            for (int i = 0; i < 4; i++) {                                   \
                int t = i * 16 + dl;                                        \
                swr[i] = scanin[(rb + t) * DI_ + d0 + n];                   \
                bcr[i] = bcp[(rb + t) * 16 + n];                            \
            }                                                               \
        }
    #define DSWRITE(p)                                                      \
        {                                                                   \
            _Pragma("unroll")                                               \
            for (int i = 0; i < 4; i++) {                                   \
                int t = i * 16 + dl;                                        \
                lsw[p][t][n] = swr[i];                                      \
                lbc[p][t][n] = bcr[i];                                      \
            }                                                               \
        }

    GLOAD(0);
    DSWRITE(0);
    __syncthreads();
    GLOAD(1);

    float h = 0.f;
    for (int c = 0; c < NCHT_; c++) {
        int p = c & 1;
        bf16* py = yb + (seqbase + (size_t)c * TCH_) * DI_ + d;
        #pragma unroll 8
        for (int t = 0; t < TCH_; t++) {
            uint2 iv = lsw[p][t][dl];
            float2 bcv = lbc[p][t][n];
            bf16x2 dv = __builtin_bit_cast(bf16x2, iv.x);
            float du = (float)dv.x, dtv = (float)dv.y;
            float dA = __builtin_amdgcn_exp2f(dtv * AvL);
            h = dA * h + du * bcv.x;
            float pq = h * bcv.y;
            pq = dpp_add_<0xB1>(pq);
            pq = dpp_add_<0x4E>(pq);
            pq = dpp_add_<0x124>(pq);
            pq = dpp_add_<0x128>(pq);
            if (n == 0) {
                bf16x2 og = __builtin_bit_cast(bf16x2, iv.y);
                py[(size_t)t * DI_] = (bf16)(pq * (float)og.y + (float)og.x);
            }
        }
        if (c + 1 < NCHT_) {
            DSWRITE(p ^ 1);
            __syncthreads();
            if (c + 2 < NCHT_) GLOAD(c + 2);
        }
    }
    #undef GLOAD
    #undef DSWRITE
}

extern "C" void kernel_launch(void* const* d_in, const int* in_sizes, int n_in,
                              void* d_out, int out_size, void* d_ws, size_t ws_size,
                              hipStream_t stream) {
    const float* x        = (const float*)d_in[0];
    const float* stat     = (const float*)d_in[1];
    const int*   mask     = (const int*)d_in[3];
    const float* emb_w    = (const float*)d_in[5];
    const float* emb_b    = (const float*)d_in[6];
    const float* static_w = (const float*)d_in[7];
    const float* static_b = (const float*)d_in[8];
    const float* ln_w     = (const float*)d_in[9];
    const float* ln_b     = (const float*)d_in[10];
    const float* norm_w   = (const float*)d_in[11];
    const float* in_proj_w  = (const float*)d_in[12];
    const float* conv_w   = (const float*)d_in[13];
    const float* conv_b   = (const float*)d_in[14];
    const float* x_proj_w = (const float*)d_in[15];
    const float* dt_proj_w= (const float*)d_in[16];
    const float* dt_proj_b= (const float*)d_in[17];
    const float* A_log    = (const float*)d_in[18];
    const float* D_param  = (const float*)d_in[19];
    const float* out_proj_w = (const float*)d_in[20];
    const float* norm_f_w = (const float*)d_in[21];
    const float* lm_head_w= (const float*)d_in[22];
    float* out = (float*)d_out;

    // ---- workspace layout (bytes), total ~215 MB ----
    char* p = (char*)d_ws;
    float*    h      = (float*)p;         p += (size_t)ROWS_ * D_ * 4;          // 50.3 MB
    bf16*     hn_bf  = (bf16*)p;          p += (size_t)CROWS_ * D_ * 2;         // 6.3
    char*     xz_region = p;                                                    // h_pre alias start
    bf16*     xz_bf  = (bf16*)p;          p += (size_t)CROWS_ * 2 * DI_ * 2;    // 25.2
    bf16*     xc_bf  = (bf16*)p;          p += (size_t)CROWS_ * DI_ * 2;        // 12.6
    unsigned* scanw  = (unsigned*)p;      p += (size_t)CROWS_ * DI_ * 8;        // 50.3 (uint2)
    float*    bc     = (float*)p;         p += (size_t)CROWS_ * 32 * 4;         // 0.5
    bf16*     dtr_bf = (bf16*)p;          p += (size_t)CROWS_ * 64 * 2;         // 0.5
    float*    pbuf   = (float*)p;         p += (size_t)KS_ * CROWS_ * 96 * 4;   // 6.3
    bf16*     y_bf   = (bf16*)p;          p += (size_t)ROWS_ * DI_ * 2;         // 50.3 (FULL batch)
    bf16*     inw_l  = (bf16*)p;          p += (size_t)2 * DI_ * D_ * 2;        // 4.7 (per-layer)
    bf16*     outw_l = (bf16*)p;          p += (size_t)D_ * DI_ * 2;            // 2.4 (per-layer)
    bf16*     xpwp_bf= (bf16*)p;          p += (size_t)NL_ * 128 * DI_ * 2;     // 1.6
    bf16*     dtwp_bf= (bf16*)p;          p += (size_t)NL_ * DI_ * 64 * 2;      // 0.8
    bf16*     lmw_bf = (bf16*)p;          p += (size_t)128 * D_ * 2;
    bf16*     embw_bf= (bf16*)p;          p += (size_t)D_ * KE_ * 2;
    bf16*     feats  = (bf16*)p;          p += (size_t)ROWS_ * KE_ * 2;         // 3.1
    float*    sstat  = (float*)p;         p += (size_t)B_ * D_ * 4;
    float*    h_pre  = (float*)xz_region; // 50.3 MB alias over xz/xc/scanw (dead then)

    // ---- weight prep ----
    pad_lm_kernel<<<(128 * D_) / 256, 256, 0, stream>>>(lm_head_w, lmw_bf);
    pad_embw_kernel<<<(D_ * KE_) / 256, 256, 0, stream>>>(emb_w, embw_bf);
    feats_kernel<<<(ROWS_ * KE_) / 256, 256, 0, stream>>>(x, mask, feats);
    dim3 gxp((128 * DI_) / 256, NL_);
    xpw_pad_kernel<<<gxp, 256, 0, stream>>>(x_proj_w, xpwp_bf);
    dim3 gdt((DI_ * 64) / 256, NL_);
    dtw_pad_kernel<<<gdt, 256, 0, stream>>>(dt_proj_w, dtwp_bf);
    sstat_kernel<<<(B_ * D_) / 256, 256, 0, stream>>>(stat, static_w, static_b, emb_b, sstat);

    // ---- embed + LN ----  (1-D swizzled grid: 6 n-tiles x 128 m-tiles = 768)
    gemm_mfma<0><<<(D_ / 128) * (ROWS_ / 128), 256, 0, stream>>>(
        feats, embw_bf, nullptr, h_pre, D_, KE_, D_ / 128,
        nullptr, nullptr, nullptr, nullptr);
    ln_embed_kernel<<<ROWS_, 256, 0, stream>>>(h_pre, sstat, ln_w, ln_b, h);

    // ---- layers ----
    for (int l = 0; l < NL_; l++) {
        cast_f2b_kernel<<<(2 * DI_ * D_) / 256, 256, 0, stream>>>(
            in_proj_w + (size_t)l * 2 * DI_ * D_, inw_l);
        cast_f2b_kernel<<<(D_ * DI_) / 256, 256, 0, stream>>>(
            out_proj_w + (size_t)l * D_ * DI_, outw_l);

        for (int c = 0; c < NCH_; c++) {
            float* hc = h + (size_t)c * CROWS_ * D_;

            rmsnorm_bf_kernel<<<CROWS_, 256, 0, stream>>>(hc, norm_w + (size_t)l * D_, hn_bf);

            // in_proj: 24 n-tiles x 32 m-tiles = 768 blocks (swizzled)
            gemm_mfma<1><<<(2 * DI_ / 128) * (CROWS_ / 128), 256, 0, stream>>>(
                hn_bf, inw_l, nullptr, xz_bf, 2 * DI_, D_, 2 * DI_ / 128,
                nullptr, nullptr, nullptr, nullptr);

            conv_silu_kernel<<<(CROWS_ * DI_ / 2) / 256, 256, 0, stream>>>(
                xz_bf, conv_w + (size_t)l * DI_ * 4, conv_b + (size_t)l * DI_,
                D_param + (size_t)l * DI_, xc_bf, scanw);

            // x_proj split-K (2-D grid, unchanged)
            dim3 g2a(KS_, CROWS_ / 128);
            gemm_mfma<4><<<g2a, 256, 0, stream>>>(xc_bf, xpwp_bf + (size_t)l * 128 * DI_,
                                                  nullptr, nullptr, 0, DI_, 1,
                                                  nullptr, nullptr, pbuf, nullptr);
            xpost_kernel<<<(CROWS_ * 96) / 256, 256, 0, stream>>>(pbuf, dtr_bf, bc);

            // dt: 12 n-tiles x 32 m-tiles = 384 blocks (swizzled)
            gemm_mfma<2><<<(DI_ / 128) * (CROWS_ / 128), 256, 0, stream>>>(
                dtr_bf, dtwp_bf + (size_t)l * DI_ * 64, nullptr, nullptr, 0, 64, DI_ / 128,
                dt_proj_b + (size_t)l * DI_, scanw, nullptr, xc_bf);

            dim3 gs(DI_ / 16, CB_);
            scan_lds_kernel<<<gs, 256, 0, stream>>>((const float2*)bc, (const uint2*)scanw,
                                                    A_log + (size_t)l * DI_ * N_,
                                                    y_bf + (size_t)c * CROWS_ * DI_);
        }

        // full-batch out_proj: 6 n-tiles x 128 m-tiles = 768 blocks (swizzled)
        gemm_mfma<0><<<(D_ / 128) * (ROWS_ / 128), 256, 0, stream>>>(
            y_bf, outw_l, h, h, D_, DI_, D_ / 128,
            nullptr, nullptr, nullptr, nullptr);
    }

    // ---- final rmsnorm + lm_head ----
    for (int c = 0; c < NCH_; c++) {
        float* hc = h + (size_t)c * CROWS_ * D_;
        rmsnorm_bf_kernel<<<CROWS_, 256, 0, stream>>>(hc, norm_f_w, hn_bf);
        // lm_head: 1 n-tile x 32 m-tiles = 32 blocks (swizzled)
        gemm_mfma<0><<<CROWS_ / 128, 256, 0, stream>>>(
            hn_bf, lmw_bf, nullptr, out + (size_t)c * CROWS_ * V_, V_, D_, 1,
            nullptr, nullptr, nullptr, nullptr);
    }
}

// Round 15
// 3129.544 us; speedup vs baseline: 1.9835x; 1.0419x over previous
//
#include <hip/hip_runtime.h>
#include <math.h>

#define B_ 32
#define L_ 512
#define S_ 37
#define STATIC_ 8
#define D_ 768
#define DI_ 1536
#define N_ 16
#define DTR_ 48
#define NL_ 4
#define V_ 32
#define ROWS_ (B_*L_)      // 16384
#define CB_ 8              // batch chunk
#define CROWS_ (CB_*L_)    // 4096
#define NCH_ (B_/CB_)      // 4
#define KE_ 96             // padded embed K (74 -> 96)
#define TCH_ 64            // scan LDS chunk (timesteps)
#define NCHT_ (L_/TCH_)    // 8 chunks
#define TPAD_ 66           // padded row stride (elements) for transposed scan LDS
#define KS_ 4              // xproj split-K slices
#define KSL_ (DI_/KS_)     // 384

typedef __bf16 bf16;
typedef __bf16 bf16x8 __attribute__((ext_vector_type(8)));
typedef __bf16 bf16x2 __attribute__((ext_vector_type(2)));
typedef float f32x4 __attribute__((ext_vector_type(4)));

typedef __attribute__((address_space(3))) void lds_void;
typedef __attribute__((address_space(1))) const void gmem_void;

__device__ __forceinline__ void gld16(const void* g, void* l) {
    __builtin_amdgcn_global_load_lds((gmem_void*)g, (lds_void*)l, 16, 0, 0);
}

__device__ __forceinline__ float silu_(float x) { return x / (1.f + __expf(-x)); }
__device__ __forceinline__ float softplus_(float x) {
    return fmaxf(x, 0.f) + __logf(1.f + __expf(-fabsf(x)));
}
__device__ __forceinline__ unsigned pack_bf2_(float a, float b) {
    bf16x2 v{(bf16)a, (bf16)b};
    return __builtin_bit_cast(unsigned, v);
}
template<int CTRL>
__device__ __forceinline__ float dpp_add_(float p) {
    int vi = __builtin_amdgcn_update_dpp(0, __builtin_bit_cast(int, p),
                                         CTRL, 0xF, 0xF, true);
    return p + __builtin_bit_cast(float, vi);
}

// ================= bf16 MFMA GEMM: C[M,*] = A[M,K] @ W[Nalloc,K]^T =================
// MODE 0: f32 out (+addsrc), stride Nstore   [1-D grid, XCD swizzle; ntn = n-tiles]
// MODE 1: bf16 out, stride Nstore            [1-D grid, XCD swizzle]
// MODE 2: dt epilogue (softplus+pack)        [1-D grid, XCD swizzle]
// MODE 4: split-K partial: blockIdx.x = K-slice, blockIdx.y = m-tile (2-D grid)
template<int MODE>
__global__ __launch_bounds__(256) void gemm_mfma(
    const bf16* __restrict__ A, const bf16* __restrict__ W,
    const float* __restrict__ addsrc, void* __restrict__ Cv,
    int Nstore, int K, int ntn,
    const float* __restrict__ dt_bias, unsigned* __restrict__ scanw,
    float* __restrict__ pbuf, const bf16* __restrict__ uref)
{
    __shared__ bf16 As[128 * 32];
    __shared__ bf16 Bs[128 * 32];
    const int tid = threadIdx.x;

    int m0, n0, kbeg, kend;
    if (MODE == 4) {
        m0 = blockIdx.y * 128; n0 = 0;
        kbeg = blockIdx.x * KSL_; kend = kbeg + KSL_;
    } else {
        int bid = blockIdx.x;
        int xcd = bid & 7, slot = bid >> 3;
        int Mtiles = gridDim.x / ntn;
        int mband = Mtiles >> 3;
        int m_tile = xcd * mband + slot / ntn;
        int n_tile = slot % ntn;
        m0 = m_tile * 128; n0 = n_tile * 128;
        kbeg = 0; kend = K;
    }

    f32x4 acc[4][4];
    #pragma unroll
    for (int i = 0; i < 4; i++)
        #pragma unroll
        for (int j = 0; j < 4; j++)
            acc[i][j] = f32x4{0.f, 0.f, 0.f, 0.f};

    const int srow = tid >> 2, spart = tid & 3;
    const bf16* ag = A + (size_t)(m0 + srow) * K + spart * 8;
    const bf16* wg = W + (size_t)(n0 + srow) * K + spart * 8;
    char* lA = (char*)As + tid * 16;
    char* lB = (char*)Bs + tid * 16;

    const int lane = tid & 63, wv = tid >> 6;
    const int wr = wv >> 1, wc = wv & 1;
    const int colL = lane & 15, quad = lane >> 4;
    const bf16* aRd = As + (wr * 64 + colL) * 32 + quad * 8;
    const bf16* bRd = Bs + (wc * 64 + colL) * 32 + quad * 8;

    for (int kt = kbeg; kt < kend; kt += 32) {
        gld16(ag + kt, lA);
        gld16(ag + kt + (size_t)64 * K, lA + 4096);
        gld16(wg + kt, lB);
        gld16(wg + kt + (size_t)64 * K, lB + 4096);
        __syncthreads();
        bf16x8 fa[4], fb[4];
        #pragma unroll
        for (int i = 0; i < 4; i++) fa[i] = *(const bf16x8*)(aRd + i * 16 * 32);
        #pragma unroll
        for (int j = 0; j < 4; j++) fb[j] = *(const bf16x8*)(bRd + j * 16 * 32);
        #pragma unroll
        for (int i = 0; i < 4; i++)
            #pragma unroll
            for (int j = 0; j < 4; j++)
                acc[i][j] = __builtin_amdgcn_mfma_f32_16x16x32_bf16(fa[i], fb[j], acc[i][j], 0, 0, 0);
        __syncthreads();
    }

    float* Cf = (float*)Cv;
    bf16*  Cb = (bf16*)Cv;
    #pragma unroll
    for (int i = 0; i < 4; i++) {
        #pragma unroll
        for (int j = 0; j < 4; j++) {
            int n = n0 + wc * 64 + j * 16 + colL;
            #pragma unroll
            for (int r = 0; r < 4; r++) {
                int m = m0 + wr * 64 + i * 16 + quad * 4 + r;
                float v = acc[i][j][r];
                if (MODE == 2) {
                    float dtv = softplus_(v + dt_bias[n]);
                    float u = (float)uref[(size_t)m * DI_ + n];
                    scanw[2 * ((size_t)m * DI_ + n)] = pack_bf2_(dtv * u, dtv);
                } else if (MODE == 4) {
                    if (n < 96)
                        pbuf[((size_t)blockIdx.x * CROWS_ + m) * 96 + n] = v;
                } else if (n < Nstore) {
                    if (addsrc) v += addsrc[(size_t)m * Nstore + n];
                    if (MODE == 1) Cb[(size_t)m * Nstore + n] = (bf16)v;
                    else           Cf[(size_t)m * Nstore + n] = v;
                }
            }
        }
    }
}

// reduce split-K partials -> dtr (bf16) + bc (interleaved f32)
__global__ __launch_bounds__(256) void xpost_kernel(const float* __restrict__ pbuf,
                                                    bf16* __restrict__ dtr,
                                                    float* __restrict__ bc) {
    int idx = blockIdx.x * 256 + threadIdx.x;   // CROWS_*96
    int m = idx / 96, j = idx % 96;
    float s = pbuf[idx];
    #pragma unroll
    for (int k = 1; k < KS_; k++) s += pbuf[(size_t)k * CROWS_ * 96 + idx];
    if (j < 64) {
        dtr[(size_t)m * 64 + j] = (bf16)s;
    } else {
        int jj = j - 64;
        int pos = (jj < 16) ? (2 * jj) : (2 * (jj - 16) + 1);
        bc[(size_t)m * 32 + pos] = s;
    }
}

// ================= small prep kernels =================
__global__ __launch_bounds__(256) void cast_f2b_kernel(const float* __restrict__ s,
                                                       bf16* __restrict__ d) {
    size_t i = (size_t)blockIdx.x * 256 + threadIdx.x;
    d[i] = (bf16)s[i];
}

__global__ __launch_bounds__(256) void pad_lm_kernel(const float* __restrict__ s, bf16* __restrict__ d) {
    int i = blockIdx.x * 256 + threadIdx.x;     // 128*768
    int row = i / D_;
    d[i] = (row < V_) ? (bf16)s[i] : (bf16)0.f;
}

__global__ __launch_bounds__(256) void pad_embw_kernel(const float* __restrict__ s, bf16* __restrict__ d) {
    int i = blockIdx.x * 256 + threadIdx.x;     // 768*96
    int row = i / KE_, col = i % KE_;
    d[i] = (col < 2 * S_) ? (bf16)s[row * 2 * S_ + col] : (bf16)0.f;
}

__global__ __launch_bounds__(256) void feats_kernel(const float* __restrict__ x,
                                                    const int* __restrict__ mask,
                                                    bf16* __restrict__ d) {
    size_t i = (size_t)blockIdx.x * 256 + threadIdx.x;  // ROWS_*96
    size_t row = i / KE_;
    int col = (int)(i % KE_);
    float v = 0.f;
    if (col < S_) v = x[row * S_ + col];
    else if (col < 2 * S_) v = (float)mask[row * S_ + (col - S_)];
    d[i] = (bf16)v;
}

// x_proj padded+remapped: (NL,128,1536) rows: 0..47=dt_r, 48..63=0, 64..95=B|C, 96..127=0
__global__ __launch_bounds__(256) void xpw_pad_kernel(const float* __restrict__ xpw,
                                                      bf16* __restrict__ d) {
    int l = blockIdx.y;
    int idx = blockIdx.x * 256 + threadIdx.x;   // 128*1536
    int row = idx / DI_, col = idx % DI_;
    float v = 0.f;
    if (row < DTR_) v = xpw[((size_t)l * (DTR_ + 2 * N_) + row) * DI_ + col];
    else if (row >= 64 && row < 96) v = xpw[((size_t)l * (DTR_ + 2 * N_) + row - 16) * DI_ + col];
    d[(size_t)l * 128 * DI_ + idx] = (bf16)v;
}

// dt_proj_w padded: (NL,1536,64), cols 48..63 = 0
__global__ __launch_bounds__(256) void dtw_pad_kernel(const float* __restrict__ dtw,
                                                      bf16* __restrict__ d) {
    int l = blockIdx.y;
    int idx = blockIdx.x * 256 + threadIdx.x;   // 1536*64
    int row = idx / 64, c = idx % 64;
    float v = (c < DTR_) ? dtw[((size_t)l * DI_ + row) * DTR_ + c] : 0.f;
    d[(size_t)l * DI_ * 64 + idx] = (bf16)v;
}

__global__ __launch_bounds__(256) void sstat_kernel(const float* __restrict__ stat,
                                                    const float* __restrict__ static_w,
                                                    const float* __restrict__ static_b,
                                                    const float* __restrict__ emb_b,
                                                    float* __restrict__ sstat) {
    int i = blockIdx.x * 256 + threadIdx.x;  // B_*D_
    int d = i % D_, b = i / D_;
    float acc = emb_b[d] + static_b[d];
    const float* sw = static_w + (size_t)d * STATIC_;
    const float* sv = stat + (size_t)b * STATIC_;
    #pragma unroll
    for (int s = 0; s < STATIC_; s++) acc += sv[s] * sw[s];
    sstat[i] = acc;
}

__device__ __forceinline__ void block_reduce2_(float& a, float& b, float* sbuf) {
    #pragma unroll
    for (int off = 32; off > 0; off >>= 1) {
        a += __shfl_down(a, off, 64);
        b += __shfl_down(b, off, 64);
    }
    int lane = threadIdx.x & 63, wid = threadIdx.x >> 6;
    if (lane == 0) { sbuf[wid] = a; sbuf[4 + wid] = b; }
    __syncthreads();
    a = sbuf[0] + sbuf[1] + sbuf[2] + sbuf[3];
    b = sbuf[4] + sbuf[5] + sbuf[6] + sbuf[7];
}

__global__ __launch_bounds__(256) void ln_embed_kernel(const float* __restrict__ h_pre,
                                                       const float* __restrict__ sstat,
                                                       const float* __restrict__ ln_w,
                                                       const float* __restrict__ ln_b,
                                                       float* __restrict__ h) {
    int row = blockIdx.x, b = row / L_, tid = threadIdx.x;
    __shared__ float sbuf[8];
    float v[3], sum = 0.f, sq = 0.f;
    #pragma unroll
    for (int j = 0; j < 3; j++) {
        int d = tid + 256 * j;
        v[j] = h_pre[(size_t)row * D_ + d] + sstat[b * D_ + d];
        sum += v[j]; sq += v[j] * v[j];
    }
    block_reduce2_(sum, sq, sbuf);
    float mu = sum * (1.f / D_);
    float rstd = rsqrtf(sq * (1.f / D_) - mu * mu + 1e-5f);
    #pragma unroll
    for (int j = 0; j < 3; j++) {
        int d = tid + 256 * j;
        h[(size_t)row * D_ + d] = (v[j] - mu) * rstd * ln_w[d] + ln_b[d];
    }
}

__global__ __launch_bounds__(256) void rmsnorm_bf_kernel(const float* __restrict__ h,
                                                         const float* __restrict__ w,
                                                         bf16* __restrict__ out) {
    int row = blockIdx.x, tid = threadIdx.x;
    __shared__ float sbuf[8];
    float v[3], ss = 0.f, dummy = 0.f;
    #pragma unroll
    for (int j = 0; j < 3; j++) {
        v[j] = h[(size_t)row * D_ + tid + 256 * j];
        ss += v[j] * v[j];
    }
    block_reduce2_(ss, dummy, sbuf);
    float rstd = rsqrtf(ss * (1.f / D_) + 1e-5f);
    #pragma unroll
    for (int j = 0; j < 3; j++) {
        int d = tid + 256 * j;
        out[(size_t)row * D_ + d] = (bf16)(v[j] * rstd * w[d]);
    }
}

// conv K=4 + silu -> xc (2 channels/thread) ; gate packs -> scanw[.y]
__global__ __launch_bounds__(256) void conv_silu_kernel(const bf16* __restrict__ xzb,
                                                        const float* __restrict__ cw,
                                                        const float* __restrict__ cb,
                                                        const float* __restrict__ Dp,
                                                        bf16* __restrict__ xcb,
                                                        unsigned* __restrict__ scanw) {
    size_t idx = (size_t)blockIdx.x * 256 + threadIdx.x;   // CROWS_*DI_/2
    int d2 = (int)(idx % (DI_ / 2));
    size_t row = idx / (DI_ / 2);
    int t = (int)(row % L_);
    int d = d2 * 2;
    const unsigned* xz32 = (const unsigned*)xzb;
    size_t base = row * DI_ + d2;
    unsigned p0  = xz32[base];
    unsigned pm1 = (t >= 1) ? xz32[base - DI_]     : 0u;
    unsigned pm2 = (t >= 2) ? xz32[base - 2 * DI_] : 0u;
    unsigned pm3 = (t >= 3) ? xz32[base - 3 * DI_] : 0u;
    unsigned pz  = xz32[row * DI_ + DI_ / 2 + d2];

    bf16x2 v0  = __builtin_bit_cast(bf16x2, p0);
    bf16x2 v1  = __builtin_bit_cast(bf16x2, pm1);
    bf16x2 v2  = __builtin_bit_cast(bf16x2, pm2);
    bf16x2 v3  = __builtin_bit_cast(bf16x2, pm3);
    bf16x2 vz  = __builtin_bit_cast(bf16x2, pz);

    float4 wa = ((const float4*)cw)[d];
    float4 wb = ((const float4*)cw)[d + 1];
    float2 cbv = ((const float2*)cb)[d2];
    float2 Dv  = ((const float2*)Dp)[d2];

    float acca = cbv.x + wa.x * (float)v3.x + wa.y * (float)v2.x + wa.z * (float)v1.x + wa.w * (float)v0.x;
    float accb = cbv.y + wb.x * (float)v3.y + wb.y * (float)v2.y + wb.z * (float)v1.y + wb.w * (float)v0.y;
    float ua = silu_(acca), ub = silu_(accb);
    ((unsigned*)xcb)[row * (DI_ / 2) + d2] = pack_bf2_(ua, ub);
    float gza = silu_((float)vz.x), gzb = silu_((float)vz.y);
    size_t sbase = 2 * (row * DI_ + d);
    scanw[sbase + 1] = pack_bf2_(Dv.x * ua * gza, gza);
    scanw[sbase + 3] = pack_bf2_(Dv.y * ub * gzb, gzb);
}

// ============== single-pass scan: transposed LDS, 2 timesteps per ds_read_b128 ==============
// lswT[buf][d_local][t] (uint2), lbcT[buf][n][t] (float2); row stride TPAD_=66 (16B-aligned, bank-spread)
__global__ __launch_bounds__(256) void scan_lds_kernel(const float2* __restrict__ bcp,
                                                       const uint2* __restrict__ scanin,
                                                       const float* __restrict__ A_log,
                                                       bf16* __restrict__ yb) {
    __shared__ uint2  lswT[2][16][TPAD_];
    __shared__ float2 lbcT[2][16][TPAD_];
    const int tid = threadIdx.x;
    const int n = tid & 15, dl = tid >> 4;
    const int d = blockIdx.x * 16 + dl;
    const int b = blockIdx.y;
    const float AvL = -__expf(A_log[(size_t)d * N_ + n]) * 1.44269504f;
    const size_t seqbase = (size_t)b * L_;
    const int d0 = blockIdx.x * 16;

    uint2  swr[4];
    float2 bcr[4];

    #define GLOAD(c)                                                        \
        {                                                                   \
            size_t rb = seqbase + (size_t)(c) * TCH_;                       \
            _Pragma("unroll")                                               \
            for (int i = 0; i < 4; i++) {                                   \
                int t = i * 16 + dl;                                        \
                swr[i] = scanin[(rb + t) * DI_ + d0 + n];                   \
                bcr[i] = bcp[(rb + t) * 16 + n];                            \
            }                                                               \
        }
    // transposed write: element for (t, d_local=n) goes to lswT[n][t]; bc (t, n) -> lbcT[n][t]
    #define DSWRITE(p)                                                      \
        {                                                                   \
            _Pragma("unroll")                                               \
            for (int i = 0; i < 4; i++) {                                   \
                int t = i * 16 + dl;                                        \
                lswT[p][n][t] = swr[i];                                     \
                lbcT[p][n][t] = bcr[i];                                     \
            }                                                               \
        }

    GLOAD(0);
    DSWRITE(0);
    __syncthreads();
    GLOAD(1);

    float h = 0.f;
    for (int c = 0; c < NCHT_; c++) {
        int p = c & 1;
        bf16* py = yb + (seqbase + (size_t)c * TCH_) * DI_ + d;
        #pragma unroll 4
        for (int t = 0; t < TCH_; t += 2) {
            // one b128 each: two timesteps of sw (this thread's d-channel) and bc (this thread's n)
            uint4  sw2 = *(const uint4*)&lswT[p][dl][t];
            float4 bc2 = *(const float4*)&lbcT[p][n][t];
            {
                bf16x2 dv = __builtin_bit_cast(bf16x2, sw2.x);
                float du = (float)dv.x, dtv = (float)dv.y;
                float dA = __builtin_amdgcn_exp2f(dtv * AvL);
                h = dA * h + du * bc2.x;
                float pq = h * bc2.y;
                pq = dpp_add_<0xB1>(pq);
                pq = dpp_add_<0x4E>(pq);
                pq = dpp_add_<0x124>(pq);
                pq = dpp_add_<0x128>(pq);
                if (n == 0) {
                    bf16x2 og = __builtin_bit_cast(bf16x2, sw2.y);
                    py[(size_t)t * DI_] = (bf16)(pq * (float)og.y + (float)og.x);
                }
            }
            {
                bf16x2 dv = __builtin_bit_cast(bf16x2, sw2.z);
                float du = (float)dv.x, dtv = (float)dv.y;
                float dA = __builtin_amdgcn_exp2f(dtv * AvL);
                h = dA * h + du * bc2.z;
                float pq = h * bc2.w;
                pq = dpp_add_<0xB1>(pq);
                pq = dpp_add_<0x4E>(pq);
                pq = dpp_add_<0x124>(pq);
                pq = dpp_add_<0x128>(pq);
                if (n == 0) {
                    bf16x2 og = __builtin_bit_cast(bf16x2, sw2.w);
                    py[(size_t)(t + 1) * DI_] = (bf16)(pq * (float)og.y + (float)og.x);
                }
            }
        }
        if (c + 1 < NCHT_) {
            DSWRITE(p ^ 1);
            __syncthreads();
            if (c + 2 < NCHT_) GLOAD(c + 2);
        }
    }
    #undef GLOAD
    #undef DSWRITE
}

extern "C" void kernel_launch(void* const* d_in, const int* in_sizes, int n_in,
                              void* d_out, int out_size, void* d_ws, size_t ws_size,
                              hipStream_t stream) {
    const float* x        = (const float*)d_in[0];
    const float* stat     = (const float*)d_in[1];
    const int*   mask     = (const int*)d_in[3];
    const float* emb_w    = (const float*)d_in[5];
    const float* emb_b    = (const float*)d_in[6];
    const float* static_w = (const float*)d_in[7];
    const float* static_b = (const float*)d_in[8];
    const float* ln_w     = (const float*)d_in[9];
    const float* ln_b     = (const float*)d_in[10];
    const float* norm_w   = (const float*)d_in[11];
    const float* in_proj_w  = (const float*)d_in[12];
    const float* conv_w   = (const float*)d_in[13];
    const float* conv_b   = (const float*)d_in[14];
    const float* x_proj_w = (const float*)d_in[15];
    const float* dt_proj_w= (const float*)d_in[16];
    const float* dt_proj_b= (const float*)d_in[17];
    const float* A_log    = (const float*)d_in[18];
    const float* D_param  = (const float*)d_in[19];
    const float* out_proj_w = (const float*)d_in[20];
    const float* norm_f_w = (const float*)d_in[21];
    const float* lm_head_w= (const float*)d_in[22];
    float* out = (float*)d_out;

    // ---- workspace layout (bytes), total ~215 MB ----
    char* p = (char*)d_ws;
    float*    h      = (float*)p;         p += (size_t)ROWS_ * D_ * 4;          // 50.3 MB
    bf16*     hn_bf  = (bf16*)p;          p += (size_t)CROWS_ * D_ * 2;         // 6.3
    char*     xz_region = p;                                                    // h_pre alias start
    bf16*     xz_bf  = (bf16*)p;          p += (size_t)CROWS_ * 2 * DI_ * 2;    // 25.2
    bf16*     xc_bf  = (bf16*)p;          p += (size_t)CROWS_ * DI_ * 2;        // 12.6
    unsigned* scanw  = (unsigned*)p;      p += (size_t)CROWS_ * DI_ * 8;        // 50.3 (uint2)
    float*    bc     = (float*)p;         p += (size_t)CROWS_ * 32 * 4;         // 0.5
    bf16*     dtr_bf = (bf16*)p;          p += (size_t)CROWS_ * 64 * 2;         // 0.5
    float*    pbuf   = (float*)p;         p += (size_t)KS_ * CROWS_ * 96 * 4;   // 6.3
    bf16*     y_bf   = (bf16*)p;          p += (size_t)ROWS_ * DI_ * 2;         // 50.3 (FULL batch)
    bf16*     inw_l  = (bf16*)p;          p += (size_t)2 * DI_ * D_ * 2;        // 4.7 (per-layer)
    bf16*     outw_l = (bf16*)p;          p += (size_t)D_ * DI_ * 2;            // 2.4 (per-layer)
    bf16*     xpwp_bf= (bf16*)p;          p += (size_t)NL_ * 128 * DI_ * 2;     // 1.6
    bf16*     dtwp_bf= (bf16*)p;          p += (size_t)NL_ * DI_ * 64 * 2;      // 0.8
    bf16*     lmw_bf = (bf16*)p;          p += (size_t)128 * D_ * 2;
    bf16*     embw_bf= (bf16*)p;          p += (size_t)D_ * KE_ * 2;
    bf16*     feats  = (bf16*)p;          p += (size_t)ROWS_ * KE_ * 2;         // 3.1
    float*    sstat  = (float*)p;         p += (size_t)B_ * D_ * 4;
    float*    h_pre  = (float*)xz_region; // 50.3 MB alias over xz/xc/scanw (dead then)

    // ---- weight prep ----
    pad_lm_kernel<<<(128 * D_) / 256, 256, 0, stream>>>(lm_head_w, lmw_bf);
    pad_embw_kernel<<<(D_ * KE_) / 256, 256, 0, stream>>>(emb_w, embw_bf);
    feats_kernel<<<(ROWS_ * KE_) / 256, 256, 0, stream>>>(x, mask, feats);
    dim3 gxp((128 * DI_) / 256, NL_);
    xpw_pad_kernel<<<gxp, 256, 0, stream>>>(x_proj_w, xpwp_bf);
    dim3 gdt((DI_ * 64) / 256, NL_);
    dtw_pad_kernel<<<gdt, 256, 0, stream>>>(dt_proj_w, dtwp_bf);
    sstat_kernel<<<(B_ * D_) / 256, 256, 0, stream>>>(stat, static_w, static_b, emb_b, sstat);

    // ---- embed + LN ----
    gemm_mfma<0><<<(D_ / 128) * (ROWS_ / 128), 256, 0, stream>>>(
        feats, embw_bf, nullptr, h_pre, D_, KE_, D_ / 128,
        nullptr, nullptr, nullptr, nullptr);
    ln_embed_kernel<<<ROWS_, 256, 0, stream>>>(h_pre, sstat, ln_w, ln_b, h);

    // ---- layers ----
    for (int l = 0; l < NL_; l++) {
        cast_f2b_kernel<<<(2 * DI_ * D_) / 256, 256, 0, stream>>>(
            in_proj_w + (size_t)l * 2 * DI_ * D_, inw_l);
        cast_f2b_kernel<<<(D_ * DI_) / 256, 256, 0, stream>>>(
            out_proj_w + (size_t)l * D_ * DI_, outw_l);

        for (int c = 0; c < NCH_; c++) {
            float* hc = h + (size_t)c * CROWS_ * D_;

            rmsnorm_bf_kernel<<<CROWS_, 256, 0, stream>>>(hc, norm_w + (size_t)l * D_, hn_bf);

            gemm_mfma<1><<<(2 * DI_ / 128) * (CROWS_ / 128), 256, 0, stream>>>(
                hn_bf, inw_l, nullptr, xz_bf, 2 * DI_, D_, 2 * DI_ / 128,
                nullptr, nullptr, nullptr, nullptr);

            conv_silu_kernel<<<(CROWS_ * DI_ / 2) / 256, 256, 0, stream>>>(
                xz_bf, conv_w + (size_t)l * DI_ * 4, conv_b + (size_t)l * DI_,
                D_param + (size_t)l * DI_, xc_bf, scanw);

            dim3 g2a(KS_, CROWS_ / 128);
            gemm_mfma<4><<<g2a, 256, 0, stream>>>(xc_bf, xpwp_bf + (size_t)l * 128 * DI_,
                                                  nullptr, nullptr, 0, DI_, 1,
                                                  nullptr, nullptr, pbuf, nullptr);
            xpost_kernel<<<(CROWS_ * 96) / 256, 256, 0, stream>>>(pbuf, dtr_bf, bc);

            gemm_mfma<2><<<(DI_ / 128) * (CROWS_ / 128), 256, 0, stream>>>(
                dtr_bf, dtwp_bf + (size_t)l * DI_ * 64, nullptr, nullptr, 0, 64, DI_ / 128,
                dt_proj_b + (size_t)l * DI_, scanw, nullptr, xc_bf);

            dim3 gs(DI_ / 16, CB_);
            scan_lds_kernel<<<gs, 256, 0, stream>>>((const float2*)bc, (const uint2*)scanw,
                                                    A_log + (size_t)l * DI_ * N_,
                                                    y_bf + (size_t)c * CROWS_ * DI_);
        }

        gemm_mfma<0><<<(D_ / 128) * (ROWS_ / 128), 256, 0, stream>>>(
            y_bf, outw_l, h, h, D_, DI_, D_ / 128,
            nullptr, nullptr, nullptr, nullptr);
    }

    // ---- final rmsnorm + lm_head ----
    for (int c = 0; c < NCH_; c++) {
        float* hc = h + (size_t)c * CROWS_ * D_;
        rmsnorm_bf_kernel<<<CROWS_, 256, 0, stream>>>(hc, norm_f_w, hn_bf);
        gemm_mfma<0><<<CROWS_ / 128, 256, 0, stream>>>(
            hn_bf, lmw_bf, nullptr, out + (size_t)c * CROWS_ * V_, V_, D_, 1,
            nullptr, nullptr, nullptr, nullptr);
    }
}

// Round 16
// 2900.385 us; speedup vs baseline: 2.1402x; 1.0790x over previous
//
#include <hip/hip_runtime.h>
#include <math.h>

#define B_ 32
#define L_ 512
#define S_ 37
#define STATIC_ 8
#define D_ 768
#define DI_ 1536
#define N_ 16
#define DTR_ 48
#define NL_ 4
#define V_ 32
#define ROWS_ (B_*L_)      // 16384
#define CB_ 8              // batch chunk
#define CROWS_ (CB_*L_)    // 4096
#define NCH_ (B_/CB_)      // 4
#define KE_ 96             // padded embed K (74 -> 96)
#define TCH_ 64            // scan LDS chunk (timesteps)
#define NCHT_ (L_/TCH_)    // 8 chunks
#define TP4_ 68            // padded row stride (u32) for scan LDS
#define KS_ 4              // xproj split-K slices
#define KSL_ (DI_/KS_)     // 384

typedef __bf16 bf16;
typedef __bf16 bf16x8 __attribute__((ext_vector_type(8)));
typedef __bf16 bf16x4 __attribute__((ext_vector_type(4)));
typedef __bf16 bf16x2 __attribute__((ext_vector_type(2)));
typedef float f32x4 __attribute__((ext_vector_type(4)));

typedef __attribute__((address_space(3))) void lds_void;
typedef __attribute__((address_space(1))) const void gmem_void;

__device__ __forceinline__ void gld16(const void* g, void* l) {
    __builtin_amdgcn_global_load_lds((gmem_void*)g, (lds_void*)l, 16, 0, 0);
}

__device__ __forceinline__ float silu_(float x) { return x / (1.f + __expf(-x)); }
__device__ __forceinline__ float softplus_(float x) {
    return fmaxf(x, 0.f) + __logf(1.f + __expf(-fabsf(x)));
}
__device__ __forceinline__ unsigned pack_bf2_(float a, float b) {
    bf16x2 v{(bf16)a, (bf16)b};
    return __builtin_bit_cast(unsigned, v);
}
template<int CTRL>
__device__ __forceinline__ float dpp_add_(float p) {
    int vi = __builtin_amdgcn_update_dpp(0, __builtin_bit_cast(int, p),
                                         CTRL, 0xF, 0xF, true);
    return p + __builtin_bit_cast(float, vi);
}

// ================= bf16 MFMA GEMM: C[M,*] = A[M,K] @ W[Nalloc,K]^T =================
// MODE 0: f32 out (+addsrc), stride Nstore   [1-D grid, XCD swizzle; ntn = n-tiles]
// MODE 1: bf16 out, stride Nstore            [1-D grid, XCD swizzle]
// MODE 2: dt epilogue: swg[m*DI_+n] = pack(du,dtv)  [1-D grid, XCD swizzle]
// MODE 4: split-K partial (2-D grid)
template<int MODE>
__global__ __launch_bounds__(256) void gemm_mfma(
    const bf16* __restrict__ A, const bf16* __restrict__ W,
    const float* __restrict__ addsrc, void* __restrict__ Cv,
    int Nstore, int K, int ntn,
    const float* __restrict__ dt_bias, unsigned* __restrict__ swg,
    float* __restrict__ pbuf, const bf16* __restrict__ uref)
{
    __shared__ bf16 As[128 * 32];
    __shared__ bf16 Bs[128 * 32];
    const int tid = threadIdx.x;

    int m0, n0, kbeg, kend;
    if (MODE == 4) {
        m0 = blockIdx.y * 128; n0 = 0;
        kbeg = blockIdx.x * KSL_; kend = kbeg + KSL_;
    } else {
        int bid = blockIdx.x;
        int xcd = bid & 7, slot = bid >> 3;
        int Mtiles = gridDim.x / ntn;
        int mband = Mtiles >> 3;
        int m_tile = xcd * mband + slot / ntn;
        int n_tile = slot % ntn;
        m0 = m_tile * 128; n0 = n_tile * 128;
        kbeg = 0; kend = K;
    }

    f32x4 acc[4][4];
    #pragma unroll
    for (int i = 0; i < 4; i++)
        #pragma unroll
        for (int j = 0; j < 4; j++)
            acc[i][j] = f32x4{0.f, 0.f, 0.f, 0.f};

    const int srow = tid >> 2, spart = tid & 3;
    const bf16* ag = A + (size_t)(m0 + srow) * K + spart * 8;
    const bf16* wg = W + (size_t)(n0 + srow) * K + spart * 8;
    char* lA = (char*)As + tid * 16;
    char* lB = (char*)Bs + tid * 16;

    const int lane = tid & 63, wv = tid >> 6;
    const int wr = wv >> 1, wc = wv & 1;
    const int colL = lane & 15, quad = lane >> 4;
    const bf16* aRd = As + (wr * 64 + colL) * 32 + quad * 8;
    const bf16* bRd = Bs + (wc * 64 + colL) * 32 + quad * 8;

    for (int kt = kbeg; kt < kend; kt += 32) {
        gld16(ag + kt, lA);
        gld16(ag + kt + (size_t)64 * K, lA + 4096);
        gld16(wg + kt, lB);
        gld16(wg + kt + (size_t)64 * K, lB + 4096);
        __syncthreads();
        bf16x8 fa[4], fb[4];
        #pragma unroll
        for (int i = 0; i < 4; i++) fa[i] = *(const bf16x8*)(aRd + i * 16 * 32);
        #pragma unroll
        for (int j = 0; j < 4; j++) fb[j] = *(const bf16x8*)(bRd + j * 16 * 32);
        #pragma unroll
        for (int i = 0; i < 4; i++)
            #pragma unroll
            for (int j = 0; j < 4; j++)
                acc[i][j] = __builtin_amdgcn_mfma_f32_16x16x32_bf16(fa[i], fb[j], acc[i][j], 0, 0, 0);
        __syncthreads();
    }

    float* Cf = (float*)Cv;
    bf16*  Cb = (bf16*)Cv;
    #pragma unroll
    for (int i = 0; i < 4; i++) {
        #pragma unroll
        for (int j = 0; j < 4; j++) {
            int n = n0 + wc * 64 + j * 16 + colL;
            #pragma unroll
            for (int r = 0; r < 4; r++) {
                int m = m0 + wr * 64 + i * 16 + quad * 4 + r;
                float v = acc[i][j][r];
                if (MODE == 2) {
                    float dtv = softplus_(v + dt_bias[n]);
                    float u = (float)uref[(size_t)m * DI_ + n];
                    swg[(size_t)m * DI_ + n] = pack_bf2_(dtv * u, dtv);
                } else if (MODE == 4) {
                    if (n < 96)
                        pbuf[((size_t)blockIdx.x * CROWS_ + m) * 96 + n] = v;
                } else if (n < Nstore) {
                    if (addsrc) v += addsrc[(size_t)m * Nstore + n];
                    if (MODE == 1) Cb[(size_t)m * Nstore + n] = (bf16)v;
                    else           Cf[(size_t)m * Nstore + n] = v;
                }
            }
        }
    }
}

// reduce split-K partials -> dtr (bf16) + bc16 (bf16 pairs (B,C) per n)
__global__ __launch_bounds__(256) void xpost_kernel(const float* __restrict__ pbuf,
                                                    bf16* __restrict__ dtr,
                                                    bf16* __restrict__ bcb) {
    int idx = blockIdx.x * 256 + threadIdx.x;   // CROWS_*96
    int m = idx / 96, j = idx % 96;
    float s = pbuf[idx];
    #pragma unroll
    for (int k = 1; k < KS_; k++) s += pbuf[(size_t)k * CROWS_ * 96 + idx];
    if (j < 64) {
        dtr[(size_t)m * 64 + j] = (bf16)s;
    } else {
        int jj = j - 64;
        int n = jj & 15, hi = jj >> 4;    // hi=0 -> B, hi=1 -> C
        bcb[(size_t)m * 32 + 2 * n + hi] = (bf16)s;
    }
}

// ================= small prep kernels =================
__global__ __launch_bounds__(256) void cast_f2b_kernel(const float* __restrict__ s,
                                                       bf16* __restrict__ d) {
    size_t i = (size_t)blockIdx.x * 256 + threadIdx.x;
    d[i] = (bf16)s[i];
}

__global__ __launch_bounds__(256) void pad_lm_kernel(const float* __restrict__ s, bf16* __restrict__ d) {
    int i = blockIdx.x * 256 + threadIdx.x;     // 128*768
    int row = i / D_;
    d[i] = (row < V_) ? (bf16)s[i] : (bf16)0.f;
}

__global__ __launch_bounds__(256) void pad_embw_kernel(const float* __restrict__ s, bf16* __restrict__ d) {
    int i = blockIdx.x * 256 + threadIdx.x;     // 768*96
    int row = i / KE_, col = i % KE_;
    d[i] = (col < 2 * S_) ? (bf16)s[row * 2 * S_ + col] : (bf16)0.f;
}

__global__ __launch_bounds__(256) void feats_kernel(const float* __restrict__ x,
                                                    const int* __restrict__ mask,
                                                    bf16* __restrict__ d) {
    size_t i = (size_t)blockIdx.x * 256 + threadIdx.x;  // ROWS_*96
    size_t row = i / KE_;
    int col = (int)(i % KE_);
    float v = 0.f;
    if (col < S_) v = x[row * S_ + col];
    else if (col < 2 * S_) v = (float)mask[row * S_ + (col - S_)];
    d[i] = (bf16)v;
}

// x_proj padded+remapped: (NL,128,1536) rows: 0..47=dt_r, 48..63=0, 64..95=B|C, 96..127=0
__global__ __launch_bounds__(256) void xpw_pad_kernel(const float* __restrict__ xpw,
                                                      bf16* __restrict__ d) {
    int l = blockIdx.y;
    int idx = blockIdx.x * 256 + threadIdx.x;   // 128*1536
    int row = idx / DI_, col = idx % DI_;
    float v = 0.f;
    if (row < DTR_) v = xpw[((size_t)l * (DTR_ + 2 * N_) + row) * DI_ + col];
    else if (row >= 64 && row < 96) v = xpw[((size_t)l * (DTR_ + 2 * N_) + row - 16) * DI_ + col];
    d[(size_t)l * 128 * DI_ + idx] = (bf16)v;
}

// dt_proj_w padded: (NL,1536,64), cols 48..63 = 0
__global__ __launch_bounds__(256) void dtw_pad_kernel(const float* __restrict__ dtw,
                                                      bf16* __restrict__ d) {
    int l = blockIdx.y;
    int idx = blockIdx.x * 256 + threadIdx.x;   // 1536*64
    int row = idx / 64, c = idx % 64;
    float v = (c < DTR_) ? dtw[((size_t)l * DI_ + row) * DTR_ + c] : 0.f;
    d[(size_t)l * DI_ * 64 + idx] = (bf16)v;
}

__global__ __launch_bounds__(256) void sstat_kernel(const float* __restrict__ stat,
                                                    const float* __restrict__ static_w,
                                                    const float* __restrict__ static_b,
                                                    const float* __restrict__ emb_b,
                                                    float* __restrict__ sstat) {
    int i = blockIdx.x * 256 + threadIdx.x;  // B_*D_
    int d = i % D_, b = i / D_;
    float acc = emb_b[d] + static_b[d];
    const float* sw = static_w + (size_t)d * STATIC_;
    const float* sv = stat + (size_t)b * STATIC_;
    #pragma unroll
    for (int s = 0; s < STATIC_; s++) acc += sv[s] * sw[s];
    sstat[i] = acc;
}

__device__ __forceinline__ void block_reduce2_(float& a, float& b, float* sbuf) {
    #pragma unroll
    for (int off = 32; off > 0; off >>= 1) {
        a += __shfl_down(a, off, 64);
        b += __shfl_down(b, off, 64);
    }
    int lane = threadIdx.x & 63, wid = threadIdx.x >> 6;
    if (lane == 0) { sbuf[wid] = a; sbuf[4 + wid] = b; }
    __syncthreads();
    a = sbuf[0] + sbuf[1] + sbuf[2] + sbuf[3];
    b = sbuf[4] + sbuf[5] + sbuf[6] + sbuf[7];
}

__global__ __launch_bounds__(256) void ln_embed_kernel(const float* __restrict__ h_pre,
                                                       const float* __restrict__ sstat,
                                                       const float* __restrict__ ln_w,
                                                       const float* __restrict__ ln_b,
                                                       float* __restrict__ h) {
    int row = blockIdx.x, b = row / L_, tid = threadIdx.x;
    __shared__ float sbuf[8];
    float v[3], sum = 0.f, sq = 0.f;
    #pragma unroll
    for (int j = 0; j < 3; j++) {
        int d = tid + 256 * j;
        v[j] = h_pre[(size_t)row * D_ + d] + sstat[b * D_ + d];
        sum += v[j]; sq += v[j] * v[j];
    }
    block_reduce2_(sum, sq, sbuf);
    float mu = sum * (1.f / D_);
    float rstd = rsqrtf(sq * (1.f / D_) - mu * mu + 1e-5f);
    #pragma unroll
    for (int j = 0; j < 3; j++) {
        int d = tid + 256 * j;
        h[(size_t)row * D_ + d] = (v[j] - mu) * rstd * ln_w[d] + ln_b[d];
    }
}

__global__ __launch_bounds__(256) void rmsnorm_bf_kernel(const float* __restrict__ h,
                                                         const float* __restrict__ w,
                                                         bf16* __restrict__ out) {
    int row = blockIdx.x, tid = threadIdx.x;
    __shared__ float sbuf[8];
    float v[3], ss = 0.f, dummy = 0.f;
    #pragma unroll
    for (int j = 0; j < 3; j++) {
        v[j] = h[(size_t)row * D_ + tid + 256 * j];
        ss += v[j] * v[j];
    }
    block_reduce2_(ss, dummy, sbuf);
    float rstd = rsqrtf(ss * (1.f / D_) + 1e-5f);
    #pragma unroll
    for (int j = 0; j < 3; j++) {
        int d = tid + 256 * j;
        out[(size_t)row * D_ + d] = (bf16)(v[j] * rstd * w[d]);
    }
}

// conv K=4 + silu -> xc (4 channels/thread) ; gate u32 per (row,d) -> gag
__global__ __launch_bounds__(256) void conv_silu_kernel(const bf16* __restrict__ xzb,
                                                        const float* __restrict__ cw,
                                                        const float* __restrict__ cb,
                                                        const float* __restrict__ Dp,
                                                        bf16* __restrict__ xcb,
                                                        unsigned* __restrict__ gag) {
    size_t idx = (size_t)blockIdx.x * 256 + threadIdx.x;   // CROWS_*DI_/4
    int d4 = (int)(idx % (DI_ / 4));
    size_t row = idx / (DI_ / 4);
    int t = (int)(row % L_);
    int d = d4 * 4;
    const uint2* xz64 = (const uint2*)xzb;                 // row stride 768 uint2
    size_t base = row * 768 + d4;
    uint2 z2{0u, 0u};
    uint2 p0  = xz64[base];
    uint2 pm1 = (t >= 1) ? xz64[base - 768]     : z2;
    uint2 pm2 = (t >= 2) ? xz64[base - 2 * 768] : z2;
    uint2 pm3 = (t >= 3) ? xz64[base - 3 * 768] : z2;
    uint2 pz  = xz64[base + 384];

    bf16x4 a0 = __builtin_bit_cast(bf16x4, p0);
    bf16x4 a1 = __builtin_bit_cast(bf16x4, pm1);
    bf16x4 a2 = __builtin_bit_cast(bf16x4, pm2);
    bf16x4 a3 = __builtin_bit_cast(bf16x4, pm3);
    bf16x4 az = __builtin_bit_cast(bf16x4, pz);

    float cbl[4], Dl[4];
    *(float4*)cbl = ((const float4*)cb)[d4];
    *(float4*)Dl  = ((const float4*)Dp)[d4];

    float u[4];
    unsigned gv[4];
    #pragma unroll
    for (int c = 0; c < 4; c++) {
        float4 wc = ((const float4*)cw)[d + c];
        float acc = cbl[c] + wc.x * (float)a3[c] + wc.y * (float)a2[c]
                           + wc.z * (float)a1[c] + wc.w * (float)a0[c];
        u[c] = silu_(acc);
        float gz = silu_((float)az[c]);
        gv[c] = pack_bf2_(Dl[c] * u[c] * gz, gz);
    }
    ((uint2*)xcb)[row * (DI_ / 4) + d4] = uint2{pack_bf2_(u[0], u[1]), pack_bf2_(u[2], u[3])};
    *(uint4*)(gag + row * DI_ + d) = uint4{gv[0], gv[1], gv[2], gv[3]};
}

// ============== single-pass scan: u32 streams, one b128 = 4 timesteps ==============
// lsw[ch][t]=(du,dtv); lga[ch][t]=(off,gz) read only by n==0 lanes; lbc[n][t]=(B,C) bf16
__global__ __launch_bounds__(256) void scan_lds_kernel(const unsigned* __restrict__ bcp,
                                                       const unsigned* __restrict__ swg,
                                                       const unsigned* __restrict__ gag,
                                                       const float* __restrict__ A_log,
                                                       bf16* __restrict__ yb) {
    __shared__ unsigned lsw[2][16][TP4_];
    __shared__ unsigned lga[2][16][TP4_];
    __shared__ unsigned lbc[2][16][TP4_];
    const int tid = threadIdx.x;
    const int n = tid & 15, dl = tid >> 4;
    const int d = blockIdx.x * 16 + dl;
    const int b = blockIdx.y;
    const float AvL = -__expf(A_log[(size_t)d * N_ + n]) * 1.44269504f;
    const size_t seqbase = (size_t)b * L_;
    const int d0 = blockIdx.x * 16;

    unsigned swr[4], gar[4], bcr[4];

    #define GLOAD(c)                                                        \
        {                                                                   \
            size_t rb = seqbase + (size_t)(c) * TCH_;                       \
            _Pragma("unroll")                                               \
            for (int i = 0; i < 4; i++) {                                   \
                size_t g = rb + i * 16 + dl;                                \
                swr[i] = swg[g * DI_ + d0 + n];                             \
                gar[i] = gag[g * DI_ + d0 + n];                             \
                bcr[i] = bcp[g * 16 + n];                                   \
            }                                                               \
        }
    #define DSWRITE(p)                                                      \
        {                                                                   \
            _Pragma("unroll")                                               \
            for (int i = 0; i < 4; i++) {                                   \
                int t = i * 16 + dl;                                        \
                lsw[p][n][t] = swr[i];                                      \
                lga[p][n][t] = gar[i];                                      \
                lbc[p][n][t] = bcr[i];                                      \
            }                                                               \
        }

    GLOAD(0);
    DSWRITE(0);
    __syncthreads();
    GLOAD(1);

    float h = 0.f;
    for (int c = 0; c < NCHT_; c++) {
        int p = c & 1;
        bf16* py = yb + (seqbase + (size_t)c * TCH_) * DI_ + d;
        #pragma unroll 4
        for (int t0 = 0; t0 < TCH_; t0 += 4) {
            uint4 s4 = *(const uint4*)&lsw[p][dl][t0];
            uint4 b4 = *(const uint4*)&lbc[p][n][t0];
            uint4 g4{0u, 0u, 0u, 0u};
            if (n == 0) g4 = *(const uint4*)&lga[p][dl][t0];
            unsigned ss[4] = {s4.x, s4.y, s4.z, s4.w};
            unsigned bb[4] = {b4.x, b4.y, b4.z, b4.w};
            unsigned gg[4] = {g4.x, g4.y, g4.z, g4.w};
            #pragma unroll
            for (int u = 0; u < 4; u++) {
                bf16x2 dv = __builtin_bit_cast(bf16x2, ss[u]);
                bf16x2 bcv = __builtin_bit_cast(bf16x2, bb[u]);
                float du = (float)dv.x, dtv = (float)dv.y;
                float dA = __builtin_amdgcn_exp2f(dtv * AvL);
                h = dA * h + du * (float)bcv.x;
                float pq = h * (float)bcv.y;
                pq = dpp_add_<0xB1>(pq);
                pq = dpp_add_<0x4E>(pq);
                pq = dpp_add_<0x124>(pq);
                pq = dpp_add_<0x128>(pq);
                if (n == 0) {
                    bf16x2 og = __builtin_bit_cast(bf16x2, gg[u]);
                    py[(size_t)(t0 + u) * DI_] = (bf16)(pq * (float)og.y + (float)og.x);
                }
            }
        }
        if (c + 1 < NCHT_) {
            DSWRITE(p ^ 1);
            __syncthreads();
            if (c + 2 < NCHT_) GLOAD(c + 2);
        }
    }
    #undef GLOAD
    #undef DSWRITE
}

extern "C" void kernel_launch(void* const* d_in, const int* in_sizes, int n_in,
                              void* d_out, int out_size, void* d_ws, size_t ws_size,
                              hipStream_t stream) {
    const float* x        = (const float*)d_in[0];
    const float* stat     = (const float*)d_in[1];
    const int*   mask     = (const int*)d_in[3];
    const float* emb_w    = (const float*)d_in[5];
    const float* emb_b    = (const float*)d_in[6];
    const float* static_w = (const float*)d_in[7];
    const float* static_b = (const float*)d_in[8];
    const float* ln_w     = (const float*)d_in[9];
    const float* ln_b     = (const float*)d_in[10];
    const float* norm_w   = (const float*)d_in[11];
    const float* in_proj_w  = (const float*)d_in[12];
    const float* conv_w   = (const float*)d_in[13];
    const float* conv_b   = (const float*)d_in[14];
    const float* x_proj_w = (const float*)d_in[15];
    const float* dt_proj_w= (const float*)d_in[16];
    const float* dt_proj_b= (const float*)d_in[17];
    const float* A_log    = (const float*)d_in[18];
    const float* D_param  = (const float*)d_in[19];
    const float* out_proj_w = (const float*)d_in[20];
    const float* norm_f_w = (const float*)d_in[21];
    const float* lm_head_w= (const float*)d_in[22];
    float* out = (float*)d_out;

    // ---- workspace layout (bytes), total ~190 MB ----
    char* p = (char*)d_ws;
    float*    h      = (float*)p;         p += (size_t)ROWS_ * D_ * 4;          // 50.3 MB
    bf16*     hn_bf  = (bf16*)p;          p += (size_t)CROWS_ * D_ * 2;         // 6.3
    char*     xz_region = p;                                                    // h_pre alias start
    bf16*     xz_bf  = (bf16*)p;          p += (size_t)CROWS_ * 2 * DI_ * 2;    // 25.2
    bf16*     xc_bf  = (bf16*)p;          p += (size_t)CROWS_ * DI_ * 2;        // 12.6
    unsigned* sw_g   = (unsigned*)p;      p += (size_t)CROWS_ * DI_ * 4;        // 25.2
    unsigned* gate_g = (unsigned*)p;      p += (size_t)CROWS_ * DI_ * 4;        // 25.2
    bf16*     bc16   = (bf16*)p;          p += (size_t)CROWS_ * 32 * 2;         // 0.26
    bf16*     dtr_bf = (bf16*)p;          p += (size_t)CROWS_ * 64 * 2;         // 0.5
    float*    pbuf   = (float*)p;         p += (size_t)KS_ * CROWS_ * 96 * 4;   // 6.3
    bf16*     y_bf   = (bf16*)p;          p += (size_t)ROWS_ * DI_ * 2;         // 50.3 (FULL batch)
    bf16*     inw_l  = (bf16*)p;          p += (size_t)2 * DI_ * D_ * 2;        // 4.7 (per-layer)
    bf16*     outw_l = (bf16*)p;          p += (size_t)D_ * DI_ * 2;            // 2.4 (per-layer)
    bf16*     xpwp_bf= (bf16*)p;          p += (size_t)NL_ * 128 * DI_ * 2;     // 1.6
    bf16*     dtwp_bf= (bf16*)p;          p += (size_t)NL_ * DI_ * 64 * 2;      // 0.8
    bf16*     lmw_bf = (bf16*)p;          p += (size_t)128 * D_ * 2;
    bf16*     embw_bf= (bf16*)p;          p += (size_t)D_ * KE_ * 2;
    bf16*     feats  = (bf16*)p;          p += (size_t)ROWS_ * KE_ * 2;         // 3.1
    float*    sstat  = (float*)p;         p += (size_t)B_ * D_ * 4;
    float*    h_pre  = (float*)xz_region; // 50.3 MB alias over xz/xc/sw_g (dead then)
    bf16*     hn_full= (bf16*)sw_g;       // 25.2 MB alias (sw_g dead at final stage)

    // ---- weight prep ----
    pad_lm_kernel<<<(128 * D_) / 256, 256, 0, stream>>>(lm_head_w, lmw_bf);
    pad_embw_kernel<<<(D_ * KE_) / 256, 256, 0, stream>>>(emb_w, embw_bf);
    feats_kernel<<<(ROWS_ * KE_) / 256, 256, 0, stream>>>(x, mask, feats);
    dim3 gxp((128 * DI_) / 256, NL_);
    xpw_pad_kernel<<<gxp, 256, 0, stream>>>(x_proj_w, xpwp_bf);
    dim3 gdt((DI_ * 64) / 256, NL_);
    dtw_pad_kernel<<<gdt, 256, 0, stream>>>(dt_proj_w, dtwp_bf);
    sstat_kernel<<<(B_ * D_) / 256, 256, 0, stream>>>(stat, static_w, static_b, emb_b, sstat);

    // ---- embed + LN ----
    gemm_mfma<0><<<(D_ / 128) * (ROWS_ / 128), 256, 0, stream>>>(
        feats, embw_bf, nullptr, h_pre, D_, KE_, D_ / 128,
        nullptr, nullptr, nullptr, nullptr);
    ln_embed_kernel<<<ROWS_, 256, 0, stream>>>(h_pre, sstat, ln_w, ln_b, h);

    // ---- layers ----
    for (int l = 0; l < NL_; l++) {
        cast_f2b_kernel<<<(2 * DI_ * D_) / 256, 256, 0, stream>>>(
            in_proj_w + (size_t)l * 2 * DI_ * D_, inw_l);
        cast_f2b_kernel<<<(D_ * DI_) / 256, 256, 0, stream>>>(
            out_proj_w + (size_t)l * D_ * DI_, outw_l);

        for (int c = 0; c < NCH_; c++) {
            float* hc = h + (size_t)c * CROWS_ * D_;

            rmsnorm_bf_kernel<<<CROWS_, 256, 0, stream>>>(hc, norm_w + (size_t)l * D_, hn_bf);

            gemm_mfma<1><<<(2 * DI_ / 128) * (CROWS_ / 128), 256, 0, stream>>>(
                hn_bf, inw_l, nullptr, xz_bf, 2 * DI_, D_, 2 * DI_ / 128,
                nullptr, nullptr, nullptr, nullptr);

            conv_silu_kernel<<<(CROWS_ * DI_ / 4) / 256, 256, 0, stream>>>(
                xz_bf, conv_w + (size_t)l * DI_ * 4, conv_b + (size_t)l * DI_,
                D_param + (size_t)l * DI_, xc_bf, gate_g);

            dim3 g2a(KS_, CROWS_ / 128);
            gemm_mfma<4><<<g2a, 256, 0, stream>>>(xc_bf, xpwp_bf + (size_t)l * 128 * DI_,
                                                  nullptr, nullptr, 0, DI_, 1,
                                                  nullptr, nullptr, pbuf, nullptr);
            xpost_kernel<<<(CROWS_ * 96) / 256, 256, 0, stream>>>(pbuf, dtr_bf, bc16);

            gemm_mfma<2><<<(DI_ / 128) * (CROWS_ / 128), 256, 0, stream>>>(
                dtr_bf, dtwp_bf + (size_t)l * DI_ * 64, nullptr, nullptr, 0, 64, DI_ / 128,
                dt_proj_b + (size_t)l * DI_, sw_g, nullptr, xc_bf);

            dim3 gs(DI_ / 16, CB_);
            scan_lds_kernel<<<gs, 256, 0, stream>>>((const unsigned*)bc16, sw_g, gate_g,
                                                    A_log + (size_t)l * DI_ * N_,
                                                    y_bf + (size_t)c * CROWS_ * DI_);
        }

        gemm_mfma<0><<<(D_ / 128) * (ROWS_ / 128), 256, 0, stream>>>(
            y_bf, outw_l, h, h, D_, DI_, D_ / 128,
            nullptr, nullptr, nullptr, nullptr);
    }

    // ---- final rmsnorm + lm_head (full batch) ----
    rmsnorm_bf_kernel<<<ROWS_, 256, 0, stream>>>(h, norm_f_w, hn_full);
    gemm_mfma<0><<<ROWS_ / 128, 256, 0, stream>>>(
        hn_full, lmw_bf, nullptr, out, V_, D_, 1,
        nullptr, nullptr, nullptr, nullptr);
}